// Round 10
// baseline (4392.287 us; speedup 1.0000x reference)
//
#include <hip/hip_runtime.h>
#include <math.h>

#define NPTS 8192
#define LGAB2 (-13.0f)   // log2(1/8192)
#define NWAVE 16         // waves per block (1024 threads)
#define MARGIN 60.0f     // chunk skip margin vs M_est (exponent units, base 2)

typedef __attribute__((ext_vector_type(2))) float f2;
typedef __attribute__((ext_vector_type(2))) int   i2;

// Packed-exp2 constants, passed as KERNEL ARGS so they live in SGPR pairs:
// VOP3P can't encode literals (R9 regression: per-use v_mov remat in the hot
// loop); runtime args can't be rematerialized and VOP3P reads SGPR directly.
struct ExpC { f2 lo, mag, c5, c4, c3, c2, c1, one; };

__device__ __forceinline__ float fexp2(float x){
#if __has_builtin(__builtin_amdgcn_exp2f)
  return __builtin_amdgcn_exp2f(x);
#else
  return exp2f(x);
#endif
}
__device__ __forceinline__ f2 ffma2(f2 a, f2 b, f2 c){
  return __builtin_elementwise_fma(a, b, c);   // v_pk_fma_f32
}
__device__ __forceinline__ f2 fmax2(f2 a, f2 b){
  return __builtin_elementwise_max(a, b);      // v_pk_max_f32
}

// Packed exp2 (deg-5 Taylor on [-0.5,0.5], rel err <= 2.4e-6), pure pk-VALU +
// 2 int ops, zero trans. Requires u <= ~+60 (guaranteed: u = w - M with M
// within ~25 of the true max); clamps u >= -120 to keep exponents normal.
__device__ __forceinline__ f2 pexp2(f2 u, const ExpC& E){
  u = fmax2(u, E.lo);
  f2 t  = u + E.mag;            // bits(t) = 0x4B400000 + rne(u)  (exact)
  f2 fi = t - E.mag;
  f2 f  = u - fi;               // f in [-0.5, 0.5]
  f2 p = ffma2(E.c5, f, E.c4);
  p = ffma2(p, f, E.c3);
  p = ffma2(p, f, E.c2);
  p = ffma2(p, f, E.c1);
  p = ffma2(p, f, E.one);
  i2 ti = __builtin_bit_cast(i2, t);
  i2 pb = __builtin_bit_cast(i2, p);
  pb += (ti << 23);             // exponent insert: 2x v_lshl_add_u32
  return __builtin_bit_cast(f2, pb);
}

// ---------------- counting sort by 12-bit Morton key (16^3 cells) ------------
__global__ __launch_bounds__(1024) void ws_sort(
    const float* __restrict__ x, const float* __restrict__ y,
    unsigned* __restrict__ sidx)
{
  __shared__ unsigned hist[4096];
  __shared__ unsigned wtot[16];
  const float* p = blockIdx.x ? y : x;
  int tid = threadIdx.x;
  for (int i = tid; i < 4096; i += 1024) hist[i] = 0;
  __syncthreads();
  unsigned key[8];
  for (int t = 0; t < 8; ++t) {
    int i = tid + (t << 10);
    unsigned q0 = (unsigned)fminf(fmaxf(p[3*i  ] * 16.f, 0.f), 15.f);
    unsigned q1 = (unsigned)fminf(fmaxf(p[3*i+1] * 16.f, 0.f), 15.f);
    unsigned q2 = (unsigned)fminf(fmaxf(p[3*i+2] * 16.f, 0.f), 15.f);
    unsigned k = 0;
    #pragma unroll
    for (int bb = 0; bb < 4; ++bb)
      k |= (((q0 >> bb) & 1u) << (3*bb)) | (((q1 >> bb) & 1u) << (3*bb+1))
         | (((q2 >> bb) & 1u) << (3*bb+2));
    key[t] = k;
    atomicAdd(&hist[k], 1u);
  }
  __syncthreads();
  unsigned c0 = hist[4*tid], c1 = hist[4*tid+1], c2 = hist[4*tid+2], c3 = hist[4*tid+3];
  unsigned tsum = c0 + c1 + c2 + c3;
  int lane = tid & 63, wv = tid >> 6;
  unsigned inc = tsum;
  for (int d = 1; d < 64; d <<= 1) {
    unsigned o = __shfl_up(inc, d);
    if (lane >= d) inc += o;
  }
  if (lane == 63) wtot[wv] = inc;
  __syncthreads();
  unsigned woff = 0;
  for (int k = 0; k < wv; ++k) woff += wtot[k];
  unsigned base = woff + inc - tsum;
  hist[4*tid] = base; hist[4*tid+1] = base + c0;
  hist[4*tid+2] = base + c0 + c1; hist[4*tid+3] = base + c0 + c1 + c2;
  __syncthreads();
  for (int t = 0; t < 8; ++t) {
    int i = tid + (t << 10);
    unsigned pos = atomicAdd(&hist[key[t]], 1u);
    sidx[blockIdx.x * NPTS + pos] = i;
  }
}

// Column pack layout (sorted domain): per 2 columns, float4 (x0,x1,y0,y1) then
// float4 (z0,z1,w0,w1) where w = h-term (exponent units base 2).
__global__ __launch_bounds__(256) void ws_setup(
    const float* __restrict__ x, const float* __restrict__ y,
    const unsigned* __restrict__ sidx,
    float4* __restrict__ xp, float4* __restrict__ yp,
    float4* __restrict__ colpack, float inv0ce)
{
  int t = blockIdx.x * 256 + threadIdx.x;
  if (t >= NPTS) return;
  int ox = sidx[t], oy = sidx[NPTS + t];
  float x0 = x[3*ox], x1 = x[3*ox+1], x2 = x[3*ox+2];
  float xs = x0*x0 + x1*x1 + x2*x2;
  float y0 = y[3*oy], y1 = y[3*oy+1], y2 = y[3*oy+2];
  float ys = y0*y0 + y1*y1 + y2*y2;
  xp[t] = make_float4(x0,x1,x2,xs);
  yp[t] = make_float4(y0,y1,y2,ys);
  float hx = LGAB2 - 0.5f*xs*inv0ce;
  float hy = LGAB2 - 0.5f*ys*inv0ce;
  int p = t >> 1, sub = t & 1;
  {
    float* c0 = (float*)(colpack + 0*NPTS);
    c0[p*8+sub] = y0; c0[p*8+2+sub] = y1; c0[p*8+4+sub] = y2; c0[p*8+6+sub] = hy;
    float* c3 = (float*)(colpack + 3*NPTS);
    c3[p*8+sub] = y0; c3[p*8+2+sub] = y1; c3[p*8+4+sub] = y2; c3[p*8+6+sub] = hy;
  }
  {
    float* c1 = (float*)(colpack + 1*NPTS);
    c1[p*8+sub] = x0; c1[p*8+2+sub] = x1; c1[p*8+4+sub] = x2; c1[p*8+6+sub] = hx;
    float* c2 = (float*)(colpack + 2*NPTS);
    c2[p*8+sub] = x0; c2[p*8+2+sub] = x1; c2[p*8+4+sub] = x2; c2[p*8+6+sub] = hx;
  }
}

// 32-point chunk bounding boxes: bbox[(set*256+c)*2 + {0,1}] = lo/hi
__global__ __launch_bounds__(256) void ws_bbox(
    const float4* __restrict__ xp, const float4* __restrict__ yp,
    float4* __restrict__ bbox)
{
  int c = threadIdx.x;
  int set = blockIdx.x;
  const float4* pp = set ? yp : xp;
  float lx = 1e30f, ly = 1e30f, lz = 1e30f;
  float hxx = -1e30f, hyy = -1e30f, hzz = -1e30f;
  for (int k = 0; k < 32; ++k) {
    float4 v = pp[c*32+k];
    lx = fminf(lx, v.x); ly = fminf(ly, v.y); lz = fminf(lz, v.z);
    hxx = fmaxf(hxx, v.x); hyy = fmaxf(hyy, v.y); hzz = fmaxf(hzz, v.z);
  }
  bbox[(set*256+c)*2+0] = make_float4(lx, ly, lz, 0.f);
  bbox[(set*256+c)*2+1] = make_float4(hxx, hyy, hzz, 0.f);
}

// dmin^2 between row-block rb (64 rows = 2 chunks of row-set) and col chunk c.
__global__ __launch_bounds__(256) void ws_dmin(
    const float4* __restrict__ bbox, float* __restrict__ dmin)
{
  int b = blockIdx.x;
  int s = b >> 7, rb = b & 127;
  int c = threadIdx.x;
  int rset = (s == 0 || s == 2) ? 0 : 1;
  int cset = (s == 0 || s == 3) ? 1 : 0;
  float4 l0 = bbox[(rset*256 + 2*rb)*2],     h0 = bbox[(rset*256 + 2*rb)*2+1];
  float4 l1 = bbox[(rset*256 + 2*rb+1)*2],   h1 = bbox[(rset*256 + 2*rb+1)*2+1];
  float alx = fminf(l0.x, l1.x), aly = fminf(l0.y, l1.y), alz = fminf(l0.z, l1.z);
  float ahx = fmaxf(h0.x, h1.x), ahy = fmaxf(h0.y, h1.y), ahz = fmaxf(h0.z, h1.z);
  float4 bl = bbox[(cset*256 + c)*2], bh = bbox[(cset*256 + c)*2+1];
  float dx = fmaxf(0.f, fmaxf(alx - bh.x, bl.x - ahx));
  float dy = fmaxf(0.f, fmaxf(aly - bh.y, bl.y - ahy));
  float dz = fmaxf(0.f, fmaxf(alz - bh.z, bl.z - ahz));
  dmin[((size_t)b << 8) + c] = dx*dx + dy*dy + dz*dz;
}

// One phase. mode 0 (p==0): exact two-pass, full scan (seeds Mw).
// mode 1 (p>=1): single pass with M_est from previous phase's LSE (rescaled by
// rho = ce_cur/ce_prev) + geometric chunk skip (margin 60). L = M_est +
// log2(sum 2^(w - M_est)) is exact for any in-range M_est.
// kind: 0 = assign (init), 1 = 0.5*(P+T) average, 2 = final (write Tfin)
__global__ __launch_bounds__(1024, 8) void ws_softmin(
    const float4* __restrict__ xp, const float4* __restrict__ yp,
    const float4* __restrict__ cps, float4* __restrict__ cpd,
    const float* __restrict__ dmin, const float* __restrict__ hmS,
    float* __restrict__ hmD, float* __restrict__ Mw,
    float* __restrict__ P, float* __restrict__ Tfin,
    float ce, float eps_ln2, float inv_next_ce, float rho, int kind, int mode,
    ExpC ec)
{
  int b = blockIdx.x;
  int s = b >> 7;
  int rb = b & 127;
  int rowbase = rb << 6;
  int tid = threadIdx.x;
  int lane = tid & 63;
  int w = __builtin_amdgcn_readfirstlane(tid >> 6);

  const float4* rp = (s == 0 || s == 2) ? xp : yp;
  float4 rv = rp[rowbase + lane];
  float a0 = rv.x * ce, a1 = rv.y * ce, a2 = rv.z * ce;
  float hx = -0.5f * rv.w * ce;
  f2 A0 = {a0,a0}, A1 = {a1,a1}, A2 = {a2,a2};
  const float4* pw = cps + (size_t)s * NPTS + (w << 9);
  int row = rowbase + lane;

  __shared__ float lm[NWAVE][64];
  __shared__ float lss[NWAVE][64];
  float myMest = 0.f;

  if (mode == 0) {
    // ---- exact two-pass full scan ----
    f2 mA = {-3.0e38f, -3.0e38f}, mB = mA;
    #pragma unroll 2
    for (int pb = 0; pb < 256; pb += 2) {
      float4 P0 = pw[2*pb+0], Q0 = pw[2*pb+1];
      float4 P1 = pw[2*pb+2], Q1 = pw[2*pb+3];
      f2 X0={P0.x,P0.y}, Y0={P0.z,P0.w}, Z0={Q0.x,Q0.y}, W0={Q0.z,Q0.w};
      f2 X1={P1.x,P1.y}, Y1={P1.z,P1.w}, Z1={Q1.x,Q1.y}, W1={Q1.z,Q1.w};
      f2 t0 = ffma2(A2, Z0, W0); t0 = ffma2(A1, Y0, t0); t0 = ffma2(A0, X0, t0);
      f2 t1 = ffma2(A2, Z1, W1); t1 = ffma2(A1, Y1, t1); t1 = ffma2(A0, X1, t1);
      mA = fmax2(mA, t0); mB = fmax2(mB, t1);
    }
    f2 mAB = fmax2(mA, mB);
    float m = fmaxf(mAB.x, mAB.y);
    f2 M2 = {m, m};
    f2 sA = {0.f,0.f}, sB = {0.f,0.f};
    #pragma unroll 2
    for (int pb = 0; pb < 256; pb += 2) {
      float4 P0 = pw[2*pb+0], Q0 = pw[2*pb+1];
      float4 P1 = pw[2*pb+2], Q1 = pw[2*pb+3];
      f2 X0={P0.x,P0.y}, Y0={P0.z,P0.w}, Z0={Q0.x,Q0.y}, W0={Q0.z,Q0.w};
      f2 X1={P1.x,P1.y}, Y1={P1.z,P1.w}, Z1={Q1.x,Q1.y}, W1={Q1.z,Q1.w};
      f2 u0 = ffma2(A2, Z0, W0 - M2); u0 = ffma2(A1, Y0, u0); u0 = ffma2(A0, X0, u0);
      f2 u1 = ffma2(A2, Z1, W1 - M2); u1 = ffma2(A1, Y1, u1); u1 = ffma2(A0, X1, u1);
      sA += pexp2(u0, ec); sB += pexp2(u1, ec);
    }
    f2 sAB = sA + sB;
    lm[w][lane] = m;
    lss[w][lane] = sAB.x + sAB.y;
  } else {
    // ---- single pass with M_est + geometric chunk skip ----
    float Mest = fmaf(Mw[s * NPTS + row] - LGAB2, rho, LGAB2);
    myMest = Mest;
    float thr = Mest - MARGIN;
    unsigned mask = 0u;
    #pragma unroll
    for (int c = 0; c < 16; ++c) {
      int gc = (w << 4) + c;
      float Wc = hmS[s*256 + gc] - 0.5f * ce * dmin[((size_t)b << 8) + gc];
      if (__ballot(Wc > thr)) mask |= (1u << c);
    }
    if (mask == 0u) mask = 0xFFFFu;     // safety: never drop everything
    mask = __builtin_amdgcn_readfirstlane(mask);
    float Mv = Mest - hx;
    f2 M2 = {Mv, Mv};
    f2 sA = {0.f,0.f}, sB = {0.f,0.f};
    #pragma unroll
    for (int c = 0; c < 16; ++c) {
      if (!((mask >> c) & 1u)) continue;
      const float4* pc = pw + (c << 5);
      #pragma unroll 4
      for (int pb = 0; pb < 16; ++pb) {
        float4 Pv = pc[2*pb], Qv = pc[2*pb+1];
        f2 X={Pv.x,Pv.y}, Y={Pv.z,Pv.w}, Z={Qv.x,Qv.y}, W={Qv.z,Qv.w};
        f2 u = ffma2(A2, Z, W - M2);
        u = ffma2(A1, Y, u);
        u = ffma2(A0, X, u);
        f2 e = pexp2(u, ec);
        if (pb & 1) sB += e; else sA += e;
      }
    }
    f2 sAB = sA + sB;
    lss[w][lane] = sAB.x + sAB.y;
  }
  __syncthreads();

  if (tid < 64) {
    float L;
    if (mode == 0) {
      float M = lm[0][lane];
      #pragma unroll
      for (int k = 1; k < NWAVE; ++k) M = fmaxf(M, lm[k][lane]);
      float S = 0.f;
      #pragma unroll
      for (int k = 0; k < NWAVE; ++k) S += lss[k][lane] * fexp2(lm[k][lane] - M);
      L = hx + M + log2f(S);
    } else {
      float S = 0.f;
      #pragma unroll
      for (int k = 0; k < NWAVE; ++k) S += lss[k][lane];
      S = fmaxf(S, 1e-30f);
      L = myMest + log2f(S);
    }
    float T = -eps_ln2 * L;
    Mw[s * NPTS + row] = L;
    if (kind == 2) {
      Tfin[s * NPTS + row] = T;
    } else {
      float* Pr = P + s * NPTS;
      float Pn = (kind == 0) ? T : 0.5f * (Pr[row] + T);
      Pr[row] = Pn;
      int dst = (s == 0) ? 1 : ((s == 1) ? 0 : s);
      float hy = LGAB2 + (Pn - 0.5f * rv.w) * inv_next_ce;
      float* cd = (float*)(cpd + (size_t)dst * NPTS);
      int p = row >> 1, sub = row & 1;
      cd[p*8+sub]   = rv.x;
      cd[p*8+2+sub] = rv.y;
      cd[p*8+4+sub] = rv.z;
      cd[p*8+6+sub] = hy;
      // per-chunk hhat-max for next phase: hhat = LGAB2 + Pn*ce_next
      float hN = fmaf(Pn, inv_next_ce, LGAB2);
      #pragma unroll
      for (int d = 16; d >= 1; d >>= 1) hN = fmaxf(hN, __shfl_xor(hN, d));
      if ((lane & 31) == 0) hmD[dst*256 + 2*rb + (lane >> 5)] = hN;
    }
  }
}

// loss = mean(f_fin - p_fin) + mean(g_fin - q_fin), fp64 accumulation
__global__ __launch_bounds__(256) void ws_reduce(
    const float* __restrict__ Tfin, float* __restrict__ out)
{
  int tid = threadIdx.x;
  double acc = 0.0;
  for (int i = tid; i < NPTS; i += 256) {
    acc += (double)Tfin[0*NPTS+i] - (double)Tfin[2*NPTS+i]
         + (double)Tfin[1*NPTS+i] - (double)Tfin[3*NPTS+i];
  }
  __shared__ double sd[256];
  sd[tid] = acc; __syncthreads();
  for (int k = 128; k > 0; k >>= 1) {
    if (tid < k) sd[tid] += sd[tid + k];
    __syncthreads();
  }
  if (tid == 0) out[0] = (float)(sd[0] / (double)NPTS);
}

extern "C" void kernel_launch(void* const* d_in, const int* in_sizes, int n_in,
                              void* d_out, int out_size, void* d_ws, size_t ws_size,
                              hipStream_t stream)
{
  const float* x = (const float*)d_in[0];
  const float* y = (const float*)d_in[1];
  float* out = (float*)d_out;

  char* wsp = (char*)d_ws;
  float4*   xp   = (float4*)wsp;   wsp += (size_t)NPTS * 16;
  float4*   yp   = (float4*)wsp;   wsp += (size_t)NPTS * 16;
  float4*   cpA  = (float4*)wsp;   wsp += (size_t)4 * NPTS * 16;
  float4*   cpB  = (float4*)wsp;   wsp += (size_t)4 * NPTS * 16;
  float*    P    = (float*)wsp;    wsp += (size_t)4 * NPTS * 4;
  float*    Tfin = (float*)wsp;    wsp += (size_t)4 * NPTS * 4;
  unsigned* sidx = (unsigned*)wsp; wsp += (size_t)2 * NPTS * 4;
  float*    Mw   = (float*)wsp;    wsp += (size_t)4 * NPTS * 4;
  float*    hmA  = (float*)wsp;    wsp += (size_t)4 * 256 * 4;
  float*    hmB  = (float*)wsp;    wsp += (size_t)4 * 256 * 4;
  float4*   bbox = (float4*)wsp;   wsp += (size_t)2 * 256 * 2 * 16;
  float*    dmin = (float*)wsp;    wsp += (size_t)4 * 128 * 256 * 4;

  // geomloss epsilon schedule, replicated in f64 exactly as Python does it
  double epss[64]; int n = 0;
  double e = 4.0;                       // DIAMETER**P
  const double r = 0.9 * 0.9;          // SCALING**P
  const double target = 0.01 * 0.01;   // BLUR**P
  while (e > target && n < 60) { epss[n++] = e; e *= r; }   // n == 51
  int NPH = n + 2;                     // init + n loop iters + final

  const double L2E  = 1.4426950408889634;
  const double LN2d = 0.6931471805599453;

  float feps[64];
  feps[0] = (float)epss[0];                       // init uses eps_sched[0]
  for (int p = 1; p <= n; ++p) feps[p] = (float)epss[p-1];
  feps[n+1] = 1e-4f;                              // eps_final

  ExpC ec;
  {
    auto mk = [](float v){ f2 r; r.x = v; r.y = v; return r; };
    ec.lo  = mk(-120.f);
    ec.mag = mk(12582912.f);          // 1.5 * 2^23
    ec.c5  = mk(1.3333558e-3f);
    ec.c4  = mk(9.6181291e-3f);
    ec.c3  = mk(5.5504109e-2f);
    ec.c2  = mk(2.4022651e-1f);
    ec.c1  = mk(6.9314718e-1f);
    ec.one = mk(1.f);
  }

  float inv0ce = (float)(L2E / (double)feps[0]);
  ws_sort<<<2, 1024, 0, stream>>>(x, y, sidx);
  ws_setup<<<(NPTS + 255) / 256, 256, 0, stream>>>(x, y, sidx, xp, yp, cpA, inv0ce);
  ws_bbox<<<2, 256, 0, stream>>>(xp, yp, bbox);
  ws_dmin<<<512, 256, 0, stream>>>(bbox, dmin);

  for (int p = 0; p < NPH; ++p) {
    float epsf = feps[p];
    float ce = (float)(L2E / (double)epsf);
    float eps_ln2 = (float)((double)epsf * LN2d);
    float inv_next_ce = 0.f;
    if (p < NPH - 1) inv_next_ce = (float)(L2E / (double)feps[p+1]);
    float rho = 1.f;
    if (p >= 1) rho = (float)((double)feps[p-1] / (double)feps[p]);
    int kind = (p == 0) ? 0 : ((p == NPH - 1) ? 2 : 1);
    int mode = (p == 0) ? 0 : 1;
    const float4* src = (p & 1) ? cpB : cpA;
    float4*       dst = (p & 1) ? cpA : cpB;
    const float*  hmS = (p & 1) ? hmB : hmA;
    float*        hmD = (p & 1) ? hmA : hmB;
    ws_softmin<<<512, 1024, 0, stream>>>(xp, yp, src, dst, dmin, hmS, hmD,
                                         Mw, P, Tfin,
                                         ce, eps_ln2, inv_next_ce, rho, kind, mode,
                                         ec);
  }

  ws_reduce<<<1, 256, 0, stream>>>(Tfin, out);
}

// Round 11
// 4312.756 us; speedup vs baseline: 1.0184x; 1.0184x over previous
//
#include <hip/hip_runtime.h>
#include <math.h>

#define NPTS 8192
#define LGAB2 (-13.0f)   // log2(1/8192)
#define NWAVE 16         // waves per block (1024 threads)
#define MARGIN 26.0f     // chunk skip margin vs M_est (<=512*2^-26 rel on S)

typedef __attribute__((ext_vector_type(2))) float f2;
typedef __attribute__((ext_vector_type(2))) int   i2;

__device__ __forceinline__ float fexp2(float x){
#if __has_builtin(__builtin_amdgcn_exp2f)
  return __builtin_amdgcn_exp2f(x);
#else
  return exp2f(x);
#endif
}
__device__ __forceinline__ f2 ffma2(f2 a, f2 b, f2 c){
  return __builtin_elementwise_fma(a, b, c);   // v_pk_fma_f32
}
__device__ __forceinline__ f2 fmax2(f2 a, f2 b){
  return __builtin_elementwise_max(a, b);      // v_pk_max_f32
}
// Force a value into a VGPR pair and make it opaque to ISel: VOP3P can't
// encode literals, and IR-constant operands get rematerialized per-use
// (R9/R10 regressions). An empty asm with "+v" pins it, materialized once.
__device__ __forceinline__ f2 opaque2(f2 v){ asm("" : "+v"(v)); return v; }

// Packed exp2, deg-5 Taylor on [-0.5,0.5] (rel err <= 2.4e-6), pure pk-VALU.
// Needs u <= ~+60 (guaranteed: u = w - M_est, M_est within ~25 of true max;
// verified empirically R9/R10 passed with no hi clamp). Lo-clamp keeps the
// exponent-insert in normal range.
__device__ __forceinline__ f2 pexp2(f2 u, f2 klo, f2 kmag, f2 k5, f2 k4,
                                    f2 k3, f2 k2, f2 k1, f2 kone){
  u = fmax2(u, klo);
  f2 t  = u + kmag;             // bits(t) = 0x4B400000 + rne(u)  (exact)
  f2 fi = t - kmag;
  f2 f  = u - fi;               // f in [-0.5, 0.5]
  f2 p = ffma2(k5, f, k4);
  p = ffma2(p, f, k3);
  p = ffma2(p, f, k2);
  p = ffma2(p, f, k1);
  p = ffma2(p, f, kone);
  i2 ti = __builtin_bit_cast(i2, t);
  i2 pb = __builtin_bit_cast(i2, p);
  pb += (ti << 23);             // exponent insert
  return __builtin_bit_cast(f2, pb);
}

// ---------------- counting sort by 12-bit Morton key (16^3 cells) ------------
__global__ __launch_bounds__(1024) void ws_sort(
    const float* __restrict__ x, const float* __restrict__ y,
    unsigned* __restrict__ sidx)
{
  __shared__ unsigned hist[4096];
  __shared__ unsigned wtot[16];
  const float* p = blockIdx.x ? y : x;
  int tid = threadIdx.x;
  for (int i = tid; i < 4096; i += 1024) hist[i] = 0;
  __syncthreads();
  unsigned key[8];
  for (int t = 0; t < 8; ++t) {
    int i = tid + (t << 10);
    unsigned q0 = (unsigned)fminf(fmaxf(p[3*i  ] * 16.f, 0.f), 15.f);
    unsigned q1 = (unsigned)fminf(fmaxf(p[3*i+1] * 16.f, 0.f), 15.f);
    unsigned q2 = (unsigned)fminf(fmaxf(p[3*i+2] * 16.f, 0.f), 15.f);
    unsigned k = 0;
    #pragma unroll
    for (int bb = 0; bb < 4; ++bb)
      k |= (((q0 >> bb) & 1u) << (3*bb)) | (((q1 >> bb) & 1u) << (3*bb+1))
         | (((q2 >> bb) & 1u) << (3*bb+2));
    key[t] = k;
    atomicAdd(&hist[k], 1u);
  }
  __syncthreads();
  unsigned c0 = hist[4*tid], c1 = hist[4*tid+1], c2 = hist[4*tid+2], c3 = hist[4*tid+3];
  unsigned tsum = c0 + c1 + c2 + c3;
  int lane = tid & 63, wv = tid >> 6;
  unsigned inc = tsum;
  for (int d = 1; d < 64; d <<= 1) {
    unsigned o = __shfl_up(inc, d);
    if (lane >= d) inc += o;
  }
  if (lane == 63) wtot[wv] = inc;
  __syncthreads();
  unsigned woff = 0;
  for (int k = 0; k < wv; ++k) woff += wtot[k];
  unsigned base = woff + inc - tsum;
  hist[4*tid] = base; hist[4*tid+1] = base + c0;
  hist[4*tid+2] = base + c0 + c1; hist[4*tid+3] = base + c0 + c1 + c2;
  __syncthreads();
  for (int t = 0; t < 8; ++t) {
    int i = tid + (t << 10);
    unsigned pos = atomicAdd(&hist[key[t]], 1u);
    sidx[blockIdx.x * NPTS + pos] = i;
  }
}

// Column pack layout (sorted domain): per 2 columns, float4 (x0,x1,y0,y1) then
// float4 (z0,z1,w0,w1) where w = h-term (exponent units base 2).
__global__ __launch_bounds__(256) void ws_setup(
    const float* __restrict__ x, const float* __restrict__ y,
    const unsigned* __restrict__ sidx,
    float4* __restrict__ xp, float4* __restrict__ yp,
    float4* __restrict__ colpack, float inv0ce)
{
  int t = blockIdx.x * 256 + threadIdx.x;
  if (t >= NPTS) return;
  int ox = sidx[t], oy = sidx[NPTS + t];
  float x0 = x[3*ox], x1 = x[3*ox+1], x2 = x[3*ox+2];
  float xs = x0*x0 + x1*x1 + x2*x2;
  float y0 = y[3*oy], y1 = y[3*oy+1], y2 = y[3*oy+2];
  float ys = y0*y0 + y1*y1 + y2*y2;
  xp[t] = make_float4(x0,x1,x2,xs);
  yp[t] = make_float4(y0,y1,y2,ys);
  float hx = LGAB2 - 0.5f*xs*inv0ce;
  float hy = LGAB2 - 0.5f*ys*inv0ce;
  int p = t >> 1, sub = t & 1;
  {
    float* c0 = (float*)(colpack + 0*NPTS);
    c0[p*8+sub] = y0; c0[p*8+2+sub] = y1; c0[p*8+4+sub] = y2; c0[p*8+6+sub] = hy;
    float* c3 = (float*)(colpack + 3*NPTS);
    c3[p*8+sub] = y0; c3[p*8+2+sub] = y1; c3[p*8+4+sub] = y2; c3[p*8+6+sub] = hy;
  }
  {
    float* c1 = (float*)(colpack + 1*NPTS);
    c1[p*8+sub] = x0; c1[p*8+2+sub] = x1; c1[p*8+4+sub] = x2; c1[p*8+6+sub] = hx;
    float* c2 = (float*)(colpack + 2*NPTS);
    c2[p*8+sub] = x0; c2[p*8+2+sub] = x1; c2[p*8+4+sub] = x2; c2[p*8+6+sub] = hx;
  }
}

// 32-point chunk bounding boxes: bbox[(set*256+c)*2 + {0,1}] = lo/hi
__global__ __launch_bounds__(256) void ws_bbox(
    const float4* __restrict__ xp, const float4* __restrict__ yp,
    float4* __restrict__ bbox)
{
  int c = threadIdx.x;
  int set = blockIdx.x;
  const float4* pp = set ? yp : xp;
  float lx = 1e30f, ly = 1e30f, lz = 1e30f;
  float hxx = -1e30f, hyy = -1e30f, hzz = -1e30f;
  for (int k = 0; k < 32; ++k) {
    float4 v = pp[c*32+k];
    lx = fminf(lx, v.x); ly = fminf(ly, v.y); lz = fminf(lz, v.z);
    hxx = fmaxf(hxx, v.x); hyy = fmaxf(hyy, v.y); hzz = fmaxf(hzz, v.z);
  }
  bbox[(set*256+c)*2+0] = make_float4(lx, ly, lz, 0.f);
  bbox[(set*256+c)*2+1] = make_float4(hxx, hyy, hzz, 0.f);
}

// dmin^2 between row-block rb (64 rows = 2 chunks of row-set) and col chunk c.
__global__ __launch_bounds__(256) void ws_dmin(
    const float4* __restrict__ bbox, float* __restrict__ dmin)
{
  int b = blockIdx.x;
  int s = b >> 7, rb = b & 127;
  int c = threadIdx.x;
  int rset = (s == 0 || s == 2) ? 0 : 1;
  int cset = (s == 0 || s == 3) ? 1 : 0;
  float4 l0 = bbox[(rset*256 + 2*rb)*2],     h0 = bbox[(rset*256 + 2*rb)*2+1];
  float4 l1 = bbox[(rset*256 + 2*rb+1)*2],   h1 = bbox[(rset*256 + 2*rb+1)*2+1];
  float alx = fminf(l0.x, l1.x), aly = fminf(l0.y, l1.y), alz = fminf(l0.z, l1.z);
  float ahx = fmaxf(h0.x, h1.x), ahy = fmaxf(h0.y, h1.y), ahz = fmaxf(h0.z, h1.z);
  float4 bl = bbox[(cset*256 + c)*2], bh = bbox[(cset*256 + c)*2+1];
  float dx = fmaxf(0.f, fmaxf(alx - bh.x, bl.x - ahx));
  float dy = fmaxf(0.f, fmaxf(aly - bh.y, bl.y - ahy));
  float dz = fmaxf(0.f, fmaxf(alz - bh.z, bl.z - ahz));
  dmin[((size_t)b << 8) + c] = dx*dx + dy*dy + dz*dz;
}

// One phase. mode 0 (p==0): exact two-pass, full scan (seeds Mw).
// mode 1 (p>=1): single pass with M_est from previous phase's LSE (rescaled by
// rho) + geometric chunk skip. L = M_est + log2(sum 2^(w - M_est)) is exact
// for any in-range M_est.
// kind: 0 = assign (init), 1 = 0.5*(P+T) average, 2 = final (write Tfin)
__global__ __launch_bounds__(1024, 8) void ws_softmin(
    const float4* __restrict__ xp, const float4* __restrict__ yp,
    const float4* __restrict__ cps, float4* __restrict__ cpd,
    const float* __restrict__ dmin, const float* __restrict__ hmS,
    float* __restrict__ hmD, float* __restrict__ Mw,
    float* __restrict__ P, float* __restrict__ Tfin,
    float ce, float eps_ln2, float inv_next_ce, float rho, int kind, int mode)
{
  int b = blockIdx.x;
  int s = b >> 7;
  int rb = b & 127;
  int rowbase = rb << 6;
  int tid = threadIdx.x;
  int lane = tid & 63;
  int w = __builtin_amdgcn_readfirstlane(tid >> 6);

  const float4* rp = (s == 0 || s == 2) ? xp : yp;
  float4 rv = rp[rowbase + lane];
  float a0 = rv.x * ce, a1 = rv.y * ce, a2 = rv.z * ce;
  float hx = -0.5f * rv.w * ce;
  f2 A0 = {a0,a0}, A1 = {a1,a1}, A2 = {a2,a2};
  const float4* pw = cps + (size_t)s * NPTS + (w << 9);
  int row = rowbase + lane;

  // Poly-exp2 constants, pinned to VGPR pairs ONCE (opaque to ISel).
  f2 klo  = opaque2((f2){-120.f, -120.f});
  f2 kmag = opaque2((f2){12582912.f, 12582912.f});   // 1.5 * 2^23
  f2 k5   = opaque2((f2){1.3333558e-3f, 1.3333558e-3f});
  f2 k4   = opaque2((f2){9.6181291e-3f, 9.6181291e-3f});
  f2 k3   = opaque2((f2){5.5504109e-2f, 5.5504109e-2f});
  f2 k2   = opaque2((f2){2.4022651e-1f, 2.4022651e-1f});
  f2 k1   = opaque2((f2){6.9314718e-1f, 6.9314718e-1f});
  f2 kone = opaque2((f2){1.f, 1.f});

  __shared__ float lm[NWAVE][64];
  __shared__ float lss[NWAVE][64];
  float myMest = 0.f;

  if (mode == 0) {
    // ---- exact two-pass full scan ----
    f2 mA = {-3.0e38f, -3.0e38f}, mB = mA;
    #pragma unroll 2
    for (int pb = 0; pb < 256; pb += 2) {
      float4 P0 = pw[2*pb+0], Q0 = pw[2*pb+1];
      float4 P1 = pw[2*pb+2], Q1 = pw[2*pb+3];
      f2 X0={P0.x,P0.y}, Y0={P0.z,P0.w}, Z0={Q0.x,Q0.y}, W0={Q0.z,Q0.w};
      f2 X1={P1.x,P1.y}, Y1={P1.z,P1.w}, Z1={Q1.x,Q1.y}, W1={Q1.z,Q1.w};
      f2 t0 = ffma2(A2, Z0, W0); t0 = ffma2(A1, Y0, t0); t0 = ffma2(A0, X0, t0);
      f2 t1 = ffma2(A2, Z1, W1); t1 = ffma2(A1, Y1, t1); t1 = ffma2(A0, X1, t1);
      mA = fmax2(mA, t0); mB = fmax2(mB, t1);
    }
    f2 mAB = fmax2(mA, mB);
    float m = fmaxf(mAB.x, mAB.y);
    f2 M2 = {m, m};
    f2 sA = {0.f,0.f}, sB = {0.f,0.f};
    #pragma unroll 2
    for (int pb = 0; pb < 256; pb += 2) {
      float4 P0 = pw[2*pb+0], Q0 = pw[2*pb+1];
      float4 P1 = pw[2*pb+2], Q1 = pw[2*pb+3];
      f2 X0={P0.x,P0.y}, Y0={P0.z,P0.w}, Z0={Q0.x,Q0.y}, W0={Q0.z,Q0.w};
      f2 X1={P1.x,P1.y}, Y1={P1.z,P1.w}, Z1={Q1.x,Q1.y}, W1={Q1.z,Q1.w};
      f2 u0 = ffma2(A2, Z0, W0 - M2); u0 = ffma2(A1, Y0, u0); u0 = ffma2(A0, X0, u0);
      f2 u1 = ffma2(A2, Z1, W1 - M2); u1 = ffma2(A1, Y1, u1); u1 = ffma2(A0, X1, u1);
      sA += pexp2(u0, klo, kmag, k5, k4, k3, k2, k1, kone);
      sB += pexp2(u1, klo, kmag, k5, k4, k3, k2, k1, kone);
    }
    f2 sAB = sA + sB;
    lm[w][lane] = m;
    lss[w][lane] = sAB.x + sAB.y;
  } else {
    // ---- single pass with M_est + geometric chunk skip ----
    float Mest = fmaf(Mw[s * NPTS + row] - LGAB2, rho, LGAB2);
    myMest = Mest;
    float thr = Mest - MARGIN;
    unsigned mask = 0u;
    #pragma unroll
    for (int c = 0; c < 16; ++c) {
      int gc = (w << 4) + c;
      float Wc = hmS[s*256 + gc] - 0.5f * ce * dmin[((size_t)b << 8) + gc];
      if (__ballot(Wc > thr)) mask |= (1u << c);
    }
    if (mask == 0u) mask = 0xFFFFu;     // safety: never drop everything
    mask = __builtin_amdgcn_readfirstlane(mask);
    float Mv = Mest - hx;
    f2 M2 = {Mv, Mv};
    f2 sA = {0.f,0.f}, sB = {0.f,0.f};
    #pragma unroll
    for (int c = 0; c < 16; ++c) {
      if (!((mask >> c) & 1u)) continue;
      const float4* pc = pw + (c << 5);
      #pragma unroll 4
      for (int pb = 0; pb < 16; ++pb) {
        float4 Pv = pc[2*pb], Qv = pc[2*pb+1];
        f2 X={Pv.x,Pv.y}, Y={Pv.z,Pv.w}, Z={Qv.x,Qv.y}, W={Qv.z,Qv.w};
        f2 u = ffma2(A2, Z, W - M2);
        u = ffma2(A1, Y, u);
        u = ffma2(A0, X, u);
        f2 e = pexp2(u, klo, kmag, k5, k4, k3, k2, k1, kone);
        if (pb & 1) sB += e; else sA += e;
      }
    }
    f2 sAB = sA + sB;
    lss[w][lane] = sAB.x + sAB.y;
  }
  __syncthreads();

  if (tid < 64) {
    float L;
    if (mode == 0) {
      float M = lm[0][lane];
      #pragma unroll
      for (int k = 1; k < NWAVE; ++k) M = fmaxf(M, lm[k][lane]);
      float S = 0.f;
      #pragma unroll
      for (int k = 0; k < NWAVE; ++k) S += lss[k][lane] * fexp2(lm[k][lane] - M);
      L = hx + M + log2f(S);
    } else {
      float S = 0.f;
      #pragma unroll
      for (int k = 0; k < NWAVE; ++k) S += lss[k][lane];
      S = fmaxf(S, 1e-30f);
      L = myMest + log2f(S);
    }
    float T = -eps_ln2 * L;
    Mw[s * NPTS + row] = L;
    if (kind == 2) {
      Tfin[s * NPTS + row] = T;
    } else {
      float* Pr = P + s * NPTS;
      float Pn = (kind == 0) ? T : 0.5f * (Pr[row] + T);
      Pr[row] = Pn;
      int dst = (s == 0) ? 1 : ((s == 1) ? 0 : s);
      float hy = LGAB2 + (Pn - 0.5f * rv.w) * inv_next_ce;
      float* cd = (float*)(cpd + (size_t)dst * NPTS);
      int p = row >> 1, sub = row & 1;
      cd[p*8+sub]   = rv.x;
      cd[p*8+2+sub] = rv.y;
      cd[p*8+4+sub] = rv.z;
      cd[p*8+6+sub] = hy;
      // per-chunk hhat-max for next phase: hhat = LGAB2 + Pn*ce_next
      float hN = fmaf(Pn, inv_next_ce, LGAB2);
      #pragma unroll
      for (int d = 16; d >= 1; d >>= 1) hN = fmaxf(hN, __shfl_xor(hN, d));
      if ((lane & 31) == 0) hmD[dst*256 + 2*rb + (lane >> 5)] = hN;
    }
  }
}

// loss = mean(f_fin - p_fin) + mean(g_fin - q_fin), fp64 accumulation
__global__ __launch_bounds__(256) void ws_reduce(
    const float* __restrict__ Tfin, float* __restrict__ out)
{
  int tid = threadIdx.x;
  double acc = 0.0;
  for (int i = tid; i < NPTS; i += 256) {
    acc += (double)Tfin[0*NPTS+i] - (double)Tfin[2*NPTS+i]
         + (double)Tfin[1*NPTS+i] - (double)Tfin[3*NPTS+i];
  }
  __shared__ double sd[256];
  sd[tid] = acc; __syncthreads();
  for (int k = 128; k > 0; k >>= 1) {
    if (tid < k) sd[tid] += sd[tid + k];
    __syncthreads();
  }
  if (tid == 0) out[0] = (float)(sd[0] / (double)NPTS);
}

extern "C" void kernel_launch(void* const* d_in, const int* in_sizes, int n_in,
                              void* d_out, int out_size, void* d_ws, size_t ws_size,
                              hipStream_t stream)
{
  const float* x = (const float*)d_in[0];
  const float* y = (const float*)d_in[1];
  float* out = (float*)d_out;

  char* wsp = (char*)d_ws;
  float4*   xp   = (float4*)wsp;   wsp += (size_t)NPTS * 16;
  float4*   yp   = (float4*)wsp;   wsp += (size_t)NPTS * 16;
  float4*   cpA  = (float4*)wsp;   wsp += (size_t)4 * NPTS * 16;
  float4*   cpB  = (float4*)wsp;   wsp += (size_t)4 * NPTS * 16;
  float*    P    = (float*)wsp;    wsp += (size_t)4 * NPTS * 4;
  float*    Tfin = (float*)wsp;    wsp += (size_t)4 * NPTS * 4;
  unsigned* sidx = (unsigned*)wsp; wsp += (size_t)2 * NPTS * 4;
  float*    Mw   = (float*)wsp;    wsp += (size_t)4 * NPTS * 4;
  float*    hmA  = (float*)wsp;    wsp += (size_t)4 * 256 * 4;
  float*    hmB  = (float*)wsp;    wsp += (size_t)4 * 256 * 4;
  float4*   bbox = (float4*)wsp;   wsp += (size_t)2 * 256 * 2 * 16;
  float*    dmin = (float*)wsp;    wsp += (size_t)4 * 128 * 256 * 4;

  // geomloss epsilon schedule, replicated in f64 exactly as Python does it
  double epss[64]; int n = 0;
  double e = 4.0;                       // DIAMETER**P
  const double r = 0.9 * 0.9;          // SCALING**P
  const double target = 0.01 * 0.01;   // BLUR**P
  while (e > target && n < 60) { epss[n++] = e; e *= r; }   // n == 51
  int NPH = n + 2;                     // init + n loop iters + final

  const double L2E  = 1.4426950408889634;
  const double LN2d = 0.6931471805599453;

  float feps[64];
  feps[0] = (float)epss[0];                       // init uses eps_sched[0]
  for (int p = 1; p <= n; ++p) feps[p] = (float)epss[p-1];
  feps[n+1] = 1e-4f;                              // eps_final

  float inv0ce = (float)(L2E / (double)feps[0]);
  ws_sort<<<2, 1024, 0, stream>>>(x, y, sidx);
  ws_setup<<<(NPTS + 255) / 256, 256, 0, stream>>>(x, y, sidx, xp, yp, cpA, inv0ce);
  ws_bbox<<<2, 256, 0, stream>>>(xp, yp, bbox);
  ws_dmin<<<512, 256, 0, stream>>>(bbox, dmin);

  for (int p = 0; p < NPH; ++p) {
    float epsf = feps[p];
    float ce = (float)(L2E / (double)epsf);
    float eps_ln2 = (float)((double)epsf * LN2d);
    float inv_next_ce = 0.f;
    if (p < NPH - 1) inv_next_ce = (float)(L2E / (double)feps[p+1]);
    float rho = 1.f;
    if (p >= 1) rho = (float)((double)feps[p-1] / (double)feps[p]);
    int kind = (p == 0) ? 0 : ((p == NPH - 1) ? 2 : 1);
    int mode = (p == 0) ? 0 : 1;
    const float4* src = (p & 1) ? cpB : cpA;
    float4*       dst = (p & 1) ? cpA : cpB;
    const float*  hmS = (p & 1) ? hmB : hmA;
    float*        hmD = (p & 1) ? hmA : hmB;
    ws_softmin<<<512, 1024, 0, stream>>>(xp, yp, src, dst, dmin, hmS, hmD,
                                         Mw, P, Tfin,
                                         ce, eps_ln2, inv_next_ce, rho, kind, mode);
  }

  ws_reduce<<<1, 256, 0, stream>>>(Tfin, out);
}

// Round 12
// 2442.223 us; speedup vs baseline: 1.7985x; 1.7659x over previous
//
#include <hip/hip_runtime.h>
#include <math.h>

#define NPTS 8192
#define LGAB2 (-13.0f)   // log2(1/8192)
#define NWAVE 16         // waves per block (1024 threads)
#define MARGIN 20.0f     // chunk skip margin vs M_est (exponent units, base 2)

typedef __attribute__((ext_vector_type(2))) float f2;

__device__ __forceinline__ float fexp2(float x){
#if __has_builtin(__builtin_amdgcn_exp2f)
  return __builtin_amdgcn_exp2f(x);
#else
  return exp2f(x);
#endif
}
__device__ __forceinline__ f2 ffma2(f2 a, f2 b, f2 c){
  return __builtin_elementwise_fma(a, b, c);   // v_pk_fma_f32
}
__device__ __forceinline__ f2 fmax2(f2 a, f2 b){
  return __builtin_elementwise_max(a, b);      // v_pk_max_f32
}

// ---------------- counting sort by 12-bit Morton key (16^3 cells) ------------
__global__ __launch_bounds__(1024) void ws_sort(
    const float* __restrict__ x, const float* __restrict__ y,
    unsigned* __restrict__ sidx)
{
  __shared__ unsigned hist[4096];
  __shared__ unsigned wtot[16];
  const float* p = blockIdx.x ? y : x;
  int tid = threadIdx.x;
  for (int i = tid; i < 4096; i += 1024) hist[i] = 0;
  __syncthreads();
  unsigned key[8];
  for (int t = 0; t < 8; ++t) {
    int i = tid + (t << 10);
    unsigned q0 = (unsigned)fminf(fmaxf(p[3*i  ] * 16.f, 0.f), 15.f);
    unsigned q1 = (unsigned)fminf(fmaxf(p[3*i+1] * 16.f, 0.f), 15.f);
    unsigned q2 = (unsigned)fminf(fmaxf(p[3*i+2] * 16.f, 0.f), 15.f);
    unsigned k = 0;
    #pragma unroll
    for (int bb = 0; bb < 4; ++bb)
      k |= (((q0 >> bb) & 1u) << (3*bb)) | (((q1 >> bb) & 1u) << (3*bb+1))
         | (((q2 >> bb) & 1u) << (3*bb+2));
    key[t] = k;
    atomicAdd(&hist[k], 1u);
  }
  __syncthreads();
  unsigned c0 = hist[4*tid], c1 = hist[4*tid+1], c2 = hist[4*tid+2], c3 = hist[4*tid+3];
  unsigned tsum = c0 + c1 + c2 + c3;
  int lane = tid & 63, wv = tid >> 6;
  unsigned inc = tsum;
  for (int d = 1; d < 64; d <<= 1) {
    unsigned o = __shfl_up(inc, d);
    if (lane >= d) inc += o;
  }
  if (lane == 63) wtot[wv] = inc;
  __syncthreads();
  unsigned woff = 0;
  for (int k = 0; k < wv; ++k) woff += wtot[k];
  unsigned base = woff + inc - tsum;
  hist[4*tid] = base; hist[4*tid+1] = base + c0;
  hist[4*tid+2] = base + c0 + c1; hist[4*tid+3] = base + c0 + c1 + c2;
  __syncthreads();
  for (int t = 0; t < 8; ++t) {
    int i = tid + (t << 10);
    unsigned pos = atomicAdd(&hist[key[t]], 1u);
    sidx[blockIdx.x * NPTS + pos] = i;
  }
}

// Column pack layout (sorted domain): per 2 columns, float4 (x0,x1,y0,y1) then
// float4 (z0,z1,w0,w1) where w = h-term (exponent units base 2).
__global__ __launch_bounds__(256) void ws_setup(
    const float* __restrict__ x, const float* __restrict__ y,
    const unsigned* __restrict__ sidx,
    float4* __restrict__ xp, float4* __restrict__ yp,
    float4* __restrict__ colpack, float inv0ce)
{
  int t = blockIdx.x * 256 + threadIdx.x;
  if (t >= NPTS) return;
  int ox = sidx[t], oy = sidx[NPTS + t];
  float x0 = x[3*ox], x1 = x[3*ox+1], x2 = x[3*ox+2];
  float xs = x0*x0 + x1*x1 + x2*x2;
  float y0 = y[3*oy], y1 = y[3*oy+1], y2 = y[3*oy+2];
  float ys = y0*y0 + y1*y1 + y2*y2;
  xp[t] = make_float4(x0,x1,x2,xs);
  yp[t] = make_float4(y0,y1,y2,ys);
  float hx = LGAB2 - 0.5f*xs*inv0ce;
  float hy = LGAB2 - 0.5f*ys*inv0ce;
  int p = t >> 1, sub = t & 1;
  {
    float* c0 = (float*)(colpack + 0*NPTS);
    c0[p*8+sub] = y0; c0[p*8+2+sub] = y1; c0[p*8+4+sub] = y2; c0[p*8+6+sub] = hy;
    float* c3 = (float*)(colpack + 3*NPTS);
    c3[p*8+sub] = y0; c3[p*8+2+sub] = y1; c3[p*8+4+sub] = y2; c3[p*8+6+sub] = hy;
  }
  {
    float* c1 = (float*)(colpack + 1*NPTS);
    c1[p*8+sub] = x0; c1[p*8+2+sub] = x1; c1[p*8+4+sub] = x2; c1[p*8+6+sub] = hx;
    float* c2 = (float*)(colpack + 2*NPTS);
    c2[p*8+sub] = x0; c2[p*8+2+sub] = x1; c2[p*8+4+sub] = x2; c2[p*8+6+sub] = hx;
  }
}

// 16-point chunk bounding boxes: bbox[(set*512+c)*2 + {0,1}] = lo/hi
__global__ __launch_bounds__(512) void ws_bbox(
    const float4* __restrict__ xp, const float4* __restrict__ yp,
    float4* __restrict__ bbox)
{
  int c = threadIdx.x;           // 0..511
  int set = blockIdx.x;
  const float4* pp = set ? yp : xp;
  float lx = 1e30f, ly = 1e30f, lz = 1e30f;
  float hxx = -1e30f, hyy = -1e30f, hzz = -1e30f;
  for (int k = 0; k < 16; ++k) {
    float4 v = pp[c*16+k];
    lx = fminf(lx, v.x); ly = fminf(ly, v.y); lz = fminf(lz, v.z);
    hxx = fmaxf(hxx, v.x); hyy = fmaxf(hyy, v.y); hzz = fmaxf(hzz, v.z);
  }
  bbox[(set*512+c)*2+0] = make_float4(lx, ly, lz, 0.f);
  bbox[(set*512+c)*2+1] = make_float4(hxx, hyy, hzz, 0.f);
}

// dmin^2 between row-block rb (64 rows = 4 chunks of row-set) and col chunk c
// (16 cols). blockIdx.x = s*128+rb (512), threadIdx.x = c (512).
__global__ __launch_bounds__(512) void ws_dmin(
    const float4* __restrict__ bbox, float* __restrict__ dmin)
{
  int b = blockIdx.x;
  int s = b >> 7, rb = b & 127;
  int c = threadIdx.x;
  int rset = (s == 0 || s == 2) ? 0 : 1;
  int cset = (s == 0 || s == 3) ? 1 : 0;
  float alx = 1e30f, aly = 1e30f, alz = 1e30f;
  float ahx = -1e30f, ahy = -1e30f, ahz = -1e30f;
  #pragma unroll
  for (int k = 0; k < 4; ++k) {
    float4 l = bbox[(rset*512 + 4*rb + k)*2];
    float4 h = bbox[(rset*512 + 4*rb + k)*2+1];
    alx = fminf(alx, l.x); aly = fminf(aly, l.y); alz = fminf(alz, l.z);
    ahx = fmaxf(ahx, h.x); ahy = fmaxf(ahy, h.y); ahz = fmaxf(ahz, h.z);
  }
  float4 bl = bbox[(cset*512 + c)*2], bh = bbox[(cset*512 + c)*2+1];
  float dx = fmaxf(0.f, fmaxf(alx - bh.x, bl.x - ahx));
  float dy = fmaxf(0.f, fmaxf(aly - bh.y, bl.y - ahy));
  float dz = fmaxf(0.f, fmaxf(alz - bh.z, bl.z - ahz));
  dmin[((size_t)b << 9) + c] = dx*dx + dy*dy + dz*dz;
}

// One phase. mode 0 (p==0): exact two-pass, full scan (seeds Mw).
// mode 1 (p>=1): single pass with M_est from previous phase's LSE (rescaled by
// rho) + geometric 16-col chunk skip. L = M_est + log2(sum 2^(w - M_est)) is
// exact for any in-range M_est.
// kind: 0 = assign (init), 1 = 0.5*(P+T) average, 2 = final (write Tfin)
__global__ __launch_bounds__(1024, 8) void ws_softmin(
    const float4* __restrict__ xp, const float4* __restrict__ yp,
    const float4* __restrict__ cps, float4* __restrict__ cpd,
    const float* __restrict__ dmin, const float* __restrict__ hmS,
    float* __restrict__ hmD, float* __restrict__ Mw,
    float* __restrict__ P, float* __restrict__ Tfin,
    float ce, float eps_ln2, float inv_next_ce, float rho, int kind, int mode)
{
  int b = blockIdx.x;
  int s = b >> 7;
  int rb = b & 127;
  int rowbase = rb << 6;
  int tid = threadIdx.x;
  int lane = tid & 63;
  int w = __builtin_amdgcn_readfirstlane(tid >> 6);

  const float4* rp = (s == 0 || s == 2) ? xp : yp;
  float4 rv = rp[rowbase + lane];
  float a0 = rv.x * ce, a1 = rv.y * ce, a2 = rv.z * ce;
  float hx = -0.5f * rv.w * ce;
  f2 A0 = {a0,a0}, A1 = {a1,a1}, A2 = {a2,a2};
  const float4* pw = cps + (size_t)s * NPTS + (w << 9);
  int row = rowbase + lane;

  __shared__ float lm[NWAVE][64];
  __shared__ float lss[NWAVE][64];
  float myMest = 0.f;

  if (mode == 0) {
    // ---- exact two-pass full scan ----
    f2 mA = {-3.0e38f, -3.0e38f}, mB = mA;
    #pragma unroll 2
    for (int pb = 0; pb < 256; pb += 2) {
      float4 P0 = pw[2*pb+0], Q0 = pw[2*pb+1];
      float4 P1 = pw[2*pb+2], Q1 = pw[2*pb+3];
      f2 X0={P0.x,P0.y}, Y0={P0.z,P0.w}, Z0={Q0.x,Q0.y}, W0={Q0.z,Q0.w};
      f2 X1={P1.x,P1.y}, Y1={P1.z,P1.w}, Z1={Q1.x,Q1.y}, W1={Q1.z,Q1.w};
      f2 t0 = ffma2(A2, Z0, W0); t0 = ffma2(A1, Y0, t0); t0 = ffma2(A0, X0, t0);
      f2 t1 = ffma2(A2, Z1, W1); t1 = ffma2(A1, Y1, t1); t1 = ffma2(A0, X1, t1);
      mA = fmax2(mA, t0); mB = fmax2(mB, t1);
    }
    f2 mAB = fmax2(mA, mB);
    float m = fmaxf(mAB.x, mAB.y);
    f2 M2 = {m, m};
    f2 sA = {0.f,0.f}, sB = {0.f,0.f};
    #pragma unroll 2
    for (int pb = 0; pb < 256; pb += 2) {
      float4 P0 = pw[2*pb+0], Q0 = pw[2*pb+1];
      float4 P1 = pw[2*pb+2], Q1 = pw[2*pb+3];
      f2 X0={P0.x,P0.y}, Y0={P0.z,P0.w}, Z0={Q0.x,Q0.y}, W0={Q0.z,Q0.w};
      f2 X1={P1.x,P1.y}, Y1={P1.z,P1.w}, Z1={Q1.x,Q1.y}, W1={Q1.z,Q1.w};
      f2 u0 = ffma2(A2, Z0, W0 - M2); u0 = ffma2(A1, Y0, u0); u0 = ffma2(A0, X0, u0);
      f2 u1 = ffma2(A2, Z1, W1 - M2); u1 = ffma2(A1, Y1, u1); u1 = ffma2(A0, X1, u1);
      f2 e0, e1;
      e0.x = fexp2(u0.x); e0.y = fexp2(u0.y);
      e1.x = fexp2(u1.x); e1.y = fexp2(u1.y);
      sA += e0; sB += e1;
    }
    f2 sAB = sA + sB;
    lm[w][lane] = m;
    lss[w][lane] = sAB.x + sAB.y;
  } else {
    // ---- single pass with M_est + geometric 16-col chunk skip ----
    float Mest = fmaf(Mw[s * NPTS + row] - LGAB2, rho, LGAB2);
    myMest = Mest;
    float thr = Mest - MARGIN;
    unsigned mask = 0u;
    #pragma unroll
    for (int c = 0; c < 32; ++c) {
      int gc = (w << 5) + c;
      float Wc = hmS[s*512 + gc] - 0.5f * ce * dmin[((size_t)b << 9) + gc];
      if (__ballot(Wc > thr)) mask |= (1u << c);
    }
    if (mask == 0u) mask = 0xFFFFFFFFu;   // safety: never drop everything
    mask = __builtin_amdgcn_readfirstlane(mask);
    float Mv = Mest - hx;
    f2 M2 = {Mv, Mv};
    f2 sA = {0.f,0.f}, sB = {0.f,0.f};
    for (int c = 0; c < 32; ++c) {
      if (!((mask >> c) & 1u)) continue;
      const float4* pc = pw + (c << 4);   // 16 cols = 8 pair-blocks
      #pragma unroll 4
      for (int pb = 0; pb < 8; ++pb) {
        float4 Pv = pc[2*pb], Qv = pc[2*pb+1];
        f2 X={Pv.x,Pv.y}, Y={Pv.z,Pv.w}, Z={Qv.x,Qv.y}, W={Qv.z,Qv.w};
        f2 u = ffma2(A2, Z, W - M2);
        u = ffma2(A1, Y, u);
        u = ffma2(A0, X, u);
        f2 e;
        e.x = fexp2(u.x); e.y = fexp2(u.y);
        if (pb & 1) sB += e; else sA += e;
      }
    }
    f2 sAB = sA + sB;
    lss[w][lane] = sAB.x + sAB.y;
  }
  __syncthreads();

  if (tid < 64) {
    float L;
    if (mode == 0) {
      float M = lm[0][lane];
      #pragma unroll
      for (int k = 1; k < NWAVE; ++k) M = fmaxf(M, lm[k][lane]);
      float S = 0.f;
      #pragma unroll
      for (int k = 0; k < NWAVE; ++k) S += lss[k][lane] * fexp2(lm[k][lane] - M);
      L = hx + M + log2f(S);
    } else {
      float S = 0.f;
      #pragma unroll
      for (int k = 0; k < NWAVE; ++k) S += lss[k][lane];
      S = fmaxf(S, 1e-30f);
      L = myMest + log2f(S);
    }
    float T = -eps_ln2 * L;
    Mw[s * NPTS + row] = L;
    if (kind == 2) {
      Tfin[s * NPTS + row] = T;
    } else {
      float* Pr = P + s * NPTS;
      float Pn = (kind == 0) ? T : 0.5f * (Pr[row] + T);
      Pr[row] = Pn;
      int dst = (s == 0) ? 1 : ((s == 1) ? 0 : s);
      float hy = LGAB2 + (Pn - 0.5f * rv.w) * inv_next_ce;
      float* cd = (float*)(cpd + (size_t)dst * NPTS);
      int p = row >> 1, sub = row & 1;
      cd[p*8+sub]   = rv.x;
      cd[p*8+2+sub] = rv.y;
      cd[p*8+4+sub] = rv.z;
      cd[p*8+6+sub] = hy;
      // per-16-col-chunk hhat-max for next phase: hhat = LGAB2 + Pn*ce_next
      float hN = fmaf(Pn, inv_next_ce, LGAB2);
      #pragma unroll
      for (int d = 8; d >= 1; d >>= 1) hN = fmaxf(hN, __shfl_xor(hN, d));
      if ((lane & 15) == 0) hmD[dst*512 + 4*rb + (lane >> 4)] = hN;
    }
  }
}

// loss = mean(f_fin - p_fin) + mean(g_fin - q_fin), fp64 accumulation
__global__ __launch_bounds__(256) void ws_reduce(
    const float* __restrict__ Tfin, float* __restrict__ out)
{
  int tid = threadIdx.x;
  double acc = 0.0;
  for (int i = tid; i < NPTS; i += 256) {
    acc += (double)Tfin[0*NPTS+i] - (double)Tfin[2*NPTS+i]
         + (double)Tfin[1*NPTS+i] - (double)Tfin[3*NPTS+i];
  }
  __shared__ double sd[256];
  sd[tid] = acc; __syncthreads();
  for (int k = 128; k > 0; k >>= 1) {
    if (tid < k) sd[tid] += sd[tid + k];
    __syncthreads();
  }
  if (tid == 0) out[0] = (float)(sd[0] / (double)NPTS);
}

extern "C" void kernel_launch(void* const* d_in, const int* in_sizes, int n_in,
                              void* d_out, int out_size, void* d_ws, size_t ws_size,
                              hipStream_t stream)
{
  const float* x = (const float*)d_in[0];
  const float* y = (const float*)d_in[1];
  float* out = (float*)d_out;

  char* wsp = (char*)d_ws;
  float4*   xp   = (float4*)wsp;   wsp += (size_t)NPTS * 16;
  float4*   yp   = (float4*)wsp;   wsp += (size_t)NPTS * 16;
  float4*   cpA  = (float4*)wsp;   wsp += (size_t)4 * NPTS * 16;
  float4*   cpB  = (float4*)wsp;   wsp += (size_t)4 * NPTS * 16;
  float*    P    = (float*)wsp;    wsp += (size_t)4 * NPTS * 4;
  float*    Tfin = (float*)wsp;    wsp += (size_t)4 * NPTS * 4;
  unsigned* sidx = (unsigned*)wsp; wsp += (size_t)2 * NPTS * 4;
  float*    Mw   = (float*)wsp;    wsp += (size_t)4 * NPTS * 4;
  float*    hmA  = (float*)wsp;    wsp += (size_t)4 * 512 * 4;
  float*    hmB  = (float*)wsp;    wsp += (size_t)4 * 512 * 4;
  float4*   bbox = (float4*)wsp;   wsp += (size_t)2 * 512 * 2 * 16;
  float*    dmin = (float*)wsp;    wsp += (size_t)4 * 128 * 512 * 4;

  // geomloss epsilon schedule, replicated in f64 exactly as Python does it
  double epss[64]; int n = 0;
  double e = 4.0;                       // DIAMETER**P
  const double r = 0.9 * 0.9;          // SCALING**P
  const double target = 0.01 * 0.01;   // BLUR**P
  while (e > target && n < 60) { epss[n++] = e; e *= r; }   // n == 51
  int NPH = n + 2;                     // init + n loop iters + final

  const double L2E  = 1.4426950408889634;
  const double LN2d = 0.6931471805599453;

  float feps[64];
  feps[0] = (float)epss[0];                       // init uses eps_sched[0]
  for (int p = 1; p <= n; ++p) feps[p] = (float)epss[p-1];
  feps[n+1] = 1e-4f;                              // eps_final

  float inv0ce = (float)(L2E / (double)feps[0]);
  ws_sort<<<2, 1024, 0, stream>>>(x, y, sidx);
  ws_setup<<<(NPTS + 255) / 256, 256, 0, stream>>>(x, y, sidx, xp, yp, cpA, inv0ce);
  ws_bbox<<<2, 512, 0, stream>>>(xp, yp, bbox);
  ws_dmin<<<512, 512, 0, stream>>>(bbox, dmin);

  for (int p = 0; p < NPH; ++p) {
    float epsf = feps[p];
    float ce = (float)(L2E / (double)epsf);
    float eps_ln2 = (float)((double)epsf * LN2d);
    float inv_next_ce = 0.f;
    if (p < NPH - 1) inv_next_ce = (float)(L2E / (double)feps[p+1]);
    float rho = 1.f;
    if (p >= 1) rho = (float)((double)feps[p-1] / (double)feps[p]);
    int kind = (p == 0) ? 0 : ((p == NPH - 1) ? 2 : 1);
    int mode = (p == 0) ? 0 : 1;
    const float4* src = (p & 1) ? cpB : cpA;
    float4*       dst = (p & 1) ? cpA : cpB;
    const float*  hmS = (p & 1) ? hmB : hmA;
    float*        hmD = (p & 1) ? hmA : hmB;
    ws_softmin<<<512, 1024, 0, stream>>>(xp, yp, src, dst, dmin, hmS, hmD,
                                         Mw, P, Tfin,
                                         ce, eps_ln2, inv_next_ce, rho, kind, mode);
  }

  ws_reduce<<<1, 256, 0, stream>>>(Tfin, out);
}

// Round 13
// 1923.192 us; speedup vs baseline: 2.2839x; 1.2699x over previous
//
#include <hip/hip_runtime.h>
#include <math.h>

#define NPTS 8192
#define LGAB2 (-13.0f)   // log2(1/8192)
#define NWAVE 16         // waves per block (1024 threads)
#define MARGIN 20.0f     // chunk skip margin vs M_est (exponent units, base 2)

typedef __attribute__((ext_vector_type(2))) float f2;

__device__ __forceinline__ float fexp2(float x){
#if __has_builtin(__builtin_amdgcn_exp2f)
  return __builtin_amdgcn_exp2f(x);
#else
  return exp2f(x);
#endif
}
__device__ __forceinline__ f2 ffma2(f2 a, f2 b, f2 c){
  return __builtin_elementwise_fma(a, b, c);   // v_pk_fma_f32
}
__device__ __forceinline__ f2 fmax2(f2 a, f2 b){
  return __builtin_elementwise_max(a, b);      // v_pk_max_f32
}

// ---------------- counting sort by 12-bit Morton key (16^3 cells) ------------
__global__ __launch_bounds__(1024) void ws_sort(
    const float* __restrict__ x, const float* __restrict__ y,
    unsigned* __restrict__ sidx)
{
  __shared__ unsigned hist[4096];
  __shared__ unsigned wtot[16];
  const float* p = blockIdx.x ? y : x;
  int tid = threadIdx.x;
  for (int i = tid; i < 4096; i += 1024) hist[i] = 0;
  __syncthreads();
  unsigned key[8];
  for (int t = 0; t < 8; ++t) {
    int i = tid + (t << 10);
    unsigned q0 = (unsigned)fminf(fmaxf(p[3*i  ] * 16.f, 0.f), 15.f);
    unsigned q1 = (unsigned)fminf(fmaxf(p[3*i+1] * 16.f, 0.f), 15.f);
    unsigned q2 = (unsigned)fminf(fmaxf(p[3*i+2] * 16.f, 0.f), 15.f);
    unsigned k = 0;
    #pragma unroll
    for (int bb = 0; bb < 4; ++bb)
      k |= (((q0 >> bb) & 1u) << (3*bb)) | (((q1 >> bb) & 1u) << (3*bb+1))
         | (((q2 >> bb) & 1u) << (3*bb+2));
    key[t] = k;
    atomicAdd(&hist[k], 1u);
  }
  __syncthreads();
  unsigned c0 = hist[4*tid], c1 = hist[4*tid+1], c2 = hist[4*tid+2], c3 = hist[4*tid+3];
  unsigned tsum = c0 + c1 + c2 + c3;
  int lane = tid & 63, wv = tid >> 6;
  unsigned inc = tsum;
  for (int d = 1; d < 64; d <<= 1) {
    unsigned o = __shfl_up(inc, d);
    if (lane >= d) inc += o;
  }
  if (lane == 63) wtot[wv] = inc;
  __syncthreads();
  unsigned woff = 0;
  for (int k = 0; k < wv; ++k) woff += wtot[k];
  unsigned base = woff + inc - tsum;
  hist[4*tid] = base; hist[4*tid+1] = base + c0;
  hist[4*tid+2] = base + c0 + c1; hist[4*tid+3] = base + c0 + c1 + c2;
  __syncthreads();
  for (int t = 0; t < 8; ++t) {
    int i = tid + (t << 10);
    unsigned pos = atomicAdd(&hist[key[t]], 1u);
    sidx[blockIdx.x * NPTS + pos] = i;
  }
}

// Column pack layout (sorted domain): per 2 columns, float4 (x0,x1,y0,y1) then
// float4 (z0,z1,w0,w1) where w = h-term (exponent units base 2).
__global__ __launch_bounds__(256) void ws_setup(
    const float* __restrict__ x, const float* __restrict__ y,
    const unsigned* __restrict__ sidx,
    float4* __restrict__ xp, float4* __restrict__ yp,
    float4* __restrict__ colpack, float inv0ce)
{
  int t = blockIdx.x * 256 + threadIdx.x;
  if (t >= NPTS) return;
  int ox = sidx[t], oy = sidx[NPTS + t];
  float x0 = x[3*ox], x1 = x[3*ox+1], x2 = x[3*ox+2];
  float xs = x0*x0 + x1*x1 + x2*x2;
  float y0 = y[3*oy], y1 = y[3*oy+1], y2 = y[3*oy+2];
  float ys = y0*y0 + y1*y1 + y2*y2;
  xp[t] = make_float4(x0,x1,x2,xs);
  yp[t] = make_float4(y0,y1,y2,ys);
  float hx = LGAB2 - 0.5f*xs*inv0ce;
  float hy = LGAB2 - 0.5f*ys*inv0ce;
  int p = t >> 1, sub = t & 1;
  {
    float* c0 = (float*)(colpack + 0*NPTS);
    c0[p*8+sub] = y0; c0[p*8+2+sub] = y1; c0[p*8+4+sub] = y2; c0[p*8+6+sub] = hy;
    float* c3 = (float*)(colpack + 3*NPTS);
    c3[p*8+sub] = y0; c3[p*8+2+sub] = y1; c3[p*8+4+sub] = y2; c3[p*8+6+sub] = hy;
  }
  {
    float* c1 = (float*)(colpack + 1*NPTS);
    c1[p*8+sub] = x0; c1[p*8+2+sub] = x1; c1[p*8+4+sub] = x2; c1[p*8+6+sub] = hx;
    float* c2 = (float*)(colpack + 2*NPTS);
    c2[p*8+sub] = x0; c2[p*8+2+sub] = x1; c2[p*8+4+sub] = x2; c2[p*8+6+sub] = hx;
  }
}

// 16-point chunk bounding boxes: bbox[(set*512+c)*2 + {0,1}] = lo/hi
__global__ __launch_bounds__(512) void ws_bbox(
    const float4* __restrict__ xp, const float4* __restrict__ yp,
    float4* __restrict__ bbox)
{
  int c = threadIdx.x;           // 0..511
  int set = blockIdx.x;
  const float4* pp = set ? yp : xp;
  float lx = 1e30f, ly = 1e30f, lz = 1e30f;
  float hxx = -1e30f, hyy = -1e30f, hzz = -1e30f;
  for (int k = 0; k < 16; ++k) {
    float4 v = pp[c*16+k];
    lx = fminf(lx, v.x); ly = fminf(ly, v.y); lz = fminf(lz, v.z);
    hxx = fmaxf(hxx, v.x); hyy = fmaxf(hyy, v.y); hzz = fmaxf(hzz, v.z);
  }
  bbox[(set*512+c)*2+0] = make_float4(lx, ly, lz, 0.f);
  bbox[(set*512+c)*2+1] = make_float4(hxx, hyy, hzz, 0.f);
}

// dmin^2 between row-block rb (64 rows = 4 chunks of row-set) and col chunk c
// (16 cols). blockIdx.x = s*128+rb (512), threadIdx.x = c (512).
__global__ __launch_bounds__(512) void ws_dmin(
    const float4* __restrict__ bbox, float* __restrict__ dmin)
{
  int b = blockIdx.x;
  int s = b >> 7, rb = b & 127;
  int c = threadIdx.x;
  int rset = (s == 0 || s == 2) ? 0 : 1;
  int cset = (s == 0 || s == 3) ? 1 : 0;
  float alx = 1e30f, aly = 1e30f, alz = 1e30f;
  float ahx = -1e30f, ahy = -1e30f, ahz = -1e30f;
  #pragma unroll
  for (int k = 0; k < 4; ++k) {
    float4 l = bbox[(rset*512 + 4*rb + k)*2];
    float4 h = bbox[(rset*512 + 4*rb + k)*2+1];
    alx = fminf(alx, l.x); aly = fminf(aly, l.y); alz = fminf(alz, l.z);
    ahx = fmaxf(ahx, h.x); ahy = fmaxf(ahy, h.y); ahz = fmaxf(ahz, h.z);
  }
  float4 bl = bbox[(cset*512 + c)*2], bh = bbox[(cset*512 + c)*2+1];
  float dx = fmaxf(0.f, fmaxf(alx - bh.x, bl.x - ahx));
  float dy = fmaxf(0.f, fmaxf(aly - bh.y, bl.y - ahy));
  float dz = fmaxf(0.f, fmaxf(alz - bh.z, bl.z - ahz));
  dmin[((size_t)b << 9) + c] = dx*dx + dy*dy + dz*dz;
}

// One phase. mode 0 (p==0): exact two-pass, full scan (seeds Mw).
// mode 1 (p>=1): single pass with M_est from previous phase's LSE (rescaled by
// rho) + geometric 16-col chunk skip. L = M_est + log2(sum 2^(w - M_est)) is
// exact for any in-range M_est.
// kind: 0 = assign (init), 1 = 0.5*(P+T) average, 2 = final (write Tfin)
__global__ __launch_bounds__(1024, 8) void ws_softmin(
    const float4* __restrict__ xp, const float4* __restrict__ yp,
    const float4* __restrict__ cps, float4* __restrict__ cpd,
    const float* __restrict__ dmin, const float* __restrict__ hmS,
    float* __restrict__ hmD, float* __restrict__ Mw,
    float* __restrict__ P, float* __restrict__ Tfin,
    float ce, float eps_ln2, float inv_next_ce, float rho, int kind, int mode)
{
  int b = blockIdx.x;
  int s = b >> 7;
  int rb = b & 127;
  int rowbase = rb << 6;
  int tid = threadIdx.x;
  int lane = tid & 63;
  int w = __builtin_amdgcn_readfirstlane(tid >> 6);

  const float4* rp = (s == 0 || s == 2) ? xp : yp;
  float4 rv = rp[rowbase + lane];
  float a0 = rv.x * ce, a1 = rv.y * ce, a2 = rv.z * ce;
  float hx = -0.5f * rv.w * ce;
  f2 A0 = {a0,a0}, A1 = {a1,a1}, A2 = {a2,a2};
  const float4* pw = cps + (size_t)s * NPTS + (w << 9);
  int row = rowbase + lane;

  __shared__ float lm[NWAVE][64];
  __shared__ float lss[NWAVE][64];
  float myMest = 0.f;

  if (mode == 0) {
    // ---- exact two-pass full scan ----
    f2 mA = {-3.0e38f, -3.0e38f}, mB = mA;
    #pragma unroll 2
    for (int pb = 0; pb < 256; pb += 2) {
      float4 P0 = pw[2*pb+0], Q0 = pw[2*pb+1];
      float4 P1 = pw[2*pb+2], Q1 = pw[2*pb+3];
      f2 X0={P0.x,P0.y}, Y0={P0.z,P0.w}, Z0={Q0.x,Q0.y}, W0={Q0.z,Q0.w};
      f2 X1={P1.x,P1.y}, Y1={P1.z,P1.w}, Z1={Q1.x,Q1.y}, W1={Q1.z,Q1.w};
      f2 t0 = ffma2(A2, Z0, W0); t0 = ffma2(A1, Y0, t0); t0 = ffma2(A0, X0, t0);
      f2 t1 = ffma2(A2, Z1, W1); t1 = ffma2(A1, Y1, t1); t1 = ffma2(A0, X1, t1);
      mA = fmax2(mA, t0); mB = fmax2(mB, t1);
    }
    f2 mAB = fmax2(mA, mB);
    float m = fmaxf(mAB.x, mAB.y);
    f2 M2 = {m, m};
    f2 sA = {0.f,0.f}, sB = {0.f,0.f};
    #pragma unroll 2
    for (int pb = 0; pb < 256; pb += 2) {
      float4 P0 = pw[2*pb+0], Q0 = pw[2*pb+1];
      float4 P1 = pw[2*pb+2], Q1 = pw[2*pb+3];
      f2 X0={P0.x,P0.y}, Y0={P0.z,P0.w}, Z0={Q0.x,Q0.y}, W0={Q0.z,Q0.w};
      f2 X1={P1.x,P1.y}, Y1={P1.z,P1.w}, Z1={Q1.x,Q1.y}, W1={Q1.z,Q1.w};
      f2 u0 = ffma2(A2, Z0, W0 - M2); u0 = ffma2(A1, Y0, u0); u0 = ffma2(A0, X0, u0);
      f2 u1 = ffma2(A2, Z1, W1 - M2); u1 = ffma2(A1, Y1, u1); u1 = ffma2(A0, X1, u1);
      f2 e0, e1;
      e0.x = fexp2(u0.x); e0.y = fexp2(u0.y);
      e1.x = fexp2(u1.x); e1.y = fexp2(u1.y);
      sA += e0; sB += e1;
    }
    f2 sAB = sA + sB;
    lm[w][lane] = m;
    lss[w][lane] = sAB.x + sAB.y;
  } else {
    // ---- single pass with M_est + geometric 16-col chunk skip ----
    float Mest = fmaf(Mw[s * NPTS + row] - LGAB2, rho, LGAB2);
    myMest = Mest;
    float thr = Mest - MARGIN;
    unsigned mask = 0u;
    #pragma unroll
    for (int c = 0; c < 32; ++c) {
      int gc = (w << 5) + c;
      float Wc = hmS[s*512 + gc] - 0.5f * ce * dmin[((size_t)b << 9) + gc];
      if (__ballot(Wc > thr)) mask |= (1u << c);
    }
    if (mask == 0u) mask = 0xFFFFFFFFu;   // safety: never drop everything
    mask = __builtin_amdgcn_readfirstlane(mask);
    float Mv = Mest - hx;
    f2 M2 = {Mv, Mv};
    f2 sA = {0.f,0.f}, sB = {0.f,0.f};
    for (int c = 0; c < 32; ++c) {
      if (!((mask >> c) & 1u)) continue;
      const float4* pc = pw + (c << 4);   // 16 cols = 8 pair-blocks
      #pragma unroll 4
      for (int pb = 0; pb < 8; ++pb) {
        float4 Pv = pc[2*pb], Qv = pc[2*pb+1];
        f2 X={Pv.x,Pv.y}, Y={Pv.z,Pv.w}, Z={Qv.x,Qv.y}, W={Qv.z,Qv.w};
        f2 u = ffma2(A2, Z, W - M2);
        u = ffma2(A1, Y, u);
        u = ffma2(A0, X, u);
        f2 e;
        e.x = fexp2(u.x); e.y = fexp2(u.y);
        if (pb & 1) sB += e; else sA += e;
      }
    }
    f2 sAB = sA + sB;
    lss[w][lane] = sAB.x + sAB.y;
  }
  __syncthreads();

  if (tid < 64) {
    float L;
    if (mode == 0) {
      float M = lm[0][lane];
      #pragma unroll
      for (int k = 1; k < NWAVE; ++k) M = fmaxf(M, lm[k][lane]);
      float S = 0.f;
      #pragma unroll
      for (int k = 0; k < NWAVE; ++k) S += lss[k][lane] * fexp2(lm[k][lane] - M);
      L = hx + M + log2f(S);
    } else {
      float S = 0.f;
      #pragma unroll
      for (int k = 0; k < NWAVE; ++k) S += lss[k][lane];
      S = fmaxf(S, 1e-30f);
      L = myMest + log2f(S);
    }
    float T = -eps_ln2 * L;
    Mw[s * NPTS + row] = L;
    if (kind == 2) {
      Tfin[s * NPTS + row] = T;
    } else {
      float* Pr = P + s * NPTS;
      float Pn = (kind == 0) ? T : 0.5f * (Pr[row] + T);
      Pr[row] = Pn;
      int dst = (s == 0) ? 1 : ((s == 1) ? 0 : s);
      float hy = LGAB2 + (Pn - 0.5f * rv.w) * inv_next_ce;
      float* cd = (float*)(cpd + (size_t)dst * NPTS);
      int p = row >> 1, sub = row & 1;
      cd[p*8+sub]   = rv.x;
      cd[p*8+2+sub] = rv.y;
      cd[p*8+4+sub] = rv.z;
      cd[p*8+6+sub] = hy;
      // per-16-col-chunk hhat-max for next phase: hhat = LGAB2 + Pn*ce_next
      float hN = fmaf(Pn, inv_next_ce, LGAB2);
      #pragma unroll
      for (int d = 8; d >= 1; d >>= 1) hN = fmaxf(hN, __shfl_xor(hN, d));
      if ((lane & 15) == 0) hmD[dst*512 + 4*rb + (lane >> 4)] = hN;
    }
  }
}

// loss = mean(f_fin - p_fin) + mean(g_fin - q_fin), fp64 accumulation
__global__ __launch_bounds__(256) void ws_reduce(
    const float* __restrict__ Tfin, float* __restrict__ out)
{
  int tid = threadIdx.x;
  double acc = 0.0;
  for (int i = tid; i < NPTS; i += 256) {
    acc += (double)Tfin[0*NPTS+i] - (double)Tfin[2*NPTS+i]
         + (double)Tfin[1*NPTS+i] - (double)Tfin[3*NPTS+i];
  }
  __shared__ double sd[256];
  sd[tid] = acc; __syncthreads();
  for (int k = 128; k > 0; k >>= 1) {
    if (tid < k) sd[tid] += sd[tid + k];
    __syncthreads();
  }
  if (tid == 0) out[0] = (float)(sd[0] / (double)NPTS);
}

extern "C" void kernel_launch(void* const* d_in, const int* in_sizes, int n_in,
                              void* d_out, int out_size, void* d_ws, size_t ws_size,
                              hipStream_t stream)
{
  const float* x = (const float*)d_in[0];
  const float* y = (const float*)d_in[1];
  float* out = (float*)d_out;

  char* wsp = (char*)d_ws;
  float4*   xp   = (float4*)wsp;   wsp += (size_t)NPTS * 16;
  float4*   yp   = (float4*)wsp;   wsp += (size_t)NPTS * 16;
  float4*   cpA  = (float4*)wsp;   wsp += (size_t)4 * NPTS * 16;
  float4*   cpB  = (float4*)wsp;   wsp += (size_t)4 * NPTS * 16;
  float*    P    = (float*)wsp;    wsp += (size_t)4 * NPTS * 4;
  float*    Tfin = (float*)wsp;    wsp += (size_t)4 * NPTS * 4;
  unsigned* sidx = (unsigned*)wsp; wsp += (size_t)2 * NPTS * 4;
  float*    Mw   = (float*)wsp;    wsp += (size_t)4 * NPTS * 4;
  float*    hmA  = (float*)wsp;    wsp += (size_t)4 * 512 * 4;
  float*    hmB  = (float*)wsp;    wsp += (size_t)4 * 512 * 4;
  float4*   bbox = (float4*)wsp;   wsp += (size_t)2 * 512 * 2 * 16;
  float*    dmin = (float*)wsp;    wsp += (size_t)4 * 128 * 512 * 4;

  // geomloss epsilon schedule (f64, exactly as Python builds it)
  double epss[64]; int n = 0;
  double e = 4.0;                       // DIAMETER**P
  const double r = 0.9 * 0.9;          // SCALING**P
  const double target = 0.01 * 0.01;   // BLUR**P
  while (e > target && n < 60) { epss[n++] = e; e *= r; }   // n == 51

  // Phase pruning: stride-2 through the loop while eps > 0.04 (errors there
  // are damped ~0.5x/step by the 30+ remaining dense steps + envelope
  // property makes the loss first-order insensitive to dual error); keep the
  // dense tail and the final extrapolation exact.
  float feps[64]; int NPH = 0;
  feps[NPH++] = (float)epss[0];        // init phase at eps_sched[0]
  {
    int k = 0;
    while (k < n) {
      feps[NPH++] = (float)epss[k];
      k += (epss[k] > 0.04) ? 2 : 1;
    }
  }
  feps[NPH++] = 1e-4f;                 // eps_final

  const double L2E  = 1.4426950408889634;
  const double LN2d = 0.6931471805599453;

  float inv0ce = (float)(L2E / (double)feps[0]);
  ws_sort<<<2, 1024, 0, stream>>>(x, y, sidx);
  ws_setup<<<(NPTS + 255) / 256, 256, 0, stream>>>(x, y, sidx, xp, yp, cpA, inv0ce);
  ws_bbox<<<2, 512, 0, stream>>>(xp, yp, bbox);
  ws_dmin<<<512, 512, 0, stream>>>(bbox, dmin);

  for (int p = 0; p < NPH; ++p) {
    float epsf = feps[p];
    float ce = (float)(L2E / (double)epsf);
    float eps_ln2 = (float)((double)epsf * LN2d);
    float inv_next_ce = 0.f;
    if (p < NPH - 1) inv_next_ce = (float)(L2E / (double)feps[p+1]);
    float rho = 1.f;
    if (p >= 1) rho = (float)((double)feps[p-1] / (double)feps[p]);
    int kind = (p == 0) ? 0 : ((p == NPH - 1) ? 2 : 1);
    int mode = (p == 0) ? 0 : 1;
    const float4* src = (p & 1) ? cpB : cpA;
    float4*       dst = (p & 1) ? cpA : cpB;
    const float*  hmS = (p & 1) ? hmB : hmA;
    float*        hmD = (p & 1) ? hmA : hmB;
    ws_softmin<<<512, 1024, 0, stream>>>(xp, yp, src, dst, dmin, hmS, hmD,
                                         Mw, P, Tfin,
                                         ce, eps_ln2, inv_next_ce, rho, kind, mode);
  }

  ws_reduce<<<1, 256, 0, stream>>>(Tfin, out);
}

// Round 15
// 1680.844 us; speedup vs baseline: 2.6131x; 1.1442x over previous
//
#include <hip/hip_runtime.h>
#include <math.h>

#define NPTS 8192
#define LGAB2 (-13.0f)   // log2(1/8192)
#define NWAVE 16         // waves per block (1024 threads)
#define MARGIN 20.0f     // chunk skip margin vs M_est (exponent units, base 2)

typedef __attribute__((ext_vector_type(2))) float f2;

__device__ __forceinline__ float fexp2(float x){
#if __has_builtin(__builtin_amdgcn_exp2f)
  return __builtin_amdgcn_exp2f(x);
#else
  return exp2f(x);
#endif
}
__device__ __forceinline__ f2 ffma2(f2 a, f2 b, f2 c){
  return __builtin_elementwise_fma(a, b, c);   // v_pk_fma_f32
}
__device__ __forceinline__ f2 fmax2(f2 a, f2 b){
  return __builtin_elementwise_max(a, b);      // v_pk_max_f32
}

// ---------------- counting sort by 12-bit Morton key (16^3 cells) ------------
__global__ __launch_bounds__(1024) void ws_sort(
    const float* __restrict__ x, const float* __restrict__ y,
    unsigned* __restrict__ sidx)
{
  __shared__ unsigned hist[4096];
  __shared__ unsigned wtot[16];
  const float* p = blockIdx.x ? y : x;
  int tid = threadIdx.x;
  for (int i = tid; i < 4096; i += 1024) hist[i] = 0;
  __syncthreads();
  unsigned key[8];
  for (int t = 0; t < 8; ++t) {
    int i = tid + (t << 10);
    unsigned q0 = (unsigned)fminf(fmaxf(p[3*i  ] * 16.f, 0.f), 15.f);
    unsigned q1 = (unsigned)fminf(fmaxf(p[3*i+1] * 16.f, 0.f), 15.f);
    unsigned q2 = (unsigned)fminf(fmaxf(p[3*i+2] * 16.f, 0.f), 15.f);
    unsigned k = 0;
    #pragma unroll
    for (int bb = 0; bb < 4; ++bb)
      k |= (((q0 >> bb) & 1u) << (3*bb)) | (((q1 >> bb) & 1u) << (3*bb+1))
         | (((q2 >> bb) & 1u) << (3*bb+2));
    key[t] = k;
    atomicAdd(&hist[k], 1u);
  }
  __syncthreads();
  unsigned c0 = hist[4*tid], c1 = hist[4*tid+1], c2 = hist[4*tid+2], c3 = hist[4*tid+3];
  unsigned tsum = c0 + c1 + c2 + c3;
  int lane = tid & 63, wv = tid >> 6;
  unsigned inc = tsum;
  for (int d = 1; d < 64; d <<= 1) {
    unsigned o = __shfl_up(inc, d);
    if (lane >= d) inc += o;
  }
  if (lane == 63) wtot[wv] = inc;
  __syncthreads();
  unsigned woff = 0;
  for (int k = 0; k < wv; ++k) woff += wtot[k];
  unsigned base = woff + inc - tsum;
  hist[4*tid] = base; hist[4*tid+1] = base + c0;
  hist[4*tid+2] = base + c0 + c1; hist[4*tid+3] = base + c0 + c1 + c2;
  __syncthreads();
  for (int t = 0; t < 8; ++t) {
    int i = tid + (t << 10);
    unsigned pos = atomicAdd(&hist[key[t]], 1u);
    sidx[blockIdx.x * NPTS + pos] = i;
  }
}

// Fine column pack (sorted domain): per 2 columns, float4 (x0,x1,y0,y1) then
// float4 (z0,z1,w0,w1) where w = h-term (exponent units base 2).
// Coarse pack (after 4*NPTS float4): 512 centroid-columns per slot, same
// pair-transposed layout with w = H_c = log2 sum_cluster 2^h.
__global__ __launch_bounds__(256) void ws_setup(
    const float* __restrict__ x, const float* __restrict__ y,
    const unsigned* __restrict__ sidx,
    float4* __restrict__ xp, float4* __restrict__ yp,
    float4* __restrict__ colpack, float inv0ce)
{
  int t = blockIdx.x * 256 + threadIdx.x;
  if (t >= NPTS) return;
  int ox = sidx[t], oy = sidx[NPTS + t];
  float x0 = x[3*ox], x1 = x[3*ox+1], x2 = x[3*ox+2];
  float xs = x0*x0 + x1*x1 + x2*x2;
  float y0 = y[3*oy], y1 = y[3*oy+1], y2 = y[3*oy+2];
  float ys = y0*y0 + y1*y1 + y2*y2;
  xp[t] = make_float4(x0,x1,x2,xs);
  yp[t] = make_float4(y0,y1,y2,ys);
  float hx = LGAB2 - 0.5f*xs*inv0ce;
  float hy = LGAB2 - 0.5f*ys*inv0ce;
  int p = t >> 1, sub = t & 1;
  {
    float* c0 = (float*)(colpack + 0*NPTS);
    c0[p*8+sub] = y0; c0[p*8+2+sub] = y1; c0[p*8+4+sub] = y2; c0[p*8+6+sub] = hy;
    float* c3 = (float*)(colpack + 3*NPTS);
    c3[p*8+sub] = y0; c3[p*8+2+sub] = y1; c3[p*8+4+sub] = y2; c3[p*8+6+sub] = hy;
  }
  {
    float* c1 = (float*)(colpack + 1*NPTS);
    c1[p*8+sub] = x0; c1[p*8+2+sub] = x1; c1[p*8+4+sub] = x2; c1[p*8+6+sub] = hx;
    float* c2 = (float*)(colpack + 2*NPTS);
    c2[p*8+sub] = x0; c2[p*8+2+sub] = x1; c2[p*8+4+sub] = x2; c2[p*8+6+sub] = hx;
  }
}

// Per-16-point cluster: bbox, centroid, and initial coarse pack (duals = 0).
__global__ __launch_bounds__(512) void ws_bbox(
    const float4* __restrict__ xp, const float4* __restrict__ yp,
    float4* __restrict__ bbox, float4* __restrict__ cent,
    float4* __restrict__ cc0, float inv0ce)
{
  int c = threadIdx.x;           // 0..511
  int set = blockIdx.x;
  const float4* pp = set ? yp : xp;
  float lx = 1e30f, ly = 1e30f, lz = 1e30f;
  float hxx = -1e30f, hyy = -1e30f, hzz = -1e30f;
  float sx = 0.f, sy = 0.f, sz = 0.f, hm = -3.0e38f;
  float hv[16];
  for (int k = 0; k < 16; ++k) {
    float4 v = pp[c*16+k];
    lx = fminf(lx, v.x); ly = fminf(ly, v.y); lz = fminf(lz, v.z);
    hxx = fmaxf(hxx, v.x); hyy = fmaxf(hyy, v.y); hzz = fmaxf(hzz, v.z);
    sx += v.x; sy += v.y; sz += v.z;
    float h = LGAB2 - 0.5f * v.w * inv0ce;
    hv[k] = h; hm = fmaxf(hm, h);
  }
  float se = 0.f;
  for (int k = 0; k < 16; ++k) se += fexp2(hv[k] - hm);
  float H = hm + log2f(se);
  bbox[(set*512+c)*2+0] = make_float4(lx, ly, lz, 0.f);
  bbox[(set*512+c)*2+1] = make_float4(hxx, hyy, hzz, 0.f);
  float cx = sx * 0.0625f, cy = sy * 0.0625f, cz = sz * 0.0625f;
  cent[set*512+c] = make_float4(cx, cy, cz, 0.f);
  int s1 = set ? 0 : 1, s2 = set ? 3 : 2;   // slots using this set as columns
  int p = c >> 1, sub = c & 1;
  float* a = (float*)(cc0 + (size_t)s1 * 512);
  a[p*8+sub] = cx; a[p*8+2+sub] = cy; a[p*8+4+sub] = cz; a[p*8+6+sub] = H;
  float* bq = (float*)(cc0 + (size_t)s2 * 512);
  bq[p*8+sub] = cx; bq[p*8+2+sub] = cy; bq[p*8+4+sub] = cz; bq[p*8+6+sub] = H;
}

// dmin^2 between row-block rb (64 rows = 4 chunks of row-set) and col chunk c
__global__ __launch_bounds__(512) void ws_dmin(
    const float4* __restrict__ bbox, float* __restrict__ dmin)
{
  int b = blockIdx.x;
  int s = b >> 7, rb = b & 127;
  int c = threadIdx.x;
  int rset = (s == 0 || s == 2) ? 0 : 1;
  int cset = (s == 0 || s == 3) ? 1 : 0;
  float alx = 1e30f, aly = 1e30f, alz = 1e30f;
  float ahx = -1e30f, ahy = -1e30f, ahz = -1e30f;
  #pragma unroll
  for (int k = 0; k < 4; ++k) {
    float4 l = bbox[(rset*512 + 4*rb + k)*2];
    float4 h = bbox[(rset*512 + 4*rb + k)*2+1];
    alx = fminf(alx, l.x); aly = fminf(aly, l.y); alz = fminf(alz, l.z);
    ahx = fmaxf(ahx, h.x); ahy = fmaxf(ahy, h.y); ahz = fmaxf(ahz, h.z);
  }
  float4 bl = bbox[(cset*512 + c)*2], bh = bbox[(cset*512 + c)*2+1];
  float dx = fmaxf(0.f, fmaxf(alx - bh.x, bl.x - ahx));
  float dy = fmaxf(0.f, fmaxf(aly - bh.y, bl.y - ahy));
  float dz = fmaxf(0.f, fmaxf(alz - bh.z, bl.z - ahz));
  dmin[((size_t)b << 9) + c] = dx*dx + dy*dy + dz*dz;
}

// One phase. mode 0: fine exact two-pass (fallback, unused in current plan).
// mode 1: fine single pass, M_est from prev LSE (x rho) + geometric chunk skip.
// mode 2: coarse exact two-pass over 512 centroid-columns (eps > 0.15 regime).
// kind: 0 = assign (init), 1 = 0.5*(P+T) average, 2 = final (write Tfin)
__global__ __launch_bounds__(1024, 8) void ws_softmin(
    const float4* __restrict__ xp, const float4* __restrict__ yp,
    const float4* __restrict__ cps, float4* __restrict__ cpd,
    const float* __restrict__ dmin, const float* __restrict__ hmS,
    float* __restrict__ hmD, float* __restrict__ Mw,
    const float4* __restrict__ cent,
    float* __restrict__ P, float* __restrict__ Tfin,
    float ce, float eps_ln2, float inv_next_ce, float rho, int kind, int mode)
{
  int b = blockIdx.x;
  int s = b >> 7;
  int rb = b & 127;
  int rowbase = rb << 6;
  int tid = threadIdx.x;
  int lane = tid & 63;
  int w = __builtin_amdgcn_readfirstlane(tid >> 6);

  int rset = (s == 0 || s == 2) ? 0 : 1;
  const float4* rp = rset ? yp : xp;
  float4 rv = rp[rowbase + lane];
  float a0 = rv.x * ce, a1 = rv.y * ce, a2 = rv.z * ce;
  float hx = -0.5f * rv.w * ce;
  f2 A0 = {a0,a0}, A1 = {a1,a1}, A2 = {a2,a2};
  const float4* pw = cps + (size_t)s * NPTS + (w << 9);
  int row = rowbase + lane;

  __shared__ float lm[NWAVE][64];
  __shared__ float lss[NWAVE][64];
  float myMest = 0.f;

  if (mode == 0) {
    // ---- fine exact two-pass full scan ----
    f2 mA = {-3.0e38f, -3.0e38f}, mB = mA;
    #pragma unroll 2
    for (int pb = 0; pb < 256; pb += 2) {
      float4 P0 = pw[2*pb+0], Q0 = pw[2*pb+1];
      float4 P1 = pw[2*pb+2], Q1 = pw[2*pb+3];
      f2 X0={P0.x,P0.y}, Y0={P0.z,P0.w}, Z0={Q0.x,Q0.y}, W0={Q0.z,Q0.w};
      f2 X1={P1.x,P1.y}, Y1={P1.z,P1.w}, Z1={Q1.x,Q1.y}, W1={Q1.z,Q1.w};
      f2 t0 = ffma2(A2, Z0, W0); t0 = ffma2(A1, Y0, t0); t0 = ffma2(A0, X0, t0);
      f2 t1 = ffma2(A2, Z1, W1); t1 = ffma2(A1, Y1, t1); t1 = ffma2(A0, X1, t1);
      mA = fmax2(mA, t0); mB = fmax2(mB, t1);
    }
    f2 mAB = fmax2(mA, mB);
    float m = fmaxf(mAB.x, mAB.y);
    f2 M2 = {m, m};
    f2 sA = {0.f,0.f}, sB = {0.f,0.f};
    #pragma unroll 2
    for (int pb = 0; pb < 256; pb += 2) {
      float4 P0 = pw[2*pb+0], Q0 = pw[2*pb+1];
      float4 P1 = pw[2*pb+2], Q1 = pw[2*pb+3];
      f2 X0={P0.x,P0.y}, Y0={P0.z,P0.w}, Z0={Q0.x,Q0.y}, W0={Q0.z,Q0.w};
      f2 X1={P1.x,P1.y}, Y1={P1.z,P1.w}, Z1={Q1.x,Q1.y}, W1={Q1.z,Q1.w};
      f2 u0 = ffma2(A2, Z0, W0 - M2); u0 = ffma2(A1, Y0, u0); u0 = ffma2(A0, X0, u0);
      f2 u1 = ffma2(A2, Z1, W1 - M2); u1 = ffma2(A1, Y1, u1); u1 = ffma2(A0, X1, u1);
      f2 e0, e1;
      e0.x = fexp2(u0.x); e0.y = fexp2(u0.y);
      e1.x = fexp2(u1.x); e1.y = fexp2(u1.y);
      sA += e0; sB += e1;
    }
    f2 sAB = sA + sB;
    lm[w][lane] = m;
    lss[w][lane] = sAB.x + sAB.y;
  } else if (mode == 2) {
    // ---- coarse exact two-pass: 512 centroid-cols, 32 per wave ----
    const float4* pwc = cps + 4*(size_t)NPTS + (size_t)s*512 + (w << 5);
    f2 mA = {-3.0e38f, -3.0e38f}, mB = mA;
    #pragma unroll
    for (int pb = 0; pb < 16; pb += 2) {
      float4 P0 = pwc[2*pb+0], Q0 = pwc[2*pb+1];
      float4 P1 = pwc[2*pb+2], Q1 = pwc[2*pb+3];
      f2 X0={P0.x,P0.y}, Y0={P0.z,P0.w}, Z0={Q0.x,Q0.y}, W0={Q0.z,Q0.w};
      f2 X1={P1.x,P1.y}, Y1={P1.z,P1.w}, Z1={Q1.x,Q1.y}, W1={Q1.z,Q1.w};
      f2 t0 = ffma2(A2, Z0, W0); t0 = ffma2(A1, Y0, t0); t0 = ffma2(A0, X0, t0);
      f2 t1 = ffma2(A2, Z1, W1); t1 = ffma2(A1, Y1, t1); t1 = ffma2(A0, X1, t1);
      mA = fmax2(mA, t0); mB = fmax2(mB, t1);
    }
    f2 mAB = fmax2(mA, mB);
    float m = fmaxf(mAB.x, mAB.y);
    f2 M2 = {m, m};
    f2 sA = {0.f,0.f}, sB = {0.f,0.f};
    #pragma unroll
    for (int pb = 0; pb < 16; pb += 2) {
      float4 P0 = pwc[2*pb+0], Q0 = pwc[2*pb+1];
      float4 P1 = pwc[2*pb+2], Q1 = pwc[2*pb+3];
      f2 X0={P0.x,P0.y}, Y0={P0.z,P0.w}, Z0={Q0.x,Q0.y}, W0={Q0.z,Q0.w};
      f2 X1={P1.x,P1.y}, Y1={P1.z,P1.w}, Z1={Q1.x,Q1.y}, W1={Q1.z,Q1.w};
      f2 u0 = ffma2(A2, Z0, W0 - M2); u0 = ffma2(A1, Y0, u0); u0 = ffma2(A0, X0, u0);
      f2 u1 = ffma2(A2, Z1, W1 - M2); u1 = ffma2(A1, Y1, u1); u1 = ffma2(A0, X1, u1);
      f2 e0, e1;
      e0.x = fexp2(u0.x); e0.y = fexp2(u0.y);
      e1.x = fexp2(u1.x); e1.y = fexp2(u1.y);
      sA += e0; sB += e1;
    }
    f2 sAB = sA + sB;
    lm[w][lane] = m;
    lss[w][lane] = sAB.x + sAB.y;
  } else {
    // ---- fine single pass with M_est + geometric 16-col chunk skip ----
    float Mest = fmaf(Mw[s * NPTS + row] - LGAB2, rho, LGAB2);
    myMest = Mest;
    float thr = Mest - MARGIN;
    unsigned mask = 0u;
    #pragma unroll
    for (int c = 0; c < 32; ++c) {
      int gc = (w << 5) + c;
      float Wc = hmS[s*512 + gc] - 0.5f * ce * dmin[((size_t)b << 9) + gc];
      if (__ballot(Wc > thr)) mask |= (1u << c);
    }
    if (mask == 0u) mask = 0xFFFFFFFFu;   // safety: never drop everything
    mask = __builtin_amdgcn_readfirstlane(mask);
    float Mv = Mest - hx;
    f2 M2 = {Mv, Mv};
    f2 sA = {0.f,0.f}, sB = {0.f,0.f};
    for (int c = 0; c < 32; ++c) {
      if (!((mask >> c) & 1u)) continue;
      const float4* pc = pw + (c << 4);   // 16 cols = 8 pair-blocks
      #pragma unroll 4
      for (int pb = 0; pb < 8; ++pb) {
        float4 Pv = pc[2*pb], Qv = pc[2*pb+1];
        f2 X={Pv.x,Pv.y}, Y={Pv.z,Pv.w}, Z={Qv.x,Qv.y}, W={Qv.z,Qv.w};
        f2 u = ffma2(A2, Z, W - M2);
        u = ffma2(A1, Y, u);
        u = ffma2(A0, X, u);
        f2 e;
        e.x = fexp2(u.x); e.y = fexp2(u.y);
        if (pb & 1) sB += e; else sA += e;
      }
    }
    f2 sAB = sA + sB;
    lss[w][lane] = sAB.x + sAB.y;
  }
  __syncthreads();

  if (tid < 64) {
    float L;
    if (mode == 1) {
      float S = 0.f;
      #pragma unroll
      for (int k = 0; k < NWAVE; ++k) S += lss[k][lane];
      S = fmaxf(S, 1e-30f);
      L = myMest + log2f(S);
    } else {
      float M = lm[0][lane];
      #pragma unroll
      for (int k = 1; k < NWAVE; ++k) M = fmaxf(M, lm[k][lane]);
      float S = 0.f;
      #pragma unroll
      for (int k = 0; k < NWAVE; ++k) S += lss[k][lane] * fexp2(lm[k][lane] - M);
      L = hx + M + log2f(S);
    }
    float T = -eps_ln2 * L;
    Mw[s * NPTS + row] = L;
    if (kind == 2) {
      Tfin[s * NPTS + row] = T;
    } else {
      float* Pr = P + s * NPTS;
      float Pn = (kind == 0) ? T : 0.5f * (Pr[row] + T);
      Pr[row] = Pn;
      int dst = (s == 0) ? 1 : ((s == 1) ? 0 : s);
      float hy = LGAB2 + (Pn - 0.5f * rv.w) * inv_next_ce;
      float* cd = (float*)(cpd + (size_t)dst * NPTS);
      int p = row >> 1, sub = row & 1;
      cd[p*8+sub]   = rv.x;
      cd[p*8+2+sub] = rv.y;
      cd[p*8+4+sub] = rv.z;
      cd[p*8+6+sub] = hy;
      // Skip-bound table: MUST be LGAB2 + Pn*ce (upper bound of the
      // dmin-decomposed contribution LGAB2 + Pn*ce - 0.5|x-y|^2*ce).
      // R14 used max(h_j) = max(LGAB2 + (Pn-0.5|y|^2)*ce) here -> NOT a
      // valid bound (the -0.5|y|^2 cancels against the x.y cross term);
      // chunks holding the true max got skipped -> inf/NaN cascade.
      float hN = fmaf(Pn, inv_next_ce, LGAB2);
      #pragma unroll
      for (int d = 8; d >= 1; d >>= 1) hN = fmaxf(hN, __shfl_xor(hN, d));
      if ((lane & 15) == 0) hmD[dst*512 + 4*rb + (lane >> 4)] = hN;
      // coarse pack for next phase: cluster LSE of hy over 16-lane group
      float mh = hy;
      #pragma unroll
      for (int d = 8; d >= 1; d >>= 1) mh = fmaxf(mh, __shfl_xor(mh, d));
      float se = fexp2(hy - mh);
      #pragma unroll
      for (int d = 8; d >= 1; d >>= 1) se += __shfl_xor(se, d);
      float Hc = mh + log2f(se);
      if ((lane & 15) == 0) {
        int gc = 4*rb + (lane >> 4);
        float4 cv = cent[rset*512 + gc];
        float* cc = (float*)(cpd + 4*(size_t)NPTS + (size_t)dst * 512);
        int p2 = gc >> 1, sub2 = gc & 1;
        cc[p2*8+sub2]   = cv.x;
        cc[p2*8+2+sub2] = cv.y;
        cc[p2*8+4+sub2] = cv.z;
        cc[p2*8+6+sub2] = Hc;
      }
    }
  }
}

// loss = mean(f_fin - p_fin) + mean(g_fin - q_fin), fp64 accumulation
__global__ __launch_bounds__(256) void ws_reduce(
    const float* __restrict__ Tfin, float* __restrict__ out)
{
  int tid = threadIdx.x;
  double acc = 0.0;
  for (int i = tid; i < NPTS; i += 256) {
    acc += (double)Tfin[0*NPTS+i] - (double)Tfin[2*NPTS+i]
         + (double)Tfin[1*NPTS+i] - (double)Tfin[3*NPTS+i];
  }
  __shared__ double sd[256];
  sd[tid] = acc; __syncthreads();
  for (int k = 128; k > 0; k >>= 1) {
    if (tid < k) sd[tid] += sd[tid + k];
    __syncthreads();
  }
  if (tid == 0) out[0] = (float)(sd[0] / (double)NPTS);
}

extern "C" void kernel_launch(void* const* d_in, const int* in_sizes, int n_in,
                              void* d_out, int out_size, void* d_ws, size_t ws_size,
                              hipStream_t stream)
{
  const float* x = (const float*)d_in[0];
  const float* y = (const float*)d_in[1];
  float* out = (float*)d_out;

  const size_t CPSZ = (size_t)4 * NPTS + 2048;   // fine + coarse pack (float4)
  char* wsp = (char*)d_ws;
  float4*   xp   = (float4*)wsp;   wsp += (size_t)NPTS * 16;
  float4*   yp   = (float4*)wsp;   wsp += (size_t)NPTS * 16;
  float4*   cpA  = (float4*)wsp;   wsp += CPSZ * 16;
  float4*   cpB  = (float4*)wsp;   wsp += CPSZ * 16;
  float*    P    = (float*)wsp;    wsp += (size_t)4 * NPTS * 4;
  float*    Tfin = (float*)wsp;    wsp += (size_t)4 * NPTS * 4;
  unsigned* sidx = (unsigned*)wsp; wsp += (size_t)2 * NPTS * 4;
  float*    Mw   = (float*)wsp;    wsp += (size_t)4 * NPTS * 4;
  float*    hmA  = (float*)wsp;    wsp += (size_t)4 * 512 * 4;
  float*    hmB  = (float*)wsp;    wsp += (size_t)4 * 512 * 4;
  float4*   bbox = (float4*)wsp;   wsp += (size_t)2 * 512 * 2 * 16;
  float4*   cent = (float4*)wsp;   wsp += (size_t)2 * 512 * 16;
  float*    dmin = (float*)wsp;    wsp += (size_t)4 * 128 * 512 * 4;

  // geomloss epsilon schedule (f64, exactly as Python builds it)
  double epss[64]; int n = 0;
  double e = 4.0;                       // DIAMETER**P
  const double r = 0.9 * 0.9;          // SCALING**P
  const double target = 0.01 * 0.01;   // BLUR**P
  while (e > target && n < 60) { epss[n++] = e; e *= r; }   // n == 51

  // Phase plan: eps > 0.15 -> coarse 512-col phases (dense; ~10 us each);
  // 0.15 >= eps > 0.04 -> fine, stride-2 (R13-validated); else fine dense.
  // Final extrapolation at eps_final, fine.
  float feps[80]; int md[80]; int NPH = 0;
  feps[NPH] = (float)epss[0]; md[NPH] = 2; NPH++;          // init (coarse)
  {
    int k = 0;
    while (k < n) {
      int coarse = (epss[k] > 0.15);
      feps[NPH] = (float)epss[k]; md[NPH] = coarse ? 2 : 1; NPH++;
      k += coarse ? 1 : ((epss[k] > 0.04) ? 2 : 1);
    }
  }
  feps[NPH] = 1e-4f; md[NPH] = 1; NPH++;                   // final

  const double L2E  = 1.4426950408889634;
  const double LN2d = 0.6931471805599453;

  float inv0ce = (float)(L2E / (double)feps[0]);
  ws_sort<<<2, 1024, 0, stream>>>(x, y, sidx);
  ws_setup<<<(NPTS + 255) / 256, 256, 0, stream>>>(x, y, sidx, xp, yp, cpA, inv0ce);
  ws_bbox<<<2, 512, 0, stream>>>(xp, yp, bbox, cent, cpA + 4*(size_t)NPTS, inv0ce);
  ws_dmin<<<512, 512, 0, stream>>>(bbox, dmin);

  for (int p = 0; p < NPH; ++p) {
    float epsf = feps[p];
    float ce = (float)(L2E / (double)epsf);
    float eps_ln2 = (float)((double)epsf * LN2d);
    float inv_next_ce = 0.f;
    if (p < NPH - 1) inv_next_ce = (float)(L2E / (double)feps[p+1]);
    float rho = 1.f;
    if (p >= 1) rho = (float)((double)feps[p-1] / (double)feps[p]);
    int kind = (p == 0) ? 0 : ((p == NPH - 1) ? 2 : 1);
    const float4* src = (p & 1) ? cpB : cpA;
    float4*       dst = (p & 1) ? cpA : cpB;
    const float*  hmS = (p & 1) ? hmB : hmA;
    float*        hmD = (p & 1) ? hmA : hmB;
    ws_softmin<<<512, 1024, 0, stream>>>(xp, yp, src, dst, dmin, hmS, hmD,
                                         Mw, cent, P, Tfin,
                                         ce, eps_ln2, inv_next_ce, rho, kind, md[p]);
  }

  ws_reduce<<<1, 256, 0, stream>>>(Tfin, out);
}

// Round 17
// 1670.847 us; speedup vs baseline: 2.6288x; 1.0060x over previous
//
#include <hip/hip_runtime.h>
#include <math.h>

#define NPTS 8192
#define LGAB2 (-13.0f)   // log2(1/8192)
#define NWAVE 16         // waves per block (1024 threads)
#define MARGIN 20.0f     // chunk skip margin vs M_est (exponent units, base 2)

typedef __attribute__((ext_vector_type(2))) float f2;

__device__ __forceinline__ float fexp2(float x){
#if __has_builtin(__builtin_amdgcn_exp2f)
  return __builtin_amdgcn_exp2f(x);
#else
  return exp2f(x);
#endif
}
__device__ __forceinline__ f2 ffma2(f2 a, f2 b, f2 c){
  return __builtin_elementwise_fma(a, b, c);   // v_pk_fma_f32
}
__device__ __forceinline__ f2 fmax2(f2 a, f2 b){
  return __builtin_elementwise_max(a, b);      // v_pk_max_f32
}

// ---------------- counting sort by 12-bit Morton key (16^3 cells) ------------
__global__ __launch_bounds__(1024) void ws_sort(
    const float* __restrict__ x, const float* __restrict__ y,
    unsigned* __restrict__ sidx)
{
  __shared__ unsigned hist[4096];
  __shared__ unsigned wtot[16];
  const float* p = blockIdx.x ? y : x;
  int tid = threadIdx.x;
  for (int i = tid; i < 4096; i += 1024) hist[i] = 0;
  __syncthreads();
  unsigned key[8];
  for (int t = 0; t < 8; ++t) {
    int i = tid + (t << 10);
    unsigned q0 = (unsigned)fminf(fmaxf(p[3*i  ] * 16.f, 0.f), 15.f);
    unsigned q1 = (unsigned)fminf(fmaxf(p[3*i+1] * 16.f, 0.f), 15.f);
    unsigned q2 = (unsigned)fminf(fmaxf(p[3*i+2] * 16.f, 0.f), 15.f);
    unsigned k = 0;
    #pragma unroll
    for (int bb = 0; bb < 4; ++bb)
      k |= (((q0 >> bb) & 1u) << (3*bb)) | (((q1 >> bb) & 1u) << (3*bb+1))
         | (((q2 >> bb) & 1u) << (3*bb+2));
    key[t] = k;
    atomicAdd(&hist[k], 1u);
  }
  __syncthreads();
  unsigned c0 = hist[4*tid], c1 = hist[4*tid+1], c2 = hist[4*tid+2], c3 = hist[4*tid+3];
  unsigned tsum = c0 + c1 + c2 + c3;
  int lane = tid & 63, wv = tid >> 6;
  unsigned inc = tsum;
  for (int d = 1; d < 64; d <<= 1) {
    unsigned o = __shfl_up(inc, d);
    if (lane >= d) inc += o;
  }
  if (lane == 63) wtot[wv] = inc;
  __syncthreads();
  unsigned woff = 0;
  for (int k = 0; k < wv; ++k) woff += wtot[k];
  unsigned base = woff + inc - tsum;
  hist[4*tid] = base; hist[4*tid+1] = base + c0;
  hist[4*tid+2] = base + c0 + c1; hist[4*tid+3] = base + c0 + c1 + c2;
  __syncthreads();
  for (int t = 0; t < 8; ++t) {
    int i = tid + (t << 10);
    unsigned pos = atomicAdd(&hist[key[t]], 1u);
    sidx[blockIdx.x * NPTS + pos] = i;
  }
}

// Fine column pack (sorted domain): per 2 columns, float4 (x0,x1,y0,y1) then
// float4 (z0,z1,w0,w1) where w = h-term (exponent units base 2).
// Coarse pack (after 4*NPTS float4): 512 centroid-columns per slot.
__global__ __launch_bounds__(256) void ws_setup(
    const float* __restrict__ x, const float* __restrict__ y,
    const unsigned* __restrict__ sidx,
    float4* __restrict__ xp, float4* __restrict__ yp,
    float4* __restrict__ colpack, float inv0ce)
{
  int t = blockIdx.x * 256 + threadIdx.x;
  if (t >= NPTS) return;
  int ox = sidx[t], oy = sidx[NPTS + t];
  float x0 = x[3*ox], x1 = x[3*ox+1], x2 = x[3*ox+2];
  float xs = x0*x0 + x1*x1 + x2*x2;
  float y0 = y[3*oy], y1 = y[3*oy+1], y2 = y[3*oy+2];
  float ys = y0*y0 + y1*y1 + y2*y2;
  xp[t] = make_float4(x0,x1,x2,xs);
  yp[t] = make_float4(y0,y1,y2,ys);
  float hx = LGAB2 - 0.5f*xs*inv0ce;
  float hy = LGAB2 - 0.5f*ys*inv0ce;
  int p = t >> 1, sub = t & 1;
  {
    float* c0 = (float*)(colpack + 0*NPTS);
    c0[p*8+sub] = y0; c0[p*8+2+sub] = y1; c0[p*8+4+sub] = y2; c0[p*8+6+sub] = hy;
    float* c3 = (float*)(colpack + 3*NPTS);
    c3[p*8+sub] = y0; c3[p*8+2+sub] = y1; c3[p*8+4+sub] = y2; c3[p*8+6+sub] = hy;
  }
  {
    float* c1 = (float*)(colpack + 1*NPTS);
    c1[p*8+sub] = x0; c1[p*8+2+sub] = x1; c1[p*8+4+sub] = x2; c1[p*8+6+sub] = hx;
    float* c2 = (float*)(colpack + 2*NPTS);
    c2[p*8+sub] = x0; c2[p*8+2+sub] = x1; c2[p*8+4+sub] = x2; c2[p*8+6+sub] = hx;
  }
}

// Per-16-pt cluster: bbox, centroid, and initial coarse pack (duals = 0).
__global__ __launch_bounds__(512) void ws_bbox(
    const float4* __restrict__ xp, const float4* __restrict__ yp,
    float4* __restrict__ bbox, float4* __restrict__ cent,
    float4* __restrict__ cc0, float inv0ce)
{
  int c = threadIdx.x;           // 0..511
  int set = blockIdx.x;
  const float4* pp = set ? yp : xp;
  float lx = 1e30f, ly = 1e30f, lz = 1e30f;
  float hxx = -1e30f, hyy = -1e30f, hzz = -1e30f;
  float sx = 0.f, sy = 0.f, sz = 0.f, hm = -3.0e38f;
  float hv[16];
  for (int k = 0; k < 16; ++k) {
    float4 v = pp[c*16+k];
    lx = fminf(lx, v.x); ly = fminf(ly, v.y); lz = fminf(lz, v.z);
    hxx = fmaxf(hxx, v.x); hyy = fmaxf(hyy, v.y); hzz = fmaxf(hzz, v.z);
    sx += v.x; sy += v.y; sz += v.z;
    float h = LGAB2 - 0.5f * v.w * inv0ce;
    hv[k] = h; hm = fmaxf(hm, h);
  }
  float se = 0.f;
  for (int k = 0; k < 16; ++k) se += fexp2(hv[k] - hm);
  float H = hm + log2f(se);
  bbox[(set*512+c)*2+0] = make_float4(lx, ly, lz, 0.f);
  bbox[(set*512+c)*2+1] = make_float4(hxx, hyy, hzz, 0.f);
  float cx = sx * 0.0625f, cy = sy * 0.0625f, cz = sz * 0.0625f;
  cent[set*512+c] = make_float4(cx, cy, cz, 0.f);
  int s1 = set ? 0 : 1, s2 = set ? 3 : 2;   // slots using this set as columns
  int p = c >> 1, sub = c & 1;
  float* a = (float*)(cc0 + (size_t)s1 * 512);
  a[p*8+sub] = cx; a[p*8+2+sub] = cy; a[p*8+4+sub] = cz; a[p*8+6+sub] = H;
  float* bq = (float*)(cc0 + (size_t)s2 * 512);
  bq[p*8+sub] = cx; bq[p*8+2+sub] = cy; bq[p*8+4+sub] = cz; bq[p*8+6+sub] = H;
}

// dmin^2 at 16-ROW-GROUP granularity (tighter than the 64-row hull: the hull
// fills gaps between the 4 groups, keeping chunks no actual row needs).
// blockIdx.x = s*128+rb, threadIdx.x = col chunk c; writes 4 groups per block.
__global__ __launch_bounds__(512) void ws_dmin(
    const float4* __restrict__ bbox, float* __restrict__ dmin)
{
  int b = blockIdx.x;
  int s = b >> 7, rb = b & 127;
  int c = threadIdx.x;
  int rset = (s == 0 || s == 2) ? 0 : 1;
  int cset = (s == 0 || s == 3) ? 1 : 0;
  float4 bl = bbox[(cset*512 + c)*2], bh = bbox[(cset*512 + c)*2+1];
  #pragma unroll
  for (int g = 0; g < 4; ++g) {
    float4 l = bbox[(rset*512 + 4*rb + g)*2];
    float4 h = bbox[(rset*512 + 4*rb + g)*2+1];
    float dx = fmaxf(0.f, fmaxf(l.x - bh.x, bl.x - h.x));
    float dy = fmaxf(0.f, fmaxf(l.y - bh.y, bl.y - h.y));
    float dz = fmaxf(0.f, fmaxf(l.z - bh.z, bl.z - h.z));
    dmin[(((size_t)s*512 + 4*rb + g) << 9) + c] = dx*dx + dy*dy + dz*dz;
  }
}

// One phase. mode 0: fine exact two-pass (re-anchor / fallback).
// mode 1: fine single pass, M_est from prev LSE (x rho) + geometric chunk skip
//   (per-lane: each row tests its OWN 16-row-group dmin in the ballot).
// mode 2: coarse exact two-pass over 512 centroid-columns (eps > 0.15 regime).
// kind: 0 = assign (init), 1 = 0.5*(P+T) average, 2 = final (write Tfin)
__global__ __launch_bounds__(1024, 8) void ws_softmin(
    const float4* __restrict__ xp, const float4* __restrict__ yp,
    const float4* __restrict__ cps, float4* __restrict__ cpd,
    const float* __restrict__ dmin, const float* __restrict__ hmS,
    float* __restrict__ hmD, float* __restrict__ Mw,
    const float4* __restrict__ cent,
    float* __restrict__ P, float* __restrict__ Tfin,
    float ce, float eps_ln2, float inv_next_ce, float rho, int kind, int mode)
{
  int b = blockIdx.x;
  int s = b >> 7;
  int rb = b & 127;
  int rowbase = rb << 6;
  int tid = threadIdx.x;
  int lane = tid & 63;
  int w = __builtin_amdgcn_readfirstlane(tid >> 6);

  int rset = (s == 0 || s == 2) ? 0 : 1;
  const float4* rp = rset ? yp : xp;
  float4 rv = rp[rowbase + lane];
  float a0 = rv.x * ce, a1 = rv.y * ce, a2 = rv.z * ce;
  float hx = -0.5f * rv.w * ce;
  f2 A0 = {a0,a0}, A1 = {a1,a1}, A2 = {a2,a2};
  const float4* pw = cps + (size_t)s * NPTS + (w << 9);
  int row = rowbase + lane;

  __shared__ float lm[NWAVE][64];
  __shared__ float lss[NWAVE][64];
  float myMest = 0.f;

  if (mode == 0) {
    // ---- fine exact two-pass full scan ----
    f2 mA = {-3.0e38f, -3.0e38f}, mB = mA;
    #pragma unroll 2
    for (int pb = 0; pb < 256; pb += 2) {
      float4 P0 = pw[2*pb+0], Q0 = pw[2*pb+1];
      float4 P1 = pw[2*pb+2], Q1 = pw[2*pb+3];
      f2 X0={P0.x,P0.y}, Y0={P0.z,P0.w}, Z0={Q0.x,Q0.y}, W0={Q0.z,Q0.w};
      f2 X1={P1.x,P1.y}, Y1={P1.z,P1.w}, Z1={Q1.x,Q1.y}, W1={Q1.z,Q1.w};
      f2 t0 = ffma2(A2, Z0, W0); t0 = ffma2(A1, Y0, t0); t0 = ffma2(A0, X0, t0);
      f2 t1 = ffma2(A2, Z1, W1); t1 = ffma2(A1, Y1, t1); t1 = ffma2(A0, X1, t1);
      mA = fmax2(mA, t0); mB = fmax2(mB, t1);
    }
    f2 mAB = fmax2(mA, mB);
    float m = fmaxf(mAB.x, mAB.y);
    f2 M2 = {m, m};
    f2 sA = {0.f,0.f}, sB = {0.f,0.f};
    #pragma unroll 2
    for (int pb = 0; pb < 256; pb += 2) {
      float4 P0 = pw[2*pb+0], Q0 = pw[2*pb+1];
      float4 P1 = pw[2*pb+2], Q1 = pw[2*pb+3];
      f2 X0={P0.x,P0.y}, Y0={P0.z,P0.w}, Z0={Q0.x,Q0.y}, W0={Q0.z,Q0.w};
      f2 X1={P1.x,P1.y}, Y1={P1.z,P1.w}, Z1={Q1.x,Q1.y}, W1={Q1.z,Q1.w};
      f2 u0 = ffma2(A2, Z0, W0 - M2); u0 = ffma2(A1, Y0, u0); u0 = ffma2(A0, X0, u0);
      f2 u1 = ffma2(A2, Z1, W1 - M2); u1 = ffma2(A1, Y1, u1); u1 = ffma2(A0, X1, u1);
      f2 e0, e1;
      e0.x = fexp2(u0.x); e0.y = fexp2(u0.y);
      e1.x = fexp2(u1.x); e1.y = fexp2(u1.y);
      sA += e0; sB += e1;
    }
    f2 sAB = sA + sB;
    lm[w][lane] = m;
    lss[w][lane] = sAB.x + sAB.y;
  } else if (mode == 2) {
    // ---- coarse exact two-pass: 512 centroid-cols, 32 per wave ----
    const float4* pwc = cps + 4*(size_t)NPTS + (size_t)s*512 + (w << 5);
    f2 mA = {-3.0e38f, -3.0e38f}, mB = mA;
    #pragma unroll
    for (int pb = 0; pb < 16; pb += 2) {
      float4 P0 = pwc[2*pb+0], Q0 = pwc[2*pb+1];
      float4 P1 = pwc[2*pb+2], Q1 = pwc[2*pb+3];
      f2 X0={P0.x,P0.y}, Y0={P0.z,P0.w}, Z0={Q0.x,Q0.y}, W0={Q0.z,Q0.w};
      f2 X1={P1.x,P1.y}, Y1={P1.z,P1.w}, Z1={Q1.x,Q1.y}, W1={Q1.z,Q1.w};
      f2 t0 = ffma2(A2, Z0, W0); t0 = ffma2(A1, Y0, t0); t0 = ffma2(A0, X0, t0);
      f2 t1 = ffma2(A2, Z1, W1); t1 = ffma2(A1, Y1, t1); t1 = ffma2(A0, X1, t1);
      mA = fmax2(mA, t0); mB = fmax2(mB, t1);
    }
    f2 mAB = fmax2(mA, mB);
    float m = fmaxf(mAB.x, mAB.y);
    f2 M2 = {m, m};
    f2 sA = {0.f,0.f}, sB = {0.f,0.f};
    #pragma unroll
    for (int pb = 0; pb < 16; pb += 2) {
      float4 P0 = pwc[2*pb+0], Q0 = pwc[2*pb+1];
      float4 P1 = pwc[2*pb+2], Q1 = pwc[2*pb+3];
      f2 X0={P0.x,P0.y}, Y0={P0.z,P0.w}, Z0={Q0.x,Q0.y}, W0={Q0.z,Q0.w};
      f2 X1={P1.x,P1.y}, Y1={P1.z,P1.w}, Z1={Q1.x,Q1.y}, W1={Q1.z,Q1.w};
      f2 u0 = ffma2(A2, Z0, W0 - M2); u0 = ffma2(A1, Y0, u0); u0 = ffma2(A0, X0, u0);
      f2 u1 = ffma2(A2, Z1, W1 - M2); u1 = ffma2(A1, Y1, u1); u1 = ffma2(A0, X1, u1);
      f2 e0, e1;
      e0.x = fexp2(u0.x); e0.y = fexp2(u0.y);
      e1.x = fexp2(u1.x); e1.y = fexp2(u1.y);
      sA += e0; sB += e1;
    }
    f2 sAB = sA + sB;
    lm[w][lane] = m;
    lss[w][lane] = sAB.x + sAB.y;
  } else {
    // ---- fine single pass with M_est + per-row-group geometric chunk skip ----
    float Mest = fmaf(Mw[s * NPTS + row] - LGAB2, rho, LGAB2);
    myMest = Mest;
    float thr = Mest - MARGIN;
    int rg = 4*rb + (lane >> 4);            // this row's 16-row group
    const float* dmr = dmin + (((size_t)s*512 + rg) << 9);
    unsigned mask = 0u;
    #pragma unroll
    for (int c = 0; c < 32; ++c) {
      int gc = (w << 5) + c;
      float Wc = hmS[s*512 + gc] - 0.5f * ce * dmr[gc];
      if (__ballot(Wc > thr)) mask |= (1u << c);
    }
    if (mask == 0u) mask = 0xFFFFFFFFu;   // safety: never drop everything
    mask = __builtin_amdgcn_readfirstlane(mask);
    float Mv = Mest - hx;
    f2 M2 = {Mv, Mv};
    f2 sA = {0.f,0.f}, sB = {0.f,0.f};
    for (int c = 0; c < 32; ++c) {
      if (!((mask >> c) & 1u)) continue;
      const float4* pc = pw + (c << 4);   // 16 cols = 8 pair-blocks
      #pragma unroll 4
      for (int pb = 0; pb < 8; ++pb) {
        float4 Pv = pc[2*pb], Qv = pc[2*pb+1];
        f2 X={Pv.x,Pv.y}, Y={Pv.z,Pv.w}, Z={Qv.x,Qv.y}, W={Qv.z,Qv.w};
        f2 u = ffma2(A2, Z, W - M2);
        u = ffma2(A1, Y, u);
        u = ffma2(A0, X, u);
        f2 e;
        e.x = fexp2(u.x); e.y = fexp2(u.y);
        if (pb & 1) sB += e; else sA += e;
      }
    }
    f2 sAB = sA + sB;
    lss[w][lane] = sAB.x + sAB.y;
  }
  __syncthreads();

  if (tid < 64) {
    float L;
    if (mode == 1) {
      float S = 0.f;
      #pragma unroll
      for (int k = 0; k < NWAVE; ++k) S += lss[k][lane];
      S = fmaxf(S, 1e-30f);
      L = myMest + log2f(S);
    } else {
      float M = lm[0][lane];
      #pragma unroll
      for (int k = 1; k < NWAVE; ++k) M = fmaxf(M, lm[k][lane]);
      float S = 0.f;
      #pragma unroll
      for (int k = 0; k < NWAVE; ++k) S += lss[k][lane] * fexp2(lm[k][lane] - M);
      L = hx + M + log2f(S);
    }
    float T = -eps_ln2 * L;
    Mw[s * NPTS + row] = L;
    if (kind == 2) {
      Tfin[s * NPTS + row] = T;
    } else {
      float* Pr = P + s * NPTS;
      float Pn = (kind == 0) ? T : 0.5f * (Pr[row] + T);
      Pr[row] = Pn;
      int dst = (s == 0) ? 1 : ((s == 1) ? 0 : s);
      float hy = LGAB2 + (Pn - 0.5f * rv.w) * inv_next_ce;
      float* cd = (float*)(cpd + (size_t)dst * NPTS);
      int p = row >> 1, sub = row & 1;
      cd[p*8+sub]   = rv.x;
      cd[p*8+2+sub] = rv.y;
      cd[p*8+4+sub] = rv.z;
      cd[p*8+6+sub] = hy;
      // Skip-bound table: MUST be LGAB2 + Pn*ce (R14 errata: max(h_j) is NOT
      // a valid bound — the -0.5|y|^2 cancels against the x.y cross term).
      float hN = fmaf(Pn, inv_next_ce, LGAB2);
      #pragma unroll
      for (int d = 8; d >= 1; d >>= 1) hN = fmaxf(hN, __shfl_xor(hN, d));
      if ((lane & 15) == 0) hmD[dst*512 + 4*rb + (lane >> 4)] = hN;
      // coarse pack for next phase: cluster LSE of hy over 16-lane group
      float mh = hy;
      #pragma unroll
      for (int d = 8; d >= 1; d >>= 1) mh = fmaxf(mh, __shfl_xor(mh, d));
      float se = fexp2(hy - mh);
      #pragma unroll
      for (int d = 8; d >= 1; d >>= 1) se += __shfl_xor(se, d);
      float Hc = mh + log2f(se);
      if ((lane & 15) == 0) {
        int gc = 4*rb + (lane >> 4);
        float4 cv = cent[rset*512 + gc];
        float* cc = (float*)(cpd + 4*(size_t)NPTS + (size_t)dst * 512);
        int p2 = gc >> 1, sub2 = gc & 1;
        cc[p2*8+sub2]   = cv.x;
        cc[p2*8+2+sub2] = cv.y;
        cc[p2*8+4+sub2] = cv.z;
        cc[p2*8+6+sub2] = Hc;
      }
    }
  }
}

// loss = mean(f_fin - p_fin) + mean(g_fin - q_fin), fp64 accumulation
__global__ __launch_bounds__(256) void ws_reduce(
    const float* __restrict__ Tfin, float* __restrict__ out)
{
  int tid = threadIdx.x;
  double acc = 0.0;
  for (int i = tid; i < NPTS; i += 256) {
    acc += (double)Tfin[0*NPTS+i] - (double)Tfin[2*NPTS+i]
         + (double)Tfin[1*NPTS+i] - (double)Tfin[3*NPTS+i];
  }
  __shared__ double sd[256];
  sd[tid] = acc; __syncthreads();
  for (int k = 128; k > 0; k >>= 1) {
    if (tid < k) sd[tid] += sd[tid + k];
    __syncthreads();
  }
  if (tid == 0) out[0] = (float)(sd[0] / (double)NPTS);
}

extern "C" void kernel_launch(void* const* d_in, const int* in_sizes, int n_in,
                              void* d_out, int out_size, void* d_ws, size_t ws_size,
                              hipStream_t stream)
{
  const float* x = (const float*)d_in[0];
  const float* y = (const float*)d_in[1];
  float* out = (float*)d_out;

  const size_t CPSZ = (size_t)4 * NPTS + 2048;   // fine + coarse pack (float4)
  char* wsp = (char*)d_ws;
  float4*   xp   = (float4*)wsp;   wsp += (size_t)NPTS * 16;
  float4*   yp   = (float4*)wsp;   wsp += (size_t)NPTS * 16;
  float4*   cpA  = (float4*)wsp;   wsp += CPSZ * 16;
  float4*   cpB  = (float4*)wsp;   wsp += CPSZ * 16;
  float*    P    = (float*)wsp;    wsp += (size_t)4 * NPTS * 4;
  float*    Tfin = (float*)wsp;    wsp += (size_t)4 * NPTS * 4;
  unsigned* sidx = (unsigned*)wsp; wsp += (size_t)2 * NPTS * 4;
  float*    Mw   = (float*)wsp;    wsp += (size_t)4 * NPTS * 4;
  float*    hmA  = (float*)wsp;    wsp += (size_t)4 * 512 * 4;
  float*    hmB  = (float*)wsp;    wsp += (size_t)4 * 512 * 4;
  float4*   bbox = (float4*)wsp;   wsp += (size_t)2 * 512 * 2 * 16;
  float4*   cent = (float4*)wsp;   wsp += (size_t)2 * 512 * 16;
  float*    dmin = (float*)wsp;    wsp += (size_t)4 * 512 * 512 * 4;  // 4 MB

  // geomloss epsilon schedule (f64, exactly as Python builds it)
  double epss[64]; int n = 0;
  double e = 4.0;                       // DIAMETER**P
  const double r = 0.9 * 0.9;          // SCALING**P
  const double target = 0.01 * 0.01;   // BLUR**P
  while (e > target && n < 60) { epss[n++] = e; e *= r; }   // n == 51

  // Phase plan (R15-proven): eps > 0.15 -> coarse512 (mode 2);
  // 0.15 >= eps > 0.04 -> fine, stride-2 (R13-validated); else fine dense.
  // Final extrapolation at eps_final, fine.
  float feps[80]; int md[80]; int NPH = 0;
  feps[NPH] = (float)epss[0]; md[NPH] = 2; NPH++;          // init (coarse)
  {
    int k = 0;
    while (k < n) {
      int coarse = (epss[k] > 0.15);
      feps[NPH] = (float)epss[k]; md[NPH] = coarse ? 2 : 1; NPH++;
      k += coarse ? 1 : ((epss[k] > 0.04) ? 2 : 1);
    }
  }
  feps[NPH] = 1e-4f; md[NPH] = 1; NPH++;                   // final

  const double L2E  = 1.4426950408889634;
  const double LN2d = 0.6931471805599453;

  float inv0ce = (float)(L2E / (double)feps[0]);
  ws_sort<<<2, 1024, 0, stream>>>(x, y, sidx);
  ws_setup<<<(NPTS + 255) / 256, 256, 0, stream>>>(x, y, sidx, xp, yp, cpA, inv0ce);
  ws_bbox<<<2, 512, 0, stream>>>(xp, yp, bbox, cent, cpA + 4*(size_t)NPTS, inv0ce);
  ws_dmin<<<512, 512, 0, stream>>>(bbox, dmin);

  for (int p = 0; p < NPH; ++p) {
    float epsf = feps[p];
    float ce = (float)(L2E / (double)epsf);
    float eps_ln2 = (float)((double)epsf * LN2d);
    float inv_next_ce = 0.f;
    if (p < NPH - 1) inv_next_ce = (float)(L2E / (double)feps[p+1]);
    float rho = 1.f;
    if (p >= 1) rho = (float)((double)feps[p-1] / (double)feps[p]);
    int kind = (p == 0) ? 0 : ((p == NPH - 1) ? 2 : 1);
    const float4* src = (p & 1) ? cpB : cpA;
    float4*       dst = (p & 1) ? cpA : cpB;
    const float*  hmS = (p & 1) ? hmB : hmA;
    float*        hmD = (p & 1) ? hmA : hmB;
    ws_softmin<<<512, 1024, 0, stream>>>(xp, yp, src, dst, dmin, hmS, hmD,
                                         Mw, cent, P, Tfin,
                                         ce, eps_ln2, inv_next_ce, rho, kind, md[p]);
  }

  ws_reduce<<<1, 256, 0, stream>>>(Tfin, out);
}

// Round 18
// 1607.049 us; speedup vs baseline: 2.7331x; 1.0397x over previous
//
#include <hip/hip_runtime.h>
#include <math.h>

#define NPTS 8192
#define LGAB2 (-13.0f)   // log2(1/8192)
#define NWAVE 16         // waves per block (1024 threads)
#define MARGIN 20.0f     // chunk skip margin vs M_est (exponent units, base 2)

typedef __attribute__((ext_vector_type(2))) float f2;

__device__ __forceinline__ float fexp2(float x){
#if __has_builtin(__builtin_amdgcn_exp2f)
  return __builtin_amdgcn_exp2f(x);
#else
  return exp2f(x);
#endif
}
__device__ __forceinline__ f2 ffma2(f2 a, f2 b, f2 c){
  return __builtin_elementwise_fma(a, b, c);   // v_pk_fma_f32
}
__device__ __forceinline__ f2 fmax2(f2 a, f2 b){
  return __builtin_elementwise_max(a, b);      // v_pk_max_f32
}

// ---------------- counting sort by 12-bit Morton key (16^3 cells) ------------
__global__ __launch_bounds__(1024) void ws_sort(
    const float* __restrict__ x, const float* __restrict__ y,
    unsigned* __restrict__ sidx)
{
  __shared__ unsigned hist[4096];
  __shared__ unsigned wtot[16];
  const float* p = blockIdx.x ? y : x;
  int tid = threadIdx.x;
  for (int i = tid; i < 4096; i += 1024) hist[i] = 0;
  __syncthreads();
  unsigned key[8];
  for (int t = 0; t < 8; ++t) {
    int i = tid + (t << 10);
    unsigned q0 = (unsigned)fminf(fmaxf(p[3*i  ] * 16.f, 0.f), 15.f);
    unsigned q1 = (unsigned)fminf(fmaxf(p[3*i+1] * 16.f, 0.f), 15.f);
    unsigned q2 = (unsigned)fminf(fmaxf(p[3*i+2] * 16.f, 0.f), 15.f);
    unsigned k = 0;
    #pragma unroll
    for (int bb = 0; bb < 4; ++bb)
      k |= (((q0 >> bb) & 1u) << (3*bb)) | (((q1 >> bb) & 1u) << (3*bb+1))
         | (((q2 >> bb) & 1u) << (3*bb+2));
    key[t] = k;
    atomicAdd(&hist[k], 1u);
  }
  __syncthreads();
  unsigned c0 = hist[4*tid], c1 = hist[4*tid+1], c2 = hist[4*tid+2], c3 = hist[4*tid+3];
  unsigned tsum = c0 + c1 + c2 + c3;
  int lane = tid & 63, wv = tid >> 6;
  unsigned inc = tsum;
  for (int d = 1; d < 64; d <<= 1) {
    unsigned o = __shfl_up(inc, d);
    if (lane >= d) inc += o;
  }
  if (lane == 63) wtot[wv] = inc;
  __syncthreads();
  unsigned woff = 0;
  for (int k = 0; k < wv; ++k) woff += wtot[k];
  unsigned base = woff + inc - tsum;
  hist[4*tid] = base; hist[4*tid+1] = base + c0;
  hist[4*tid+2] = base + c0 + c1; hist[4*tid+3] = base + c0 + c1 + c2;
  __syncthreads();
  for (int t = 0; t < 8; ++t) {
    int i = tid + (t << 10);
    unsigned pos = atomicAdd(&hist[key[t]], 1u);
    sidx[blockIdx.x * NPTS + pos] = i;
  }
}

// Fine column pack (sorted domain): per 2 columns, float4 (x0,x1,y0,y1) then
// float4 (z0,z1,w0,w1) where w = h-term (exponent units base 2).
// Coarse pack (after 4*NPTS float4): 512 centroid-columns per slot.
__global__ __launch_bounds__(256) void ws_setup(
    const float* __restrict__ x, const float* __restrict__ y,
    const unsigned* __restrict__ sidx,
    float4* __restrict__ xp, float4* __restrict__ yp,
    float4* __restrict__ colpack, float inv0ce)
{
  int t = blockIdx.x * 256 + threadIdx.x;
  if (t >= NPTS) return;
  int ox = sidx[t], oy = sidx[NPTS + t];
  float x0 = x[3*ox], x1 = x[3*ox+1], x2 = x[3*ox+2];
  float xs = x0*x0 + x1*x1 + x2*x2;
  float y0 = y[3*oy], y1 = y[3*oy+1], y2 = y[3*oy+2];
  float ys = y0*y0 + y1*y1 + y2*y2;
  xp[t] = make_float4(x0,x1,x2,xs);
  yp[t] = make_float4(y0,y1,y2,ys);
  float hx = LGAB2 - 0.5f*xs*inv0ce;
  float hy = LGAB2 - 0.5f*ys*inv0ce;
  int p = t >> 1, sub = t & 1;
  {
    float* c0 = (float*)(colpack + 0*NPTS);
    c0[p*8+sub] = y0; c0[p*8+2+sub] = y1; c0[p*8+4+sub] = y2; c0[p*8+6+sub] = hy;
    float* c3 = (float*)(colpack + 3*NPTS);
    c3[p*8+sub] = y0; c3[p*8+2+sub] = y1; c3[p*8+4+sub] = y2; c3[p*8+6+sub] = hy;
  }
  {
    float* c1 = (float*)(colpack + 1*NPTS);
    c1[p*8+sub] = x0; c1[p*8+2+sub] = x1; c1[p*8+4+sub] = x2; c1[p*8+6+sub] = hx;
    float* c2 = (float*)(colpack + 2*NPTS);
    c2[p*8+sub] = x0; c2[p*8+2+sub] = x1; c2[p*8+4+sub] = x2; c2[p*8+6+sub] = hx;
  }
}

// Per-16-pt cluster: bbox, centroid, and initial coarse pack (duals = 0).
__global__ __launch_bounds__(512) void ws_bbox(
    const float4* __restrict__ xp, const float4* __restrict__ yp,
    float4* __restrict__ bbox, float4* __restrict__ cent,
    float4* __restrict__ cc0, float inv0ce)
{
  int c = threadIdx.x;           // 0..511
  int set = blockIdx.x;
  const float4* pp = set ? yp : xp;
  float lx = 1e30f, ly = 1e30f, lz = 1e30f;
  float hxx = -1e30f, hyy = -1e30f, hzz = -1e30f;
  float sx = 0.f, sy = 0.f, sz = 0.f, hm = -3.0e38f;
  float hv[16];
  for (int k = 0; k < 16; ++k) {
    float4 v = pp[c*16+k];
    lx = fminf(lx, v.x); ly = fminf(ly, v.y); lz = fminf(lz, v.z);
    hxx = fmaxf(hxx, v.x); hyy = fmaxf(hyy, v.y); hzz = fmaxf(hzz, v.z);
    sx += v.x; sy += v.y; sz += v.z;
    float h = LGAB2 - 0.5f * v.w * inv0ce;
    hv[k] = h; hm = fmaxf(hm, h);
  }
  float se = 0.f;
  for (int k = 0; k < 16; ++k) se += fexp2(hv[k] - hm);
  float H = hm + log2f(se);
  bbox[(set*512+c)*2+0] = make_float4(lx, ly, lz, 0.f);
  bbox[(set*512+c)*2+1] = make_float4(hxx, hyy, hzz, 0.f);
  float cx = sx * 0.0625f, cy = sy * 0.0625f, cz = sz * 0.0625f;
  cent[set*512+c] = make_float4(cx, cy, cz, 0.f);
  int s1 = set ? 0 : 1, s2 = set ? 3 : 2;   // slots using this set as columns
  int p = c >> 1, sub = c & 1;
  float* a = (float*)(cc0 + (size_t)s1 * 512);
  a[p*8+sub] = cx; a[p*8+2+sub] = cy; a[p*8+4+sub] = cz; a[p*8+6+sub] = H;
  float* bq = (float*)(cc0 + (size_t)s2 * 512);
  bq[p*8+sub] = cx; bq[p*8+2+sub] = cy; bq[p*8+4+sub] = cz; bq[p*8+6+sub] = H;
}

// dmin^2 at 16-ROW-GROUP granularity.
// blockIdx.x = s*128+rb, threadIdx.x = col chunk c; writes 4 groups per block.
__global__ __launch_bounds__(512) void ws_dmin(
    const float4* __restrict__ bbox, float* __restrict__ dmin)
{
  int b = blockIdx.x;
  int s = b >> 7, rb = b & 127;
  int c = threadIdx.x;
  int rset = (s == 0 || s == 2) ? 0 : 1;
  int cset = (s == 0 || s == 3) ? 1 : 0;
  float4 bl = bbox[(cset*512 + c)*2], bh = bbox[(cset*512 + c)*2+1];
  #pragma unroll
  for (int g = 0; g < 4; ++g) {
    float4 l = bbox[(rset*512 + 4*rb + g)*2];
    float4 h = bbox[(rset*512 + 4*rb + g)*2+1];
    float dx = fmaxf(0.f, fmaxf(l.x - bh.x, bl.x - h.x));
    float dy = fmaxf(0.f, fmaxf(l.y - bh.y, bl.y - h.y));
    float dz = fmaxf(0.f, fmaxf(l.z - bh.z, bl.z - h.z));
    dmin[(((size_t)s*512 + 4*rb + g) << 9) + c] = dx*dx + dy*dy + dz*dz;
  }
}

// One phase. mode 0: fine exact two-pass (re-anchor / fallback).
// mode 1: fine single pass, M_est from prev LSE (x rho) + geometric chunk skip.
//   Chunk ownership is INTERLEAVED across waves (gc = (c<<4)|w): surviving
//   chunks (a Morton-local ball) scatter uniformly over waves, so the barrier
//   waits on the mean wave, not the max (R17: contiguous slices left 1-2 waves
//   doing all surviving work on late phases while 14 idled).
// mode 2: coarse exact two-pass over 512 centroid-columns (eps > 0.15 regime).
// kind: 0 = assign (init), 1 = 0.5*(P+T) average, 2 = final (write Tfin)
__global__ __launch_bounds__(1024, 8) void ws_softmin(
    const float4* __restrict__ xp, const float4* __restrict__ yp,
    const float4* __restrict__ cps, float4* __restrict__ cpd,
    const float* __restrict__ dmin, const float* __restrict__ hmS,
    float* __restrict__ hmD, float* __restrict__ Mw,
    const float4* __restrict__ cent,
    float* __restrict__ P, float* __restrict__ Tfin,
    float ce, float eps_ln2, float inv_next_ce, float rho, int kind, int mode)
{
  int b = blockIdx.x;
  int s = b >> 7;
  int rb = b & 127;
  int rowbase = rb << 6;
  int tid = threadIdx.x;
  int lane = tid & 63;
  int w = __builtin_amdgcn_readfirstlane(tid >> 6);

  int rset = (s == 0 || s == 2) ? 0 : 1;
  const float4* rp = rset ? yp : xp;
  float4 rv = rp[rowbase + lane];
  float a0 = rv.x * ce, a1 = rv.y * ce, a2 = rv.z * ce;
  float hx = -0.5f * rv.w * ce;
  f2 A0 = {a0,a0}, A1 = {a1,a1}, A2 = {a2,a2};
  const float4* pw = cps + (size_t)s * NPTS + (w << 9);
  const float4* slotbase = cps + (size_t)s * NPTS;
  int row = rowbase + lane;

  __shared__ float lm[NWAVE][64];
  __shared__ float lss[NWAVE][64];
  float myMest = 0.f;

  if (mode == 0) {
    // ---- fine exact two-pass full scan ----
    f2 mA = {-3.0e38f, -3.0e38f}, mB = mA;
    #pragma unroll 2
    for (int pb = 0; pb < 256; pb += 2) {
      float4 P0 = pw[2*pb+0], Q0 = pw[2*pb+1];
      float4 P1 = pw[2*pb+2], Q1 = pw[2*pb+3];
      f2 X0={P0.x,P0.y}, Y0={P0.z,P0.w}, Z0={Q0.x,Q0.y}, W0={Q0.z,Q0.w};
      f2 X1={P1.x,P1.y}, Y1={P1.z,P1.w}, Z1={Q1.x,Q1.y}, W1={Q1.z,Q1.w};
      f2 t0 = ffma2(A2, Z0, W0); t0 = ffma2(A1, Y0, t0); t0 = ffma2(A0, X0, t0);
      f2 t1 = ffma2(A2, Z1, W1); t1 = ffma2(A1, Y1, t1); t1 = ffma2(A0, X1, t1);
      mA = fmax2(mA, t0); mB = fmax2(mB, t1);
    }
    f2 mAB = fmax2(mA, mB);
    float m = fmaxf(mAB.x, mAB.y);
    f2 M2 = {m, m};
    f2 sA = {0.f,0.f}, sB = {0.f,0.f};
    #pragma unroll 2
    for (int pb = 0; pb < 256; pb += 2) {
      float4 P0 = pw[2*pb+0], Q0 = pw[2*pb+1];
      float4 P1 = pw[2*pb+2], Q1 = pw[2*pb+3];
      f2 X0={P0.x,P0.y}, Y0={P0.z,P0.w}, Z0={Q0.x,Q0.y}, W0={Q0.z,Q0.w};
      f2 X1={P1.x,P1.y}, Y1={P1.z,P1.w}, Z1={Q1.x,Q1.y}, W1={Q1.z,Q1.w};
      f2 u0 = ffma2(A2, Z0, W0 - M2); u0 = ffma2(A1, Y0, u0); u0 = ffma2(A0, X0, u0);
      f2 u1 = ffma2(A2, Z1, W1 - M2); u1 = ffma2(A1, Y1, u1); u1 = ffma2(A0, X1, u1);
      f2 e0, e1;
      e0.x = fexp2(u0.x); e0.y = fexp2(u0.y);
      e1.x = fexp2(u1.x); e1.y = fexp2(u1.y);
      sA += e0; sB += e1;
    }
    f2 sAB = sA + sB;
    lm[w][lane] = m;
    lss[w][lane] = sAB.x + sAB.y;
  } else if (mode == 2) {
    // ---- coarse exact two-pass: 512 centroid-cols, 32 per wave ----
    const float4* pwc = cps + 4*(size_t)NPTS + (size_t)s*512 + (w << 5);
    f2 mA = {-3.0e38f, -3.0e38f}, mB = mA;
    #pragma unroll
    for (int pb = 0; pb < 16; pb += 2) {
      float4 P0 = pwc[2*pb+0], Q0 = pwc[2*pb+1];
      float4 P1 = pwc[2*pb+2], Q1 = pwc[2*pb+3];
      f2 X0={P0.x,P0.y}, Y0={P0.z,P0.w}, Z0={Q0.x,Q0.y}, W0={Q0.z,Q0.w};
      f2 X1={P1.x,P1.y}, Y1={P1.z,P1.w}, Z1={Q1.x,Q1.y}, W1={Q1.z,Q1.w};
      f2 t0 = ffma2(A2, Z0, W0); t0 = ffma2(A1, Y0, t0); t0 = ffma2(A0, X0, t0);
      f2 t1 = ffma2(A2, Z1, W1); t1 = ffma2(A1, Y1, t1); t1 = ffma2(A0, X1, t1);
      mA = fmax2(mA, t0); mB = fmax2(mB, t1);
    }
    f2 mAB = fmax2(mA, mB);
    float m = fmaxf(mAB.x, mAB.y);
    f2 M2 = {m, m};
    f2 sA = {0.f,0.f}, sB = {0.f,0.f};
    #pragma unroll
    for (int pb = 0; pb < 16; pb += 2) {
      float4 P0 = pwc[2*pb+0], Q0 = pwc[2*pb+1];
      float4 P1 = pwc[2*pb+2], Q1 = pwc[2*pb+3];
      f2 X0={P0.x,P0.y}, Y0={P0.z,P0.w}, Z0={Q0.x,Q0.y}, W0={Q0.z,Q0.w};
      f2 X1={P1.x,P1.y}, Y1={P1.z,P1.w}, Z1={Q1.x,Q1.y}, W1={Q1.z,Q1.w};
      f2 u0 = ffma2(A2, Z0, W0 - M2); u0 = ffma2(A1, Y0, u0); u0 = ffma2(A0, X0, u0);
      f2 u1 = ffma2(A2, Z1, W1 - M2); u1 = ffma2(A1, Y1, u1); u1 = ffma2(A0, X1, u1);
      f2 e0, e1;
      e0.x = fexp2(u0.x); e0.y = fexp2(u0.y);
      e1.x = fexp2(u1.x); e1.y = fexp2(u1.y);
      sA += e0; sB += e1;
    }
    f2 sAB = sA + sB;
    lm[w][lane] = m;
    lss[w][lane] = sAB.x + sAB.y;
  } else {
    // ---- fine single pass with M_est + interleaved-chunk geometric skip ----
    float Mest = fmaf(Mw[s * NPTS + row] - LGAB2, rho, LGAB2);
    myMest = Mest;
    float thr = Mest - MARGIN;
    int rg = 4*rb + (lane >> 4);            // this row's 16-row group
    const float* dmr = dmin + (((size_t)s*512 + rg) << 9);
    unsigned mask = 0u;
    #pragma unroll
    for (int c = 0; c < 32; ++c) {
      int gc = (c << 4) | w;                // interleaved: stride-16 chunks
      float Wc = hmS[s*512 + gc] - 0.5f * ce * dmr[gc];
      if (__ballot(Wc > thr)) mask |= (1u << c);
    }
    if (mask == 0u) mask = 0xFFFFFFFFu;   // safety: never drop everything
    mask = __builtin_amdgcn_readfirstlane(mask);
    float Mv = Mest - hx;
    f2 M2 = {Mv, Mv};
    f2 sA = {0.f,0.f}, sB = {0.f,0.f};
    for (int c = 0; c < 32; ++c) {
      if (!((mask >> c) & 1u)) continue;
      int gc = (c << 4) | w;
      const float4* pc = slotbase + ((size_t)gc << 4);  // 16 cols = 16 float4s
      #pragma unroll 4
      for (int pb = 0; pb < 8; ++pb) {
        float4 Pv = pc[2*pb], Qv = pc[2*pb+1];
        f2 X={Pv.x,Pv.y}, Y={Pv.z,Pv.w}, Z={Qv.x,Qv.y}, W={Qv.z,Qv.w};
        f2 u = ffma2(A2, Z, W - M2);
        u = ffma2(A1, Y, u);
        u = ffma2(A0, X, u);
        f2 e;
        e.x = fexp2(u.x); e.y = fexp2(u.y);
        if (pb & 1) sB += e; else sA += e;
      }
    }
    f2 sAB = sA + sB;
    lss[w][lane] = sAB.x + sAB.y;
  }
  __syncthreads();

  if (tid < 64) {
    float L;
    if (mode == 1) {
      float S = 0.f;
      #pragma unroll
      for (int k = 0; k < NWAVE; ++k) S += lss[k][lane];
      S = fmaxf(S, 1e-30f);
      L = myMest + log2f(S);
    } else {
      float M = lm[0][lane];
      #pragma unroll
      for (int k = 1; k < NWAVE; ++k) M = fmaxf(M, lm[k][lane]);
      float S = 0.f;
      #pragma unroll
      for (int k = 0; k < NWAVE; ++k) S += lss[k][lane] * fexp2(lm[k][lane] - M);
      L = hx + M + log2f(S);
    }
    float T = -eps_ln2 * L;
    Mw[s * NPTS + row] = L;
    if (kind == 2) {
      Tfin[s * NPTS + row] = T;
    } else {
      float* Pr = P + s * NPTS;
      float Pn = (kind == 0) ? T : 0.5f * (Pr[row] + T);
      Pr[row] = Pn;
      int dst = (s == 0) ? 1 : ((s == 1) ? 0 : s);
      float hy = LGAB2 + (Pn - 0.5f * rv.w) * inv_next_ce;
      float* cd = (float*)(cpd + (size_t)dst * NPTS);
      int p = row >> 1, sub = row & 1;
      cd[p*8+sub]   = rv.x;
      cd[p*8+2+sub] = rv.y;
      cd[p*8+4+sub] = rv.z;
      cd[p*8+6+sub] = hy;
      // Skip-bound table: MUST be LGAB2 + Pn*ce (R14 errata: max(h_j) is NOT
      // a valid bound — the -0.5|y|^2 cancels against the x.y cross term).
      float hN = fmaf(Pn, inv_next_ce, LGAB2);
      #pragma unroll
      for (int d = 8; d >= 1; d >>= 1) hN = fmaxf(hN, __shfl_xor(hN, d));
      if ((lane & 15) == 0) hmD[dst*512 + 4*rb + (lane >> 4)] = hN;
      // coarse pack for next phase: cluster LSE of hy over 16-lane group
      float mh = hy;
      #pragma unroll
      for (int d = 8; d >= 1; d >>= 1) mh = fmaxf(mh, __shfl_xor(mh, d));
      float se = fexp2(hy - mh);
      #pragma unroll
      for (int d = 8; d >= 1; d >>= 1) se += __shfl_xor(se, d);
      float Hc = mh + log2f(se);
      if ((lane & 15) == 0) {
        int gc = 4*rb + (lane >> 4);
        float4 cv = cent[rset*512 + gc];
        float* cc = (float*)(cpd + 4*(size_t)NPTS + (size_t)dst * 512);
        int p2 = gc >> 1, sub2 = gc & 1;
        cc[p2*8+sub2]   = cv.x;
        cc[p2*8+2+sub2] = cv.y;
        cc[p2*8+4+sub2] = cv.z;
        cc[p2*8+6+sub2] = Hc;
      }
    }
  }
}

// loss = mean(f_fin - p_fin) + mean(g_fin - q_fin), fp64 accumulation
__global__ __launch_bounds__(256) void ws_reduce(
    const float* __restrict__ Tfin, float* __restrict__ out)
{
  int tid = threadIdx.x;
  double acc = 0.0;
  for (int i = tid; i < NPTS; i += 256) {
    acc += (double)Tfin[0*NPTS+i] - (double)Tfin[2*NPTS+i]
         + (double)Tfin[1*NPTS+i] - (double)Tfin[3*NPTS+i];
  }
  __shared__ double sd[256];
  sd[tid] = acc; __syncthreads();
  for (int k = 128; k > 0; k >>= 1) {
    if (tid < k) sd[tid] += sd[tid + k];
    __syncthreads();
  }
  if (tid == 0) out[0] = (float)(sd[0] / (double)NPTS);
}

extern "C" void kernel_launch(void* const* d_in, const int* in_sizes, int n_in,
                              void* d_out, int out_size, void* d_ws, size_t ws_size,
                              hipStream_t stream)
{
  const float* x = (const float*)d_in[0];
  const float* y = (const float*)d_in[1];
  float* out = (float*)d_out;

  const size_t CPSZ = (size_t)4 * NPTS + 2048;   // fine + coarse pack (float4)
  char* wsp = (char*)d_ws;
  float4*   xp   = (float4*)wsp;   wsp += (size_t)NPTS * 16;
  float4*   yp   = (float4*)wsp;   wsp += (size_t)NPTS * 16;
  float4*   cpA  = (float4*)wsp;   wsp += CPSZ * 16;
  float4*   cpB  = (float4*)wsp;   wsp += CPSZ * 16;
  float*    P    = (float*)wsp;    wsp += (size_t)4 * NPTS * 4;
  float*    Tfin = (float*)wsp;    wsp += (size_t)4 * NPTS * 4;
  unsigned* sidx = (unsigned*)wsp; wsp += (size_t)2 * NPTS * 4;
  float*    Mw   = (float*)wsp;    wsp += (size_t)4 * NPTS * 4;
  float*    hmA  = (float*)wsp;    wsp += (size_t)4 * 512 * 4;
  float*    hmB  = (float*)wsp;    wsp += (size_t)4 * 512 * 4;
  float4*   bbox = (float4*)wsp;   wsp += (size_t)2 * 512 * 2 * 16;
  float4*   cent = (float4*)wsp;   wsp += (size_t)2 * 512 * 16;
  float*    dmin = (float*)wsp;    wsp += (size_t)4 * 512 * 512 * 4;  // 4 MB

  // geomloss epsilon schedule (f64, exactly as Python builds it)
  double epss[64]; int n = 0;
  double e = 4.0;                       // DIAMETER**P
  const double r = 0.9 * 0.9;          // SCALING**P
  const double target = 0.01 * 0.01;   // BLUR**P
  while (e > target && n < 60) { epss[n++] = e; e *= r; }   // n == 51

  // Phase plan (R15-proven): eps > 0.15 -> coarse512 (mode 2);
  // 0.15 >= eps > 0.04 -> fine, stride-2 (R13-validated); else fine dense.
  // Final extrapolation at eps_final, fine.
  float feps[80]; int md[80]; int NPH = 0;
  feps[NPH] = (float)epss[0]; md[NPH] = 2; NPH++;          // init (coarse)
  {
    int k = 0;
    while (k < n) {
      int coarse = (epss[k] > 0.15);
      feps[NPH] = (float)epss[k]; md[NPH] = coarse ? 2 : 1; NPH++;
      k += coarse ? 1 : ((epss[k] > 0.04) ? 2 : 1);
    }
  }
  feps[NPH] = 1e-4f; md[NPH] = 1; NPH++;                   // final

  const double L2E  = 1.4426950408889634;
  const double LN2d = 0.6931471805599453;

  float inv0ce = (float)(L2E / (double)feps[0]);
  ws_sort<<<2, 1024, 0, stream>>>(x, y, sidx);
  ws_setup<<<(NPTS + 255) / 256, 256, 0, stream>>>(x, y, sidx, xp, yp, cpA, inv0ce);
  ws_bbox<<<2, 512, 0, stream>>>(xp, yp, bbox, cent, cpA + 4*(size_t)NPTS, inv0ce);
  ws_dmin<<<512, 512, 0, stream>>>(bbox, dmin);

  for (int p = 0; p < NPH; ++p) {
    float epsf = feps[p];
    float ce = (float)(L2E / (double)epsf);
    float eps_ln2 = (float)((double)epsf * LN2d);
    float inv_next_ce = 0.f;
    if (p < NPH - 1) inv_next_ce = (float)(L2E / (double)feps[p+1]);
    float rho = 1.f;
    if (p >= 1) rho = (float)((double)feps[p-1] / (double)feps[p]);
    int kind = (p == 0) ? 0 : ((p == NPH - 1) ? 2 : 1);
    const float4* src = (p & 1) ? cpB : cpA;
    float4*       dst = (p & 1) ? cpA : cpB;
    const float*  hmS = (p & 1) ? hmB : hmA;
    float*        hmD = (p & 1) ? hmA : hmB;
    ws_softmin<<<512, 1024, 0, stream>>>(xp, yp, src, dst, dmin, hmS, hmD,
                                         Mw, cent, P, Tfin,
                                         ce, eps_ln2, inv_next_ce, rho, kind, md[p]);
  }

  ws_reduce<<<1, 256, 0, stream>>>(Tfin, out);
}

// Round 19
// 1325.439 us; speedup vs baseline: 3.3138x; 1.2125x over previous
//
#include <hip/hip_runtime.h>
#include <math.h>

#define NPTS 8192
#define LGAB2 (-13.0f)   // log2(1/8192)
#define NWAVE 16         // waves per block (1024 threads)
#define MARGIN 20.0f     // chunk skip margin vs M_est (exponent units, base 2)

typedef __attribute__((ext_vector_type(2))) float f2;

__device__ __forceinline__ float fexp2(float x){
#if __has_builtin(__builtin_amdgcn_exp2f)
  return __builtin_amdgcn_exp2f(x);
#else
  return exp2f(x);
#endif
}
__device__ __forceinline__ f2 ffma2(f2 a, f2 b, f2 c){
  return __builtin_elementwise_fma(a, b, c);   // v_pk_fma_f32
}
__device__ __forceinline__ f2 fmax2(f2 a, f2 b){
  return __builtin_elementwise_max(a, b);      // v_pk_max_f32
}

// ---------------- counting sort by 12-bit Morton key (16^3 cells) ------------
__global__ __launch_bounds__(1024) void ws_sort(
    const float* __restrict__ x, const float* __restrict__ y,
    unsigned* __restrict__ sidx)
{
  __shared__ unsigned hist[4096];
  __shared__ unsigned wtot[16];
  const float* p = blockIdx.x ? y : x;
  int tid = threadIdx.x;
  for (int i = tid; i < 4096; i += 1024) hist[i] = 0;
  __syncthreads();
  unsigned key[8];
  for (int t = 0; t < 8; ++t) {
    int i = tid + (t << 10);
    unsigned q0 = (unsigned)fminf(fmaxf(p[3*i  ] * 16.f, 0.f), 15.f);
    unsigned q1 = (unsigned)fminf(fmaxf(p[3*i+1] * 16.f, 0.f), 15.f);
    unsigned q2 = (unsigned)fminf(fmaxf(p[3*i+2] * 16.f, 0.f), 15.f);
    unsigned k = 0;
    #pragma unroll
    for (int bb = 0; bb < 4; ++bb)
      k |= (((q0 >> bb) & 1u) << (3*bb)) | (((q1 >> bb) & 1u) << (3*bb+1))
         | (((q2 >> bb) & 1u) << (3*bb+2));
    key[t] = k;
    atomicAdd(&hist[k], 1u);
  }
  __syncthreads();
  unsigned c0 = hist[4*tid], c1 = hist[4*tid+1], c2 = hist[4*tid+2], c3 = hist[4*tid+3];
  unsigned tsum = c0 + c1 + c2 + c3;
  int lane = tid & 63, wv = tid >> 6;
  unsigned inc = tsum;
  for (int d = 1; d < 64; d <<= 1) {
    unsigned o = __shfl_up(inc, d);
    if (lane >= d) inc += o;
  }
  if (lane == 63) wtot[wv] = inc;
  __syncthreads();
  unsigned woff = 0;
  for (int k = 0; k < wv; ++k) woff += wtot[k];
  unsigned base = woff + inc - tsum;
  hist[4*tid] = base; hist[4*tid+1] = base + c0;
  hist[4*tid+2] = base + c0 + c1; hist[4*tid+3] = base + c0 + c1 + c2;
  __syncthreads();
  for (int t = 0; t < 8; ++t) {
    int i = tid + (t << 10);
    unsigned pos = atomicAdd(&hist[key[t]], 1u);
    sidx[blockIdx.x * NPTS + pos] = i;
  }
}

// Fine column pack (sorted domain): per 2 columns, float4 (x0,x1,y0,y1) then
// float4 (z0,z1,w0,w1) where w = h-term (exponent units base 2).
// Coarse pack (after 4*NPTS float4): 512 centroid-columns per slot.
__global__ __launch_bounds__(256) void ws_setup(
    const float* __restrict__ x, const float* __restrict__ y,
    const unsigned* __restrict__ sidx,
    float4* __restrict__ xp, float4* __restrict__ yp,
    float4* __restrict__ colpack, float inv0ce)
{
  int t = blockIdx.x * 256 + threadIdx.x;
  if (t >= NPTS) return;
  int ox = sidx[t], oy = sidx[NPTS + t];
  float x0 = x[3*ox], x1 = x[3*ox+1], x2 = x[3*ox+2];
  float xs = x0*x0 + x1*x1 + x2*x2;
  float y0 = y[3*oy], y1 = y[3*oy+1], y2 = y[3*oy+2];
  float ys = y0*y0 + y1*y1 + y2*y2;
  xp[t] = make_float4(x0,x1,x2,xs);
  yp[t] = make_float4(y0,y1,y2,ys);
  float hx = LGAB2 - 0.5f*xs*inv0ce;
  float hy = LGAB2 - 0.5f*ys*inv0ce;
  int p = t >> 1, sub = t & 1;
  {
    float* c0 = (float*)(colpack + 0*NPTS);
    c0[p*8+sub] = y0; c0[p*8+2+sub] = y1; c0[p*8+4+sub] = y2; c0[p*8+6+sub] = hy;
    float* c3 = (float*)(colpack + 3*NPTS);
    c3[p*8+sub] = y0; c3[p*8+2+sub] = y1; c3[p*8+4+sub] = y2; c3[p*8+6+sub] = hy;
  }
  {
    float* c1 = (float*)(colpack + 1*NPTS);
    c1[p*8+sub] = x0; c1[p*8+2+sub] = x1; c1[p*8+4+sub] = x2; c1[p*8+6+sub] = hx;
    float* c2 = (float*)(colpack + 2*NPTS);
    c2[p*8+sub] = x0; c2[p*8+2+sub] = x1; c2[p*8+4+sub] = x2; c2[p*8+6+sub] = hx;
  }
}

// Per-16-pt cluster: bbox, centroid, and initial coarse pack (duals = 0).
__global__ __launch_bounds__(512) void ws_bbox(
    const float4* __restrict__ xp, const float4* __restrict__ yp,
    float4* __restrict__ bbox, float4* __restrict__ cent,
    float4* __restrict__ cc0, float inv0ce)
{
  int c = threadIdx.x;           // 0..511
  int set = blockIdx.x;
  const float4* pp = set ? yp : xp;
  float lx = 1e30f, ly = 1e30f, lz = 1e30f;
  float hxx = -1e30f, hyy = -1e30f, hzz = -1e30f;
  float sx = 0.f, sy = 0.f, sz = 0.f, hm = -3.0e38f;
  float hv[16];
  for (int k = 0; k < 16; ++k) {
    float4 v = pp[c*16+k];
    lx = fminf(lx, v.x); ly = fminf(ly, v.y); lz = fminf(lz, v.z);
    hxx = fmaxf(hxx, v.x); hyy = fmaxf(hyy, v.y); hzz = fmaxf(hzz, v.z);
    sx += v.x; sy += v.y; sz += v.z;
    float h = LGAB2 - 0.5f * v.w * inv0ce;
    hv[k] = h; hm = fmaxf(hm, h);
  }
  float se = 0.f;
  for (int k = 0; k < 16; ++k) se += fexp2(hv[k] - hm);
  float H = hm + log2f(se);
  bbox[(set*512+c)*2+0] = make_float4(lx, ly, lz, 0.f);
  bbox[(set*512+c)*2+1] = make_float4(hxx, hyy, hzz, 0.f);
  float cx = sx * 0.0625f, cy = sy * 0.0625f, cz = sz * 0.0625f;
  cent[set*512+c] = make_float4(cx, cy, cz, 0.f);
  int s1 = set ? 0 : 1, s2 = set ? 3 : 2;   // slots using this set as columns
  int p = c >> 1, sub = c & 1;
  float* a = (float*)(cc0 + (size_t)s1 * 512);
  a[p*8+sub] = cx; a[p*8+2+sub] = cy; a[p*8+4+sub] = cz; a[p*8+6+sub] = H;
  float* bq = (float*)(cc0 + (size_t)s2 * 512);
  bq[p*8+sub] = cx; bq[p*8+2+sub] = cy; bq[p*8+4+sub] = cz; bq[p*8+6+sub] = H;
}

// dmin^2 at 16-ROW-GROUP granularity.
// blockIdx.x = s*128+rb, threadIdx.x = col chunk c; writes 4 groups per block.
__global__ __launch_bounds__(512) void ws_dmin(
    const float4* __restrict__ bbox, float* __restrict__ dmin)
{
  int b = blockIdx.x;
  int s = b >> 7, rb = b & 127;
  int c = threadIdx.x;
  int rset = (s == 0 || s == 2) ? 0 : 1;
  int cset = (s == 0 || s == 3) ? 1 : 0;
  float4 bl = bbox[(cset*512 + c)*2], bh = bbox[(cset*512 + c)*2+1];
  #pragma unroll
  for (int g = 0; g < 4; ++g) {
    float4 l = bbox[(rset*512 + 4*rb + g)*2];
    float4 h = bbox[(rset*512 + 4*rb + g)*2+1];
    float dx = fmaxf(0.f, fmaxf(l.x - bh.x, bl.x - h.x));
    float dy = fmaxf(0.f, fmaxf(l.y - bh.y, bl.y - h.y));
    float dz = fmaxf(0.f, fmaxf(l.z - bh.z, bl.z - h.z));
    dmin[(((size_t)s*512 + 4*rb + g) << 9) + c] = dx*dx + dy*dy + dz*dz;
  }
}

// One phase. mode 0: fine exact two-pass (fallback).
// mode 1: fine single pass, M_est from prev LSE (x rho) + geometric chunk skip.
//   Chunk ownership INTERLEAVED across waves (gc = (c<<4)|w) for balance (R18).
// mode 2: coarse exact two-pass over 512 centroid-columns (eps > 0.15 regime).
// kind: 0 = assign (init), 1 = 0.5*(P+T) average, 2 = final (write Tfin)
__global__ __launch_bounds__(1024, 8) void ws_softmin(
    const float4* __restrict__ xp, const float4* __restrict__ yp,
    const float4* __restrict__ cps, float4* __restrict__ cpd,
    const float* __restrict__ dmin, const float* __restrict__ hmS,
    float* __restrict__ hmD, float* __restrict__ Mw,
    const float4* __restrict__ cent,
    float* __restrict__ P, float* __restrict__ Tfin,
    float ce, float eps_ln2, float inv_next_ce, float rho, int kind, int mode)
{
  int b = blockIdx.x;
  int s = b >> 7;
  int rb = b & 127;
  int rowbase = rb << 6;
  int tid = threadIdx.x;
  int lane = tid & 63;
  int w = __builtin_amdgcn_readfirstlane(tid >> 6);

  int rset = (s == 0 || s == 2) ? 0 : 1;
  const float4* rp = rset ? yp : xp;
  float4 rv = rp[rowbase + lane];
  float a0 = rv.x * ce, a1 = rv.y * ce, a2 = rv.z * ce;
  float hx = -0.5f * rv.w * ce;
  f2 A0 = {a0,a0}, A1 = {a1,a1}, A2 = {a2,a2};
  const float4* pw = cps + (size_t)s * NPTS + (w << 9);
  const float4* slotbase = cps + (size_t)s * NPTS;
  int row = rowbase + lane;

  __shared__ float lm[NWAVE][64];
  __shared__ float lss[NWAVE][64];
  float myMest = 0.f;

  if (mode == 0) {
    // ---- fine exact two-pass full scan ----
    f2 mA = {-3.0e38f, -3.0e38f}, mB = mA;
    #pragma unroll 2
    for (int pb = 0; pb < 256; pb += 2) {
      float4 P0 = pw[2*pb+0], Q0 = pw[2*pb+1];
      float4 P1 = pw[2*pb+2], Q1 = pw[2*pb+3];
      f2 X0={P0.x,P0.y}, Y0={P0.z,P0.w}, Z0={Q0.x,Q0.y}, W0={Q0.z,Q0.w};
      f2 X1={P1.x,P1.y}, Y1={P1.z,P1.w}, Z1={Q1.x,Q1.y}, W1={Q1.z,Q1.w};
      f2 t0 = ffma2(A2, Z0, W0); t0 = ffma2(A1, Y0, t0); t0 = ffma2(A0, X0, t0);
      f2 t1 = ffma2(A2, Z1, W1); t1 = ffma2(A1, Y1, t1); t1 = ffma2(A0, X1, t1);
      mA = fmax2(mA, t0); mB = fmax2(mB, t1);
    }
    f2 mAB = fmax2(mA, mB);
    float m = fmaxf(mAB.x, mAB.y);
    f2 M2 = {m, m};
    f2 sA = {0.f,0.f}, sB = {0.f,0.f};
    #pragma unroll 2
    for (int pb = 0; pb < 256; pb += 2) {
      float4 P0 = pw[2*pb+0], Q0 = pw[2*pb+1];
      float4 P1 = pw[2*pb+2], Q1 = pw[2*pb+3];
      f2 X0={P0.x,P0.y}, Y0={P0.z,P0.w}, Z0={Q0.x,Q0.y}, W0={Q0.z,Q0.w};
      f2 X1={P1.x,P1.y}, Y1={P1.z,P1.w}, Z1={Q1.x,Q1.y}, W1={Q1.z,Q1.w};
      f2 u0 = ffma2(A2, Z0, W0 - M2); u0 = ffma2(A1, Y0, u0); u0 = ffma2(A0, X0, u0);
      f2 u1 = ffma2(A2, Z1, W1 - M2); u1 = ffma2(A1, Y1, u1); u1 = ffma2(A0, X1, u1);
      f2 e0, e1;
      e0.x = fexp2(u0.x); e0.y = fexp2(u0.y);
      e1.x = fexp2(u1.x); e1.y = fexp2(u1.y);
      sA += e0; sB += e1;
    }
    f2 sAB = sA + sB;
    lm[w][lane] = m;
    lss[w][lane] = sAB.x + sAB.y;
  } else if (mode == 2) {
    // ---- coarse exact two-pass: 512 centroid-cols, 32 per wave ----
    const float4* pwc = cps + 4*(size_t)NPTS + (size_t)s*512 + (w << 5);
    f2 mA = {-3.0e38f, -3.0e38f}, mB = mA;
    #pragma unroll
    for (int pb = 0; pb < 16; pb += 2) {
      float4 P0 = pwc[2*pb+0], Q0 = pwc[2*pb+1];
      float4 P1 = pwc[2*pb+2], Q1 = pwc[2*pb+3];
      f2 X0={P0.x,P0.y}, Y0={P0.z,P0.w}, Z0={Q0.x,Q0.y}, W0={Q0.z,Q0.w};
      f2 X1={P1.x,P1.y}, Y1={P1.z,P1.w}, Z1={Q1.x,Q1.y}, W1={Q1.z,Q1.w};
      f2 t0 = ffma2(A2, Z0, W0); t0 = ffma2(A1, Y0, t0); t0 = ffma2(A0, X0, t0);
      f2 t1 = ffma2(A2, Z1, W1); t1 = ffma2(A1, Y1, t1); t1 = ffma2(A0, X1, t1);
      mA = fmax2(mA, t0); mB = fmax2(mB, t1);
    }
    f2 mAB = fmax2(mA, mB);
    float m = fmaxf(mAB.x, mAB.y);
    f2 M2 = {m, m};
    f2 sA = {0.f,0.f}, sB = {0.f,0.f};
    #pragma unroll
    for (int pb = 0; pb < 16; pb += 2) {
      float4 P0 = pwc[2*pb+0], Q0 = pwc[2*pb+1];
      float4 P1 = pwc[2*pb+2], Q1 = pwc[2*pb+3];
      f2 X0={P0.x,P0.y}, Y0={P0.z,P0.w}, Z0={Q0.x,Q0.y}, W0={Q0.z,Q0.w};
      f2 X1={P1.x,P1.y}, Y1={P1.z,P1.w}, Z1={Q1.x,Q1.y}, W1={Q1.z,Q1.w};
      f2 u0 = ffma2(A2, Z0, W0 - M2); u0 = ffma2(A1, Y0, u0); u0 = ffma2(A0, X0, u0);
      f2 u1 = ffma2(A2, Z1, W1 - M2); u1 = ffma2(A1, Y1, u1); u1 = ffma2(A0, X1, u1);
      f2 e0, e1;
      e0.x = fexp2(u0.x); e0.y = fexp2(u0.y);
      e1.x = fexp2(u1.x); e1.y = fexp2(u1.y);
      sA += e0; sB += e1;
    }
    f2 sAB = sA + sB;
    lm[w][lane] = m;
    lss[w][lane] = sAB.x + sAB.y;
  } else {
    // ---- fine single pass with M_est + interleaved-chunk geometric skip ----
    float Mest = fmaf(Mw[s * NPTS + row] - LGAB2, rho, LGAB2);
    myMest = Mest;
    float thr = Mest - MARGIN;
    int rg = 4*rb + (lane >> 4);            // this row's 16-row group
    const float* dmr = dmin + (((size_t)s*512 + rg) << 9);
    unsigned mask = 0u;
    #pragma unroll
    for (int c = 0; c < 32; ++c) {
      int gc = (c << 4) | w;                // interleaved: stride-16 chunks
      float Wc = hmS[s*512 + gc] - 0.5f * ce * dmr[gc];
      if (__ballot(Wc > thr)) mask |= (1u << c);
    }
    if (mask == 0u) mask = 0xFFFFFFFFu;   // safety: never drop everything
    mask = __builtin_amdgcn_readfirstlane(mask);
    float Mv = Mest - hx;
    f2 M2 = {Mv, Mv};
    f2 sA = {0.f,0.f}, sB = {0.f,0.f};
    for (int c = 0; c < 32; ++c) {
      if (!((mask >> c) & 1u)) continue;
      int gc = (c << 4) | w;
      const float4* pc = slotbase + ((size_t)gc << 4);  // 16 cols = 16 float4s
      #pragma unroll 4
      for (int pb = 0; pb < 8; ++pb) {
        float4 Pv = pc[2*pb], Qv = pc[2*pb+1];
        f2 X={Pv.x,Pv.y}, Y={Pv.z,Pv.w}, Z={Qv.x,Qv.y}, W={Qv.z,Qv.w};
        f2 u = ffma2(A2, Z, W - M2);
        u = ffma2(A1, Y, u);
        u = ffma2(A0, X, u);
        f2 e;
        e.x = fexp2(u.x); e.y = fexp2(u.y);
        if (pb & 1) sB += e; else sA += e;
      }
    }
    f2 sAB = sA + sB;
    lss[w][lane] = sAB.x + sAB.y;
  }
  __syncthreads();

  if (tid < 64) {
    float L;
    if (mode == 1) {
      float S = 0.f;
      #pragma unroll
      for (int k = 0; k < NWAVE; ++k) S += lss[k][lane];
      S = fmaxf(S, 1e-30f);
      L = myMest + log2f(S);
    } else {
      float M = lm[0][lane];
      #pragma unroll
      for (int k = 1; k < NWAVE; ++k) M = fmaxf(M, lm[k][lane]);
      float S = 0.f;
      #pragma unroll
      for (int k = 0; k < NWAVE; ++k) S += lss[k][lane] * fexp2(lm[k][lane] - M);
      L = hx + M + log2f(S);
    }
    float T = -eps_ln2 * L;
    Mw[s * NPTS + row] = L;
    if (kind == 2) {
      Tfin[s * NPTS + row] = T;
    } else {
      float* Pr = P + s * NPTS;
      float Pn = (kind == 0) ? T : 0.5f * (Pr[row] + T);
      Pr[row] = Pn;
      int dst = (s == 0) ? 1 : ((s == 1) ? 0 : s);
      float hy = LGAB2 + (Pn - 0.5f * rv.w) * inv_next_ce;
      float* cd = (float*)(cpd + (size_t)dst * NPTS);
      int p = row >> 1, sub = row & 1;
      cd[p*8+sub]   = rv.x;
      cd[p*8+2+sub] = rv.y;
      cd[p*8+4+sub] = rv.z;
      cd[p*8+6+sub] = hy;
      // Skip-bound table: MUST be LGAB2 + Pn*ce (R14 errata: max(h_j) is NOT
      // a valid bound — the -0.5|y|^2 cancels against the x.y cross term).
      float hN = fmaf(Pn, inv_next_ce, LGAB2);
      #pragma unroll
      for (int d = 8; d >= 1; d >>= 1) hN = fmaxf(hN, __shfl_xor(hN, d));
      if ((lane & 15) == 0) hmD[dst*512 + 4*rb + (lane >> 4)] = hN;
      // coarse pack for next phase: cluster LSE of hy over 16-lane group
      float mh = hy;
      #pragma unroll
      for (int d = 8; d >= 1; d >>= 1) mh = fmaxf(mh, __shfl_xor(mh, d));
      float se = fexp2(hy - mh);
      #pragma unroll
      for (int d = 8; d >= 1; d >>= 1) se += __shfl_xor(se, d);
      float Hc = mh + log2f(se);
      if ((lane & 15) == 0) {
        int gc = 4*rb + (lane >> 4);
        float4 cv = cent[rset*512 + gc];
        float* cc = (float*)(cpd + 4*(size_t)NPTS + (size_t)dst * 512);
        int p2 = gc >> 1, sub2 = gc & 1;
        cc[p2*8+sub2]   = cv.x;
        cc[p2*8+2+sub2] = cv.y;
        cc[p2*8+4+sub2] = cv.z;
        cc[p2*8+6+sub2] = Hc;
      }
    }
  }
}

// loss = mean(f_fin - p_fin) + mean(g_fin - q_fin), fp64 accumulation
__global__ __launch_bounds__(256) void ws_reduce(
    const float* __restrict__ Tfin, float* __restrict__ out)
{
  int tid = threadIdx.x;
  double acc = 0.0;
  for (int i = tid; i < NPTS; i += 256) {
    acc += (double)Tfin[0*NPTS+i] - (double)Tfin[2*NPTS+i]
         + (double)Tfin[1*NPTS+i] - (double)Tfin[3*NPTS+i];
  }
  __shared__ double sd[256];
  sd[tid] = acc; __syncthreads();
  for (int k = 128; k > 0; k >>= 1) {
    if (tid < k) sd[tid] += sd[tid + k];
    __syncthreads();
  }
  if (tid == 0) out[0] = (float)(sd[0] / (double)NPTS);
}

extern "C" void kernel_launch(void* const* d_in, const int* in_sizes, int n_in,
                              void* d_out, int out_size, void* d_ws, size_t ws_size,
                              hipStream_t stream)
{
  const float* x = (const float*)d_in[0];
  const float* y = (const float*)d_in[1];
  float* out = (float*)d_out;

  const size_t CPSZ = (size_t)4 * NPTS + 2048;   // fine + coarse pack (float4)
  char* wsp = (char*)d_ws;
  float4*   xp   = (float4*)wsp;   wsp += (size_t)NPTS * 16;
  float4*   yp   = (float4*)wsp;   wsp += (size_t)NPTS * 16;
  float4*   cpA  = (float4*)wsp;   wsp += CPSZ * 16;
  float4*   cpB  = (float4*)wsp;   wsp += CPSZ * 16;
  float*    P    = (float*)wsp;    wsp += (size_t)4 * NPTS * 4;
  float*    Tfin = (float*)wsp;    wsp += (size_t)4 * NPTS * 4;
  unsigned* sidx = (unsigned*)wsp; wsp += (size_t)2 * NPTS * 4;
  float*    Mw   = (float*)wsp;    wsp += (size_t)4 * NPTS * 4;
  float*    hmA  = (float*)wsp;    wsp += (size_t)4 * 512 * 4;
  float*    hmB  = (float*)wsp;    wsp += (size_t)4 * 512 * 4;
  float4*   bbox = (float4*)wsp;   wsp += (size_t)2 * 512 * 2 * 16;
  float4*   cent = (float4*)wsp;   wsp += (size_t)2 * 512 * 16;
  float*    dmin = (float*)wsp;    wsp += (size_t)4 * 512 * 512 * 4;  // 4 MB

  // geomloss epsilon schedule (f64, exactly as Python builds it)
  double epss[64]; int n = 0;
  double e = 4.0;                       // DIAMETER**P
  const double r = 0.9 * 0.9;          // SCALING**P
  const double target = 0.01 * 0.01;   // BLUR**P
  while (e > target && n < 60) { epss[n++] = e; e *= r; }   // n == 51

  // Phase plan: eps > 0.15 -> coarse512 (mode 2), STRIDE-2 (hyper-contractive
  // regime, error invisible vs bf16 grid — R13/R15 evidence);
  // 0.15 >= eps > 0.01 -> fine stride-2 (extends R13's >0.04 band; damped by
  // the 10+ dense phases after); eps <= 0.01 -> fine dense.
  // Final extrapolation at eps_final, fine masked.
  float feps[80]; int md[80]; int NPH = 0;
  feps[NPH] = (float)epss[0]; md[NPH] = 2; NPH++;          // init (coarse)
  {
    int k = 0;
    while (k < n) {
      int coarse = (epss[k] > 0.15);
      feps[NPH] = (float)epss[k]; md[NPH] = coarse ? 2 : 1; NPH++;
      k += (epss[k] > 0.01) ? 2 : 1;
    }
  }
  feps[NPH] = 1e-4f; md[NPH] = 1; NPH++;                   // final

  const double L2E  = 1.4426950408889634;
  const double LN2d = 0.6931471805599453;

  float inv0ce = (float)(L2E / (double)feps[0]);
  ws_sort<<<2, 1024, 0, stream>>>(x, y, sidx);
  ws_setup<<<(NPTS + 255) / 256, 256, 0, stream>>>(x, y, sidx, xp, yp, cpA, inv0ce);
  ws_bbox<<<2, 512, 0, stream>>>(xp, yp, bbox, cent, cpA + 4*(size_t)NPTS, inv0ce);
  ws_dmin<<<512, 512, 0, stream>>>(bbox, dmin);

  for (int p = 0; p < NPH; ++p) {
    float epsf = feps[p];
    float ce = (float)(L2E / (double)epsf);
    float eps_ln2 = (float)((double)epsf * LN2d);
    float inv_next_ce = 0.f;
    if (p < NPH - 1) inv_next_ce = (float)(L2E / (double)feps[p+1]);
    float rho = 1.f;
    if (p >= 1) rho = (float)((double)feps[p-1] / (double)feps[p]);
    int kind = (p == 0) ? 0 : ((p == NPH - 1) ? 2 : 1);
    const float4* src = (p & 1) ? cpB : cpA;
    float4*       dst = (p & 1) ? cpA : cpB;
    const float*  hmS = (p & 1) ? hmB : hmA;
    float*        hmD = (p & 1) ? hmA : hmB;
    ws_softmin<<<512, 1024, 0, stream>>>(xp, yp, src, dst, dmin, hmS, hmD,
                                         Mw, cent, P, Tfin,
                                         ce, eps_ln2, inv_next_ce, rho, kind, md[p]);
  }

  ws_reduce<<<1, 256, 0, stream>>>(Tfin, out);
}

// Round 20
// 1176.046 us; speedup vs baseline: 3.7348x; 1.1270x over previous
//
#include <hip/hip_runtime.h>
#include <math.h>

#define NPTS 8192
#define LGAB2 (-13.0f)   // log2(1/8192)
#define NWAVE 16         // waves per block (1024 threads)
#define MARGIN 20.0f     // chunk skip margin vs M_est (exponent units, base 2)

typedef __attribute__((ext_vector_type(2))) float f2;

__device__ __forceinline__ float fexp2(float x){
#if __has_builtin(__builtin_amdgcn_exp2f)
  return __builtin_amdgcn_exp2f(x);
#else
  return exp2f(x);
#endif
}
__device__ __forceinline__ f2 ffma2(f2 a, f2 b, f2 c){
  return __builtin_elementwise_fma(a, b, c);   // v_pk_fma_f32
}
__device__ __forceinline__ f2 fmax2(f2 a, f2 b){
  return __builtin_elementwise_max(a, b);      // v_pk_max_f32
}

// ---------------- counting sort by 12-bit Morton key (16^3 cells) ------------
__global__ __launch_bounds__(1024) void ws_sort(
    const float* __restrict__ x, const float* __restrict__ y,
    unsigned* __restrict__ sidx)
{
  __shared__ unsigned hist[4096];
  __shared__ unsigned wtot[16];
  const float* p = blockIdx.x ? y : x;
  int tid = threadIdx.x;
  for (int i = tid; i < 4096; i += 1024) hist[i] = 0;
  __syncthreads();
  unsigned key[8];
  for (int t = 0; t < 8; ++t) {
    int i = tid + (t << 10);
    unsigned q0 = (unsigned)fminf(fmaxf(p[3*i  ] * 16.f, 0.f), 15.f);
    unsigned q1 = (unsigned)fminf(fmaxf(p[3*i+1] * 16.f, 0.f), 15.f);
    unsigned q2 = (unsigned)fminf(fmaxf(p[3*i+2] * 16.f, 0.f), 15.f);
    unsigned k = 0;
    #pragma unroll
    for (int bb = 0; bb < 4; ++bb)
      k |= (((q0 >> bb) & 1u) << (3*bb)) | (((q1 >> bb) & 1u) << (3*bb+1))
         | (((q2 >> bb) & 1u) << (3*bb+2));
    key[t] = k;
    atomicAdd(&hist[k], 1u);
  }
  __syncthreads();
  unsigned c0 = hist[4*tid], c1 = hist[4*tid+1], c2 = hist[4*tid+2], c3 = hist[4*tid+3];
  unsigned tsum = c0 + c1 + c2 + c3;
  int lane = tid & 63, wv = tid >> 6;
  unsigned inc = tsum;
  for (int d = 1; d < 64; d <<= 1) {
    unsigned o = __shfl_up(inc, d);
    if (lane >= d) inc += o;
  }
  if (lane == 63) wtot[wv] = inc;
  __syncthreads();
  unsigned woff = 0;
  for (int k = 0; k < wv; ++k) woff += wtot[k];
  unsigned base = woff + inc - tsum;
  hist[4*tid] = base; hist[4*tid+1] = base + c0;
  hist[4*tid+2] = base + c0 + c1; hist[4*tid+3] = base + c0 + c1 + c2;
  __syncthreads();
  for (int t = 0; t < 8; ++t) {
    int i = tid + (t << 10);
    unsigned pos = atomicAdd(&hist[key[t]], 1u);
    sidx[blockIdx.x * NPTS + pos] = i;
  }
}

// Fine column pack (sorted domain): per 2 columns, float4 (x0,x1,y0,y1) then
// float4 (z0,z1,w0,w1) where w = h-term (exponent units base 2).
// Coarse pack (after 4*NPTS float4): 512 centroid-columns per slot.
__global__ __launch_bounds__(256) void ws_setup(
    const float* __restrict__ x, const float* __restrict__ y,
    const unsigned* __restrict__ sidx,
    float4* __restrict__ xp, float4* __restrict__ yp,
    float4* __restrict__ colpack, float inv0ce)
{
  int t = blockIdx.x * 256 + threadIdx.x;
  if (t >= NPTS) return;
  int ox = sidx[t], oy = sidx[NPTS + t];
  float x0 = x[3*ox], x1 = x[3*ox+1], x2 = x[3*ox+2];
  float xs = x0*x0 + x1*x1 + x2*x2;
  float y0 = y[3*oy], y1 = y[3*oy+1], y2 = y[3*oy+2];
  float ys = y0*y0 + y1*y1 + y2*y2;
  xp[t] = make_float4(x0,x1,x2,xs);
  yp[t] = make_float4(y0,y1,y2,ys);
  float hx = LGAB2 - 0.5f*xs*inv0ce;
  float hy = LGAB2 - 0.5f*ys*inv0ce;
  int p = t >> 1, sub = t & 1;
  {
    float* c0 = (float*)(colpack + 0*NPTS);
    c0[p*8+sub] = y0; c0[p*8+2+sub] = y1; c0[p*8+4+sub] = y2; c0[p*8+6+sub] = hy;
    float* c3 = (float*)(colpack + 3*NPTS);
    c3[p*8+sub] = y0; c3[p*8+2+sub] = y1; c3[p*8+4+sub] = y2; c3[p*8+6+sub] = hy;
  }
  {
    float* c1 = (float*)(colpack + 1*NPTS);
    c1[p*8+sub] = x0; c1[p*8+2+sub] = x1; c1[p*8+4+sub] = x2; c1[p*8+6+sub] = hx;
    float* c2 = (float*)(colpack + 2*NPTS);
    c2[p*8+sub] = x0; c2[p*8+2+sub] = x1; c2[p*8+4+sub] = x2; c2[p*8+6+sub] = hx;
  }
}

// Per-16-pt cluster: bbox, centroid, and initial coarse pack (duals = 0).
__global__ __launch_bounds__(512) void ws_bbox(
    const float4* __restrict__ xp, const float4* __restrict__ yp,
    float4* __restrict__ bbox, float4* __restrict__ cent,
    float4* __restrict__ cc0, float inv0ce)
{
  int c = threadIdx.x;           // 0..511
  int set = blockIdx.x;
  const float4* pp = set ? yp : xp;
  float lx = 1e30f, ly = 1e30f, lz = 1e30f;
  float hxx = -1e30f, hyy = -1e30f, hzz = -1e30f;
  float sx = 0.f, sy = 0.f, sz = 0.f, hm = -3.0e38f;
  float hv[16];
  for (int k = 0; k < 16; ++k) {
    float4 v = pp[c*16+k];
    lx = fminf(lx, v.x); ly = fminf(ly, v.y); lz = fminf(lz, v.z);
    hxx = fmaxf(hxx, v.x); hyy = fmaxf(hyy, v.y); hzz = fmaxf(hzz, v.z);
    sx += v.x; sy += v.y; sz += v.z;
    float h = LGAB2 - 0.5f * v.w * inv0ce;
    hv[k] = h; hm = fmaxf(hm, h);
  }
  float se = 0.f;
  for (int k = 0; k < 16; ++k) se += fexp2(hv[k] - hm);
  float H = hm + log2f(se);
  bbox[(set*512+c)*2+0] = make_float4(lx, ly, lz, 0.f);
  bbox[(set*512+c)*2+1] = make_float4(hxx, hyy, hzz, 0.f);
  float cx = sx * 0.0625f, cy = sy * 0.0625f, cz = sz * 0.0625f;
  cent[set*512+c] = make_float4(cx, cy, cz, 0.f);
  int s1 = set ? 0 : 1, s2 = set ? 3 : 2;   // slots using this set as columns
  int p = c >> 1, sub = c & 1;
  float* a = (float*)(cc0 + (size_t)s1 * 512);
  a[p*8+sub] = cx; a[p*8+2+sub] = cy; a[p*8+4+sub] = cz; a[p*8+6+sub] = H;
  float* bq = (float*)(cc0 + (size_t)s2 * 512);
  bq[p*8+sub] = cx; bq[p*8+2+sub] = cy; bq[p*8+4+sub] = cz; bq[p*8+6+sub] = H;
}

// dmin^2 at 16-ROW-GROUP granularity.
// blockIdx.x = s*128+rb, threadIdx.x = col chunk c; writes 4 groups per block.
__global__ __launch_bounds__(512) void ws_dmin(
    const float4* __restrict__ bbox, float* __restrict__ dmin)
{
  int b = blockIdx.x;
  int s = b >> 7, rb = b & 127;
  int c = threadIdx.x;
  int rset = (s == 0 || s == 2) ? 0 : 1;
  int cset = (s == 0 || s == 3) ? 1 : 0;
  float4 bl = bbox[(cset*512 + c)*2], bh = bbox[(cset*512 + c)*2+1];
  #pragma unroll
  for (int g = 0; g < 4; ++g) {
    float4 l = bbox[(rset*512 + 4*rb + g)*2];
    float4 h = bbox[(rset*512 + 4*rb + g)*2+1];
    float dx = fmaxf(0.f, fmaxf(l.x - bh.x, bl.x - h.x));
    float dy = fmaxf(0.f, fmaxf(l.y - bh.y, bl.y - h.y));
    float dz = fmaxf(0.f, fmaxf(l.z - bh.z, bl.z - h.z));
    dmin[(((size_t)s*512 + 4*rb + g) << 9) + c] = dx*dx + dy*dy + dz*dz;
  }
}

// One phase. mode 0: fine exact two-pass (fallback).
// mode 1: fine single pass, M_est from prev LSE (x rho) + geometric chunk skip.
//   Chunk ownership INTERLEAVED across waves (gc = (c<<4)|w) for balance (R18).
// mode 2: coarse exact two-pass over 512 centroid-columns (eps > 0.15 regime).
// kind: 0 = assign (init), 1 = 0.5*(P+T) average, 2 = final (write Tfin)
__global__ __launch_bounds__(1024, 8) void ws_softmin(
    const float4* __restrict__ xp, const float4* __restrict__ yp,
    const float4* __restrict__ cps, float4* __restrict__ cpd,
    const float* __restrict__ dmin, const float* __restrict__ hmS,
    float* __restrict__ hmD, float* __restrict__ Mw,
    const float4* __restrict__ cent,
    float* __restrict__ P, float* __restrict__ Tfin,
    float ce, float eps_ln2, float inv_next_ce, float rho, int kind, int mode)
{
  int b = blockIdx.x;
  int s = b >> 7;
  int rb = b & 127;
  int rowbase = rb << 6;
  int tid = threadIdx.x;
  int lane = tid & 63;
  int w = __builtin_amdgcn_readfirstlane(tid >> 6);

  int rset = (s == 0 || s == 2) ? 0 : 1;
  const float4* rp = rset ? yp : xp;
  float4 rv = rp[rowbase + lane];
  float a0 = rv.x * ce, a1 = rv.y * ce, a2 = rv.z * ce;
  float hx = -0.5f * rv.w * ce;
  f2 A0 = {a0,a0}, A1 = {a1,a1}, A2 = {a2,a2};
  const float4* pw = cps + (size_t)s * NPTS + (w << 9);
  const float4* slotbase = cps + (size_t)s * NPTS;
  int row = rowbase + lane;

  __shared__ float lm[NWAVE][64];
  __shared__ float lss[NWAVE][64];
  float myMest = 0.f;

  if (mode == 0) {
    // ---- fine exact two-pass full scan ----
    f2 mA = {-3.0e38f, -3.0e38f}, mB = mA;
    #pragma unroll 2
    for (int pb = 0; pb < 256; pb += 2) {
      float4 P0 = pw[2*pb+0], Q0 = pw[2*pb+1];
      float4 P1 = pw[2*pb+2], Q1 = pw[2*pb+3];
      f2 X0={P0.x,P0.y}, Y0={P0.z,P0.w}, Z0={Q0.x,Q0.y}, W0={Q0.z,Q0.w};
      f2 X1={P1.x,P1.y}, Y1={P1.z,P1.w}, Z1={Q1.x,Q1.y}, W1={Q1.z,Q1.w};
      f2 t0 = ffma2(A2, Z0, W0); t0 = ffma2(A1, Y0, t0); t0 = ffma2(A0, X0, t0);
      f2 t1 = ffma2(A2, Z1, W1); t1 = ffma2(A1, Y1, t1); t1 = ffma2(A0, X1, t1);
      mA = fmax2(mA, t0); mB = fmax2(mB, t1);
    }
    f2 mAB = fmax2(mA, mB);
    float m = fmaxf(mAB.x, mAB.y);
    f2 M2 = {m, m};
    f2 sA = {0.f,0.f}, sB = {0.f,0.f};
    #pragma unroll 2
    for (int pb = 0; pb < 256; pb += 2) {
      float4 P0 = pw[2*pb+0], Q0 = pw[2*pb+1];
      float4 P1 = pw[2*pb+2], Q1 = pw[2*pb+3];
      f2 X0={P0.x,P0.y}, Y0={P0.z,P0.w}, Z0={Q0.x,Q0.y}, W0={Q0.z,Q0.w};
      f2 X1={P1.x,P1.y}, Y1={P1.z,P1.w}, Z1={Q1.x,Q1.y}, W1={Q1.z,Q1.w};
      f2 u0 = ffma2(A2, Z0, W0 - M2); u0 = ffma2(A1, Y0, u0); u0 = ffma2(A0, X0, u0);
      f2 u1 = ffma2(A2, Z1, W1 - M2); u1 = ffma2(A1, Y1, u1); u1 = ffma2(A0, X1, u1);
      f2 e0, e1;
      e0.x = fexp2(u0.x); e0.y = fexp2(u0.y);
      e1.x = fexp2(u1.x); e1.y = fexp2(u1.y);
      sA += e0; sB += e1;
    }
    f2 sAB = sA + sB;
    lm[w][lane] = m;
    lss[w][lane] = sAB.x + sAB.y;
  } else if (mode == 2) {
    // ---- coarse exact two-pass: 512 centroid-cols, 32 per wave ----
    const float4* pwc = cps + 4*(size_t)NPTS + (size_t)s*512 + (w << 5);
    f2 mA = {-3.0e38f, -3.0e38f}, mB = mA;
    #pragma unroll
    for (int pb = 0; pb < 16; pb += 2) {
      float4 P0 = pwc[2*pb+0], Q0 = pwc[2*pb+1];
      float4 P1 = pwc[2*pb+2], Q1 = pwc[2*pb+3];
      f2 X0={P0.x,P0.y}, Y0={P0.z,P0.w}, Z0={Q0.x,Q0.y}, W0={Q0.z,Q0.w};
      f2 X1={P1.x,P1.y}, Y1={P1.z,P1.w}, Z1={Q1.x,Q1.y}, W1={Q1.z,Q1.w};
      f2 t0 = ffma2(A2, Z0, W0); t0 = ffma2(A1, Y0, t0); t0 = ffma2(A0, X0, t0);
      f2 t1 = ffma2(A2, Z1, W1); t1 = ffma2(A1, Y1, t1); t1 = ffma2(A0, X1, t1);
      mA = fmax2(mA, t0); mB = fmax2(mB, t1);
    }
    f2 mAB = fmax2(mA, mB);
    float m = fmaxf(mAB.x, mAB.y);
    f2 M2 = {m, m};
    f2 sA = {0.f,0.f}, sB = {0.f,0.f};
    #pragma unroll
    for (int pb = 0; pb < 16; pb += 2) {
      float4 P0 = pwc[2*pb+0], Q0 = pwc[2*pb+1];
      float4 P1 = pwc[2*pb+2], Q1 = pwc[2*pb+3];
      f2 X0={P0.x,P0.y}, Y0={P0.z,P0.w}, Z0={Q0.x,Q0.y}, W0={Q0.z,Q0.w};
      f2 X1={P1.x,P1.y}, Y1={P1.z,P1.w}, Z1={Q1.x,Q1.y}, W1={Q1.z,Q1.w};
      f2 u0 = ffma2(A2, Z0, W0 - M2); u0 = ffma2(A1, Y0, u0); u0 = ffma2(A0, X0, u0);
      f2 u1 = ffma2(A2, Z1, W1 - M2); u1 = ffma2(A1, Y1, u1); u1 = ffma2(A0, X1, u1);
      f2 e0, e1;
      e0.x = fexp2(u0.x); e0.y = fexp2(u0.y);
      e1.x = fexp2(u1.x); e1.y = fexp2(u1.y);
      sA += e0; sB += e1;
    }
    f2 sAB = sA + sB;
    lm[w][lane] = m;
    lss[w][lane] = sAB.x + sAB.y;
  } else {
    // ---- fine single pass with M_est + interleaved-chunk geometric skip ----
    float Mest = fmaf(Mw[s * NPTS + row] - LGAB2, rho, LGAB2);
    myMest = Mest;
    float thr = Mest - MARGIN;
    int rg = 4*rb + (lane >> 4);            // this row's 16-row group
    const float* dmr = dmin + (((size_t)s*512 + rg) << 9);
    unsigned mask = 0u;
    #pragma unroll
    for (int c = 0; c < 32; ++c) {
      int gc = (c << 4) | w;                // interleaved: stride-16 chunks
      float Wc = hmS[s*512 + gc] - 0.5f * ce * dmr[gc];
      if (__ballot(Wc > thr)) mask |= (1u << c);
    }
    if (mask == 0u) mask = 0xFFFFFFFFu;   // safety: never drop everything
    mask = __builtin_amdgcn_readfirstlane(mask);
    float Mv = Mest - hx;
    f2 M2 = {Mv, Mv};
    f2 sA = {0.f,0.f}, sB = {0.f,0.f};
    for (int c = 0; c < 32; ++c) {
      if (!((mask >> c) & 1u)) continue;
      int gc = (c << 4) | w;
      const float4* pc = slotbase + ((size_t)gc << 4);  // 16 cols = 16 float4s
      #pragma unroll 4
      for (int pb = 0; pb < 8; ++pb) {
        float4 Pv = pc[2*pb], Qv = pc[2*pb+1];
        f2 X={Pv.x,Pv.y}, Y={Pv.z,Pv.w}, Z={Qv.x,Qv.y}, W={Qv.z,Qv.w};
        f2 u = ffma2(A2, Z, W - M2);
        u = ffma2(A1, Y, u);
        u = ffma2(A0, X, u);
        f2 e;
        e.x = fexp2(u.x); e.y = fexp2(u.y);
        if (pb & 1) sB += e; else sA += e;
      }
    }
    f2 sAB = sA + sB;
    lss[w][lane] = sAB.x + sAB.y;
  }
  __syncthreads();

  if (tid < 64) {
    float L;
    if (mode == 1) {
      float S = 0.f;
      #pragma unroll
      for (int k = 0; k < NWAVE; ++k) S += lss[k][lane];
      S = fmaxf(S, 1e-30f);
      L = myMest + log2f(S);
    } else {
      float M = lm[0][lane];
      #pragma unroll
      for (int k = 1; k < NWAVE; ++k) M = fmaxf(M, lm[k][lane]);
      float S = 0.f;
      #pragma unroll
      for (int k = 0; k < NWAVE; ++k) S += lss[k][lane] * fexp2(lm[k][lane] - M);
      L = hx + M + log2f(S);
    }
    float T = -eps_ln2 * L;
    Mw[s * NPTS + row] = L;
    if (kind == 2) {
      Tfin[s * NPTS + row] = T;
    } else {
      float* Pr = P + s * NPTS;
      float Pn = (kind == 0) ? T : 0.5f * (Pr[row] + T);
      Pr[row] = Pn;
      int dst = (s == 0) ? 1 : ((s == 1) ? 0 : s);
      float hy = LGAB2 + (Pn - 0.5f * rv.w) * inv_next_ce;
      float* cd = (float*)(cpd + (size_t)dst * NPTS);
      int p = row >> 1, sub = row & 1;
      cd[p*8+sub]   = rv.x;
      cd[p*8+2+sub] = rv.y;
      cd[p*8+4+sub] = rv.z;
      cd[p*8+6+sub] = hy;
      // Skip-bound table: MUST be LGAB2 + Pn*ce (R14 errata: max(h_j) is NOT
      // a valid bound — the -0.5|y|^2 cancels against the x.y cross term).
      float hN = fmaf(Pn, inv_next_ce, LGAB2);
      #pragma unroll
      for (int d = 8; d >= 1; d >>= 1) hN = fmaxf(hN, __shfl_xor(hN, d));
      if ((lane & 15) == 0) hmD[dst*512 + 4*rb + (lane >> 4)] = hN;
      // coarse pack for next phase: cluster LSE of hy over 16-lane group
      float mh = hy;
      #pragma unroll
      for (int d = 8; d >= 1; d >>= 1) mh = fmaxf(mh, __shfl_xor(mh, d));
      float se = fexp2(hy - mh);
      #pragma unroll
      for (int d = 8; d >= 1; d >>= 1) se += __shfl_xor(se, d);
      float Hc = mh + log2f(se);
      if ((lane & 15) == 0) {
        int gc = 4*rb + (lane >> 4);
        float4 cv = cent[rset*512 + gc];
        float* cc = (float*)(cpd + 4*(size_t)NPTS + (size_t)dst * 512);
        int p2 = gc >> 1, sub2 = gc & 1;
        cc[p2*8+sub2]   = cv.x;
        cc[p2*8+2+sub2] = cv.y;
        cc[p2*8+4+sub2] = cv.z;
        cc[p2*8+6+sub2] = Hc;
      }
    }
  }
}

// loss = mean(f_fin - p_fin) + mean(g_fin - q_fin), fp64 accumulation
__global__ __launch_bounds__(256) void ws_reduce(
    const float* __restrict__ Tfin, float* __restrict__ out)
{
  int tid = threadIdx.x;
  double acc = 0.0;
  for (int i = tid; i < NPTS; i += 256) {
    acc += (double)Tfin[0*NPTS+i] - (double)Tfin[2*NPTS+i]
         + (double)Tfin[1*NPTS+i] - (double)Tfin[3*NPTS+i];
  }
  __shared__ double sd[256];
  sd[tid] = acc; __syncthreads();
  for (int k = 128; k > 0; k >>= 1) {
    if (tid < k) sd[tid] += sd[tid + k];
    __syncthreads();
  }
  if (tid == 0) out[0] = (float)(sd[0] / (double)NPTS);
}

extern "C" void kernel_launch(void* const* d_in, const int* in_sizes, int n_in,
                              void* d_out, int out_size, void* d_ws, size_t ws_size,
                              hipStream_t stream)
{
  const float* x = (const float*)d_in[0];
  const float* y = (const float*)d_in[1];
  float* out = (float*)d_out;

  const size_t CPSZ = (size_t)4 * NPTS + 2048;   // fine + coarse pack (float4)
  char* wsp = (char*)d_ws;
  float4*   xp   = (float4*)wsp;   wsp += (size_t)NPTS * 16;
  float4*   yp   = (float4*)wsp;   wsp += (size_t)NPTS * 16;
  float4*   cpA  = (float4*)wsp;   wsp += CPSZ * 16;
  float4*   cpB  = (float4*)wsp;   wsp += CPSZ * 16;
  float*    P    = (float*)wsp;    wsp += (size_t)4 * NPTS * 4;
  float*    Tfin = (float*)wsp;    wsp += (size_t)4 * NPTS * 4;
  unsigned* sidx = (unsigned*)wsp; wsp += (size_t)2 * NPTS * 4;
  float*    Mw   = (float*)wsp;    wsp += (size_t)4 * NPTS * 4;
  float*    hmA  = (float*)wsp;    wsp += (size_t)4 * 512 * 4;
  float*    hmB  = (float*)wsp;    wsp += (size_t)4 * 512 * 4;
  float4*   bbox = (float4*)wsp;   wsp += (size_t)2 * 512 * 2 * 16;
  float4*   cent = (float4*)wsp;   wsp += (size_t)2 * 512 * 16;
  float*    dmin = (float*)wsp;    wsp += (size_t)4 * 512 * 512 * 4;  // 4 MB

  // geomloss epsilon schedule (f64, exactly as Python builds it)
  double epss[64]; int n = 0;
  double e = 4.0;                       // DIAMETER**P
  const double r = 0.9 * 0.9;          // SCALING**P
  const double target = 0.01 * 0.01;   // BLUR**P
  while (e > target && n < 60) { epss[n++] = e; e *= r; }   // n == 51

  // Phase plan: eps > 0.15 -> coarse512 (mode 2), STRIDE-3 (exact two-pass,
  // no M_est dependence; hyper-contractive regime — trajectory lag invisible,
  // R13/R15 evidence); 0.15 >= eps > 0.004 -> fine stride-2 (extends R19's
  // >0.01 band; >=16 dense recovery phases below); eps <= 0.004 -> fine dense.
  // Final extrapolation at eps_final, fine masked.
  float feps[80]; int md[80]; int NPH = 0;
  feps[NPH] = (float)epss[0]; md[NPH] = 2; NPH++;          // init (coarse)
  {
    int k = 0;
    while (k < n) {
      int coarse = (epss[k] > 0.15);
      feps[NPH] = (float)epss[k]; md[NPH] = coarse ? 2 : 1; NPH++;
      k += coarse ? 3 : ((epss[k] > 0.004) ? 2 : 1);
    }
  }
  feps[NPH] = 1e-4f; md[NPH] = 1; NPH++;                   // final

  const double L2E  = 1.4426950408889634;
  const double LN2d = 0.6931471805599453;

  float inv0ce = (float)(L2E / (double)feps[0]);
  ws_sort<<<2, 1024, 0, stream>>>(x, y, sidx);
  ws_setup<<<(NPTS + 255) / 256, 256, 0, stream>>>(x, y, sidx, xp, yp, cpA, inv0ce);
  ws_bbox<<<2, 512, 0, stream>>>(xp, yp, bbox, cent, cpA + 4*(size_t)NPTS, inv0ce);
  ws_dmin<<<512, 512, 0, stream>>>(bbox, dmin);

  for (int p = 0; p < NPH; ++p) {
    float epsf = feps[p];
    float ce = (float)(L2E / (double)epsf);
    float eps_ln2 = (float)((double)epsf * LN2d);
    float inv_next_ce = 0.f;
    if (p < NPH - 1) inv_next_ce = (float)(L2E / (double)feps[p+1]);
    float rho = 1.f;
    if (p >= 1) rho = (float)((double)feps[p-1] / (double)feps[p]);
    int kind = (p == 0) ? 0 : ((p == NPH - 1) ? 2 : 1);
    const float4* src = (p & 1) ? cpB : cpA;
    float4*       dst = (p & 1) ? cpA : cpB;
    const float*  hmS = (p & 1) ? hmB : hmA;
    float*        hmD = (p & 1) ? hmA : hmB;
    ws_softmin<<<512, 1024, 0, stream>>>(xp, yp, src, dst, dmin, hmS, hmD,
                                         Mw, cent, P, Tfin,
                                         ce, eps_ln2, inv_next_ce, rho, kind, md[p]);
  }

  ws_reduce<<<1, 256, 0, stream>>>(Tfin, out);
}

// Round 21
// 1125.418 us; speedup vs baseline: 3.9028x; 1.0450x over previous
//
#include <hip/hip_runtime.h>
#include <math.h>

#define NPTS 8192
#define LGAB2 (-13.0f)   // log2(1/8192)
#define NWAVE 16         // waves per block (1024 threads)
#define MARGIN 20.0f     // chunk skip margin vs M_est (exponent units, base 2)

typedef __attribute__((ext_vector_type(2))) float f2;

__device__ __forceinline__ float fexp2(float x){
#if __has_builtin(__builtin_amdgcn_exp2f)
  return __builtin_amdgcn_exp2f(x);
#else
  return exp2f(x);
#endif
}
__device__ __forceinline__ f2 ffma2(f2 a, f2 b, f2 c){
  return __builtin_elementwise_fma(a, b, c);   // v_pk_fma_f32
}
__device__ __forceinline__ f2 fmax2(f2 a, f2 b){
  return __builtin_elementwise_max(a, b);      // v_pk_max_f32
}

// ---------------- counting sort by 12-bit Morton key (16^3 cells) ------------
__global__ __launch_bounds__(1024) void ws_sort(
    const float* __restrict__ x, const float* __restrict__ y,
    unsigned* __restrict__ sidx)
{
  __shared__ unsigned hist[4096];
  __shared__ unsigned wtot[16];
  const float* p = blockIdx.x ? y : x;
  int tid = threadIdx.x;
  for (int i = tid; i < 4096; i += 1024) hist[i] = 0;
  __syncthreads();
  unsigned key[8];
  for (int t = 0; t < 8; ++t) {
    int i = tid + (t << 10);
    unsigned q0 = (unsigned)fminf(fmaxf(p[3*i  ] * 16.f, 0.f), 15.f);
    unsigned q1 = (unsigned)fminf(fmaxf(p[3*i+1] * 16.f, 0.f), 15.f);
    unsigned q2 = (unsigned)fminf(fmaxf(p[3*i+2] * 16.f, 0.f), 15.f);
    unsigned k = 0;
    #pragma unroll
    for (int bb = 0; bb < 4; ++bb)
      k |= (((q0 >> bb) & 1u) << (3*bb)) | (((q1 >> bb) & 1u) << (3*bb+1))
         | (((q2 >> bb) & 1u) << (3*bb+2));
    key[t] = k;
    atomicAdd(&hist[k], 1u);
  }
  __syncthreads();
  unsigned c0 = hist[4*tid], c1 = hist[4*tid+1], c2 = hist[4*tid+2], c3 = hist[4*tid+3];
  unsigned tsum = c0 + c1 + c2 + c3;
  int lane = tid & 63, wv = tid >> 6;
  unsigned inc = tsum;
  for (int d = 1; d < 64; d <<= 1) {
    unsigned o = __shfl_up(inc, d);
    if (lane >= d) inc += o;
  }
  if (lane == 63) wtot[wv] = inc;
  __syncthreads();
  unsigned woff = 0;
  for (int k = 0; k < wv; ++k) woff += wtot[k];
  unsigned base = woff + inc - tsum;
  hist[4*tid] = base; hist[4*tid+1] = base + c0;
  hist[4*tid+2] = base + c0 + c1; hist[4*tid+3] = base + c0 + c1 + c2;
  __syncthreads();
  for (int t = 0; t < 8; ++t) {
    int i = tid + (t << 10);
    unsigned pos = atomicAdd(&hist[key[t]], 1u);
    sidx[blockIdx.x * NPTS + pos] = i;
  }
}

// Fine column pack (sorted domain): per 2 columns, float4 (x0,x1,y0,y1) then
// float4 (z0,z1,w0,w1) where w = h-term (exponent units base 2).
// Coarse pack (after 4*NPTS float4): 512 centroid-columns per slot.
__global__ __launch_bounds__(256) void ws_setup(
    const float* __restrict__ x, const float* __restrict__ y,
    const unsigned* __restrict__ sidx,
    float4* __restrict__ xp, float4* __restrict__ yp,
    float4* __restrict__ colpack, float inv0ce)
{
  int t = blockIdx.x * 256 + threadIdx.x;
  if (t >= NPTS) return;
  int ox = sidx[t], oy = sidx[NPTS + t];
  float x0 = x[3*ox], x1 = x[3*ox+1], x2 = x[3*ox+2];
  float xs = x0*x0 + x1*x1 + x2*x2;
  float y0 = y[3*oy], y1 = y[3*oy+1], y2 = y[3*oy+2];
  float ys = y0*y0 + y1*y1 + y2*y2;
  xp[t] = make_float4(x0,x1,x2,xs);
  yp[t] = make_float4(y0,y1,y2,ys);
  float hx = LGAB2 - 0.5f*xs*inv0ce;
  float hy = LGAB2 - 0.5f*ys*inv0ce;
  int p = t >> 1, sub = t & 1;
  {
    float* c0 = (float*)(colpack + 0*NPTS);
    c0[p*8+sub] = y0; c0[p*8+2+sub] = y1; c0[p*8+4+sub] = y2; c0[p*8+6+sub] = hy;
    float* c3 = (float*)(colpack + 3*NPTS);
    c3[p*8+sub] = y0; c3[p*8+2+sub] = y1; c3[p*8+4+sub] = y2; c3[p*8+6+sub] = hy;
  }
  {
    float* c1 = (float*)(colpack + 1*NPTS);
    c1[p*8+sub] = x0; c1[p*8+2+sub] = x1; c1[p*8+4+sub] = x2; c1[p*8+6+sub] = hx;
    float* c2 = (float*)(colpack + 2*NPTS);
    c2[p*8+sub] = x0; c2[p*8+2+sub] = x1; c2[p*8+4+sub] = x2; c2[p*8+6+sub] = hx;
  }
}

// Per-16-pt cluster: bbox, centroid, and initial coarse pack (duals = 0).
__global__ __launch_bounds__(512) void ws_bbox(
    const float4* __restrict__ xp, const float4* __restrict__ yp,
    float4* __restrict__ bbox, float4* __restrict__ cent,
    float4* __restrict__ cc0, float inv0ce)
{
  int c = threadIdx.x;           // 0..511
  int set = blockIdx.x;
  const float4* pp = set ? yp : xp;
  float lx = 1e30f, ly = 1e30f, lz = 1e30f;
  float hxx = -1e30f, hyy = -1e30f, hzz = -1e30f;
  float sx = 0.f, sy = 0.f, sz = 0.f, hm = -3.0e38f;
  float hv[16];
  for (int k = 0; k < 16; ++k) {
    float4 v = pp[c*16+k];
    lx = fminf(lx, v.x); ly = fminf(ly, v.y); lz = fminf(lz, v.z);
    hxx = fmaxf(hxx, v.x); hyy = fmaxf(hyy, v.y); hzz = fmaxf(hzz, v.z);
    sx += v.x; sy += v.y; sz += v.z;
    float h = LGAB2 - 0.5f * v.w * inv0ce;
    hv[k] = h; hm = fmaxf(hm, h);
  }
  float se = 0.f;
  for (int k = 0; k < 16; ++k) se += fexp2(hv[k] - hm);
  float H = hm + log2f(se);
  bbox[(set*512+c)*2+0] = make_float4(lx, ly, lz, 0.f);
  bbox[(set*512+c)*2+1] = make_float4(hxx, hyy, hzz, 0.f);
  float cx = sx * 0.0625f, cy = sy * 0.0625f, cz = sz * 0.0625f;
  cent[set*512+c] = make_float4(cx, cy, cz, 0.f);
  int s1 = set ? 0 : 1, s2 = set ? 3 : 2;   // slots using this set as columns
  int p = c >> 1, sub = c & 1;
  float* a = (float*)(cc0 + (size_t)s1 * 512);
  a[p*8+sub] = cx; a[p*8+2+sub] = cy; a[p*8+4+sub] = cz; a[p*8+6+sub] = H;
  float* bq = (float*)(cc0 + (size_t)s2 * 512);
  bq[p*8+sub] = cx; bq[p*8+2+sub] = cy; bq[p*8+4+sub] = cz; bq[p*8+6+sub] = H;
}

// dmin^2 at 16-ROW-GROUP granularity.
// blockIdx.x = s*128+rb, threadIdx.x = col chunk c; writes 4 groups per block.
__global__ __launch_bounds__(512) void ws_dmin(
    const float4* __restrict__ bbox, float* __restrict__ dmin)
{
  int b = blockIdx.x;
  int s = b >> 7, rb = b & 127;
  int c = threadIdx.x;
  int rset = (s == 0 || s == 2) ? 0 : 1;
  int cset = (s == 0 || s == 3) ? 1 : 0;
  float4 bl = bbox[(cset*512 + c)*2], bh = bbox[(cset*512 + c)*2+1];
  #pragma unroll
  for (int g = 0; g < 4; ++g) {
    float4 l = bbox[(rset*512 + 4*rb + g)*2];
    float4 h = bbox[(rset*512 + 4*rb + g)*2+1];
    float dx = fmaxf(0.f, fmaxf(l.x - bh.x, bl.x - h.x));
    float dy = fmaxf(0.f, fmaxf(l.y - bh.y, bl.y - h.y));
    float dz = fmaxf(0.f, fmaxf(l.z - bh.z, bl.z - h.z));
    dmin[(((size_t)s*512 + 4*rb + g) << 9) + c] = dx*dx + dy*dy + dz*dz;
  }
}

// One phase. mode 0: fine exact two-pass (fallback).
// mode 1: fine single pass, M_est from prev LSE (x rho) + geometric chunk skip.
//   Chunk ownership INTERLEAVED across waves (gc = (c<<4)|w) for balance (R18).
// mode 2: coarse exact two-pass over 512 centroid-columns (eps > 0.15 regime).
// kind: 0 = assign (init), 1 = 0.5*(P+T) average, 2 = final (write Tfin)
__global__ __launch_bounds__(1024, 8) void ws_softmin(
    const float4* __restrict__ xp, const float4* __restrict__ yp,
    const float4* __restrict__ cps, float4* __restrict__ cpd,
    const float* __restrict__ dmin, const float* __restrict__ hmS,
    float* __restrict__ hmD, float* __restrict__ Mw,
    const float4* __restrict__ cent,
    float* __restrict__ P, float* __restrict__ Tfin,
    float ce, float eps_ln2, float inv_next_ce, float rho, int kind, int mode)
{
  int b = blockIdx.x;
  int s = b >> 7;
  int rb = b & 127;
  int rowbase = rb << 6;
  int tid = threadIdx.x;
  int lane = tid & 63;
  int w = __builtin_amdgcn_readfirstlane(tid >> 6);

  int rset = (s == 0 || s == 2) ? 0 : 1;
  const float4* rp = rset ? yp : xp;
  float4 rv = rp[rowbase + lane];
  float a0 = rv.x * ce, a1 = rv.y * ce, a2 = rv.z * ce;
  float hx = -0.5f * rv.w * ce;
  f2 A0 = {a0,a0}, A1 = {a1,a1}, A2 = {a2,a2};
  const float4* pw = cps + (size_t)s * NPTS + (w << 9);
  const float4* slotbase = cps + (size_t)s * NPTS;
  int row = rowbase + lane;

  __shared__ float lm[NWAVE][64];
  __shared__ float lss[NWAVE][64];
  float myMest = 0.f;

  if (mode == 0) {
    // ---- fine exact two-pass full scan ----
    f2 mA = {-3.0e38f, -3.0e38f}, mB = mA;
    #pragma unroll 2
    for (int pb = 0; pb < 256; pb += 2) {
      float4 P0 = pw[2*pb+0], Q0 = pw[2*pb+1];
      float4 P1 = pw[2*pb+2], Q1 = pw[2*pb+3];
      f2 X0={P0.x,P0.y}, Y0={P0.z,P0.w}, Z0={Q0.x,Q0.y}, W0={Q0.z,Q0.w};
      f2 X1={P1.x,P1.y}, Y1={P1.z,P1.w}, Z1={Q1.x,Q1.y}, W1={Q1.z,Q1.w};
      f2 t0 = ffma2(A2, Z0, W0); t0 = ffma2(A1, Y0, t0); t0 = ffma2(A0, X0, t0);
      f2 t1 = ffma2(A2, Z1, W1); t1 = ffma2(A1, Y1, t1); t1 = ffma2(A0, X1, t1);
      mA = fmax2(mA, t0); mB = fmax2(mB, t1);
    }
    f2 mAB = fmax2(mA, mB);
    float m = fmaxf(mAB.x, mAB.y);
    f2 M2 = {m, m};
    f2 sA = {0.f,0.f}, sB = {0.f,0.f};
    #pragma unroll 2
    for (int pb = 0; pb < 256; pb += 2) {
      float4 P0 = pw[2*pb+0], Q0 = pw[2*pb+1];
      float4 P1 = pw[2*pb+2], Q1 = pw[2*pb+3];
      f2 X0={P0.x,P0.y}, Y0={P0.z,P0.w}, Z0={Q0.x,Q0.y}, W0={Q0.z,Q0.w};
      f2 X1={P1.x,P1.y}, Y1={P1.z,P1.w}, Z1={Q1.x,Q1.y}, W1={Q1.z,Q1.w};
      f2 u0 = ffma2(A2, Z0, W0 - M2); u0 = ffma2(A1, Y0, u0); u0 = ffma2(A0, X0, u0);
      f2 u1 = ffma2(A2, Z1, W1 - M2); u1 = ffma2(A1, Y1, u1); u1 = ffma2(A0, X1, u1);
      f2 e0, e1;
      e0.x = fexp2(u0.x); e0.y = fexp2(u0.y);
      e1.x = fexp2(u1.x); e1.y = fexp2(u1.y);
      sA += e0; sB += e1;
    }
    f2 sAB = sA + sB;
    lm[w][lane] = m;
    lss[w][lane] = sAB.x + sAB.y;
  } else if (mode == 2) {
    // ---- coarse exact two-pass: 512 centroid-cols, 32 per wave ----
    const float4* pwc = cps + 4*(size_t)NPTS + (size_t)s*512 + (w << 5);
    f2 mA = {-3.0e38f, -3.0e38f}, mB = mA;
    #pragma unroll
    for (int pb = 0; pb < 16; pb += 2) {
      float4 P0 = pwc[2*pb+0], Q0 = pwc[2*pb+1];
      float4 P1 = pwc[2*pb+2], Q1 = pwc[2*pb+3];
      f2 X0={P0.x,P0.y}, Y0={P0.z,P0.w}, Z0={Q0.x,Q0.y}, W0={Q0.z,Q0.w};
      f2 X1={P1.x,P1.y}, Y1={P1.z,P1.w}, Z1={Q1.x,Q1.y}, W1={Q1.z,Q1.w};
      f2 t0 = ffma2(A2, Z0, W0); t0 = ffma2(A1, Y0, t0); t0 = ffma2(A0, X0, t0);
      f2 t1 = ffma2(A2, Z1, W1); t1 = ffma2(A1, Y1, t1); t1 = ffma2(A0, X1, t1);
      mA = fmax2(mA, t0); mB = fmax2(mB, t1);
    }
    f2 mAB = fmax2(mA, mB);
    float m = fmaxf(mAB.x, mAB.y);
    f2 M2 = {m, m};
    f2 sA = {0.f,0.f}, sB = {0.f,0.f};
    #pragma unroll
    for (int pb = 0; pb < 16; pb += 2) {
      float4 P0 = pwc[2*pb+0], Q0 = pwc[2*pb+1];
      float4 P1 = pwc[2*pb+2], Q1 = pwc[2*pb+3];
      f2 X0={P0.x,P0.y}, Y0={P0.z,P0.w}, Z0={Q0.x,Q0.y}, W0={Q0.z,Q0.w};
      f2 X1={P1.x,P1.y}, Y1={P1.z,P1.w}, Z1={Q1.x,Q1.y}, W1={Q1.z,Q1.w};
      f2 u0 = ffma2(A2, Z0, W0 - M2); u0 = ffma2(A1, Y0, u0); u0 = ffma2(A0, X0, u0);
      f2 u1 = ffma2(A2, Z1, W1 - M2); u1 = ffma2(A1, Y1, u1); u1 = ffma2(A0, X1, u1);
      f2 e0, e1;
      e0.x = fexp2(u0.x); e0.y = fexp2(u0.y);
      e1.x = fexp2(u1.x); e1.y = fexp2(u1.y);
      sA += e0; sB += e1;
    }
    f2 sAB = sA + sB;
    lm[w][lane] = m;
    lss[w][lane] = sAB.x + sAB.y;
  } else {
    // ---- fine single pass with M_est + interleaved-chunk geometric skip ----
    float Mest = fmaf(Mw[s * NPTS + row] - LGAB2, rho, LGAB2);
    myMest = Mest;
    float thr = Mest - MARGIN;
    int rg = 4*rb + (lane >> 4);            // this row's 16-row group
    const float* dmr = dmin + (((size_t)s*512 + rg) << 9);
    unsigned mask = 0u;
    #pragma unroll
    for (int c = 0; c < 32; ++c) {
      int gc = (c << 4) | w;                // interleaved: stride-16 chunks
      float Wc = hmS[s*512 + gc] - 0.5f * ce * dmr[gc];
      if (__ballot(Wc > thr)) mask |= (1u << c);
    }
    if (mask == 0u) mask = 0xFFFFFFFFu;   // safety: never drop everything
    mask = __builtin_amdgcn_readfirstlane(mask);
    float Mv = Mest - hx;
    f2 M2 = {Mv, Mv};
    f2 sA = {0.f,0.f}, sB = {0.f,0.f};
    for (int c = 0; c < 32; ++c) {
      if (!((mask >> c) & 1u)) continue;
      int gc = (c << 4) | w;
      const float4* pc = slotbase + ((size_t)gc << 4);  // 16 cols = 16 float4s
      #pragma unroll 4
      for (int pb = 0; pb < 8; ++pb) {
        float4 Pv = pc[2*pb], Qv = pc[2*pb+1];
        f2 X={Pv.x,Pv.y}, Y={Pv.z,Pv.w}, Z={Qv.x,Qv.y}, W={Qv.z,Qv.w};
        f2 u = ffma2(A2, Z, W - M2);
        u = ffma2(A1, Y, u);
        u = ffma2(A0, X, u);
        f2 e;
        e.x = fexp2(u.x); e.y = fexp2(u.y);
        if (pb & 1) sB += e; else sA += e;
      }
    }
    f2 sAB = sA + sB;
    lss[w][lane] = sAB.x + sAB.y;
  }
  __syncthreads();

  if (tid < 64) {
    float L;
    if (mode == 1) {
      float S = 0.f;
      #pragma unroll
      for (int k = 0; k < NWAVE; ++k) S += lss[k][lane];
      S = fmaxf(S, 1e-30f);
      L = myMest + log2f(S);
    } else {
      float M = lm[0][lane];
      #pragma unroll
      for (int k = 1; k < NWAVE; ++k) M = fmaxf(M, lm[k][lane]);
      float S = 0.f;
      #pragma unroll
      for (int k = 0; k < NWAVE; ++k) S += lss[k][lane] * fexp2(lm[k][lane] - M);
      L = hx + M + log2f(S);
    }
    float T = -eps_ln2 * L;
    Mw[s * NPTS + row] = L;
    if (kind == 2) {
      Tfin[s * NPTS + row] = T;
    } else {
      float* Pr = P + s * NPTS;
      float Pn = (kind == 0) ? T : 0.5f * (Pr[row] + T);
      Pr[row] = Pn;
      int dst = (s == 0) ? 1 : ((s == 1) ? 0 : s);
      float hy = LGAB2 + (Pn - 0.5f * rv.w) * inv_next_ce;
      float* cd = (float*)(cpd + (size_t)dst * NPTS);
      int p = row >> 1, sub = row & 1;
      cd[p*8+sub]   = rv.x;
      cd[p*8+2+sub] = rv.y;
      cd[p*8+4+sub] = rv.z;
      cd[p*8+6+sub] = hy;
      // Skip-bound table: MUST be LGAB2 + Pn*ce (R14 errata: max(h_j) is NOT
      // a valid bound — the -0.5|y|^2 cancels against the x.y cross term).
      float hN = fmaf(Pn, inv_next_ce, LGAB2);
      #pragma unroll
      for (int d = 8; d >= 1; d >>= 1) hN = fmaxf(hN, __shfl_xor(hN, d));
      if ((lane & 15) == 0) hmD[dst*512 + 4*rb + (lane >> 4)] = hN;
      // coarse pack for next phase: cluster LSE of hy over 16-lane group
      float mh = hy;
      #pragma unroll
      for (int d = 8; d >= 1; d >>= 1) mh = fmaxf(mh, __shfl_xor(mh, d));
      float se = fexp2(hy - mh);
      #pragma unroll
      for (int d = 8; d >= 1; d >>= 1) se += __shfl_xor(se, d);
      float Hc = mh + log2f(se);
      if ((lane & 15) == 0) {
        int gc = 4*rb + (lane >> 4);
        float4 cv = cent[rset*512 + gc];
        float* cc = (float*)(cpd + 4*(size_t)NPTS + (size_t)dst * 512);
        int p2 = gc >> 1, sub2 = gc & 1;
        cc[p2*8+sub2]   = cv.x;
        cc[p2*8+2+sub2] = cv.y;
        cc[p2*8+4+sub2] = cv.z;
        cc[p2*8+6+sub2] = Hc;
      }
    }
  }
}

// loss = mean(f_fin - p_fin) + mean(g_fin - q_fin), fp64 accumulation
__global__ __launch_bounds__(256) void ws_reduce(
    const float* __restrict__ Tfin, float* __restrict__ out)
{
  int tid = threadIdx.x;
  double acc = 0.0;
  for (int i = tid; i < NPTS; i += 256) {
    acc += (double)Tfin[0*NPTS+i] - (double)Tfin[2*NPTS+i]
         + (double)Tfin[1*NPTS+i] - (double)Tfin[3*NPTS+i];
  }
  __shared__ double sd[256];
  sd[tid] = acc; __syncthreads();
  for (int k = 128; k > 0; k >>= 1) {
    if (tid < k) sd[tid] += sd[tid + k];
    __syncthreads();
  }
  if (tid == 0) out[0] = (float)(sd[0] / (double)NPTS);
}

extern "C" void kernel_launch(void* const* d_in, const int* in_sizes, int n_in,
                              void* d_out, int out_size, void* d_ws, size_t ws_size,
                              hipStream_t stream)
{
  const float* x = (const float*)d_in[0];
  const float* y = (const float*)d_in[1];
  float* out = (float*)d_out;

  const size_t CPSZ = (size_t)4 * NPTS + 2048;   // fine + coarse pack (float4)
  char* wsp = (char*)d_ws;
  float4*   xp   = (float4*)wsp;   wsp += (size_t)NPTS * 16;
  float4*   yp   = (float4*)wsp;   wsp += (size_t)NPTS * 16;
  float4*   cpA  = (float4*)wsp;   wsp += CPSZ * 16;
  float4*   cpB  = (float4*)wsp;   wsp += CPSZ * 16;
  float*    P    = (float*)wsp;    wsp += (size_t)4 * NPTS * 4;
  float*    Tfin = (float*)wsp;    wsp += (size_t)4 * NPTS * 4;
  unsigned* sidx = (unsigned*)wsp; wsp += (size_t)2 * NPTS * 4;
  float*    Mw   = (float*)wsp;    wsp += (size_t)4 * NPTS * 4;
  float*    hmA  = (float*)wsp;    wsp += (size_t)4 * 512 * 4;
  float*    hmB  = (float*)wsp;    wsp += (size_t)4 * 512 * 4;
  float4*   bbox = (float4*)wsp;   wsp += (size_t)2 * 512 * 2 * 16;
  float4*   cent = (float4*)wsp;   wsp += (size_t)2 * 512 * 16;
  float*    dmin = (float*)wsp;    wsp += (size_t)4 * 512 * 512 * 4;  // 4 MB

  // geomloss epsilon schedule (f64, exactly as Python builds it)
  double epss[64]; int n = 0;
  double e = 4.0;                       // DIAMETER**P
  const double r = 0.9 * 0.9;          // SCALING**P
  const double target = 0.01 * 0.01;   // BLUR**P
  while (e > target && n < 60) { epss[n++] = e; e *= r; }   // n == 51

  // Phase plan: eps > 0.15 -> coarse512 (mode 2), STRIDE-3 (exact two-pass,
  // hyper-contractive — trajectory lag invisible, R13/R15/R20 evidence);
  // 0.15 >= eps > 0.0025 -> fine stride-2 (extends R20's >0.004 band; ~14
  // dense recovery phases below); eps <= 0.0025 -> fine dense.
  // Final extrapolation at eps_final, fine masked.
  float feps[80]; int md[80]; int NPH = 0;
  feps[NPH] = (float)epss[0]; md[NPH] = 2; NPH++;          // init (coarse)
  {
    int k = 0;
    while (k < n) {
      int coarse = (epss[k] > 0.15);
      feps[NPH] = (float)epss[k]; md[NPH] = coarse ? 2 : 1; NPH++;
      k += coarse ? 3 : ((epss[k] > 0.0025) ? 2 : 1);
    }
  }
  feps[NPH] = 1e-4f; md[NPH] = 1; NPH++;                   // final

  const double L2E  = 1.4426950408889634;
  const double LN2d = 0.6931471805599453;

  float inv0ce = (float)(L2E / (double)feps[0]);
  ws_sort<<<2, 1024, 0, stream>>>(x, y, sidx);
  ws_setup<<<(NPTS + 255) / 256, 256, 0, stream>>>(x, y, sidx, xp, yp, cpA, inv0ce);
  ws_bbox<<<2, 512, 0, stream>>>(xp, yp, bbox, cent, cpA + 4*(size_t)NPTS, inv0ce);
  ws_dmin<<<512, 512, 0, stream>>>(bbox, dmin);

  for (int p = 0; p < NPH; ++p) {
    float epsf = feps[p];
    float ce = (float)(L2E / (double)epsf);
    float eps_ln2 = (float)((double)epsf * LN2d);
    float inv_next_ce = 0.f;
    if (p < NPH - 1) inv_next_ce = (float)(L2E / (double)feps[p+1]);
    float rho = 1.f;
    if (p >= 1) rho = (float)((double)feps[p-1] / (double)feps[p]);
    int kind = (p == 0) ? 0 : ((p == NPH - 1) ? 2 : 1);
    const float4* src = (p & 1) ? cpB : cpA;
    float4*       dst = (p & 1) ? cpA : cpB;
    const float*  hmS = (p & 1) ? hmB : hmA;
    float*        hmD = (p & 1) ? hmA : hmB;
    ws_softmin<<<512, 1024, 0, stream>>>(xp, yp, src, dst, dmin, hmS, hmD,
                                         Mw, cent, P, Tfin,
                                         ce, eps_ln2, inv_next_ce, rho, kind, md[p]);
  }

  ws_reduce<<<1, 256, 0, stream>>>(Tfin, out);
}